// Round 10
// baseline (3642.241 us; speedup 1.0000x reference)
//
#include <hip/hip_runtime.h>
#include <math.h>

// ---------------- problem sizes ----------------
#define NB 8
#define NN 56
#define POS 3136             // 56*56
#define ROWS 25088           // 8*3136
#define GR 111               // 2N-1
#define GROWS 12321          // 111*111
#define FREQ 16640           // per-channel spectrum: [kq 65][256] (re 128 | im 128)

// ---------------- workspace layout (float offsets), base 36.5 MB ----------------
#define OFF_MVT    0u
#define OFF_M2T    28672u
#define OFF_RT2T   57344u
#define OFF_RTC    64960u
#define OFF_MG     79392u
#define OFF_RTCAH  136224u
#define OFF_RTCAL  140384u
#define OFF_MVAH   144544u
#define OFF_MVAL   160928u
#define OFF_M2AH   177312u
#define OFF_M2AL   191648u
#define OFF_RT2BH  205984u
#define OFF_RT2BL  210592u
#define OFF_NINV   215200u
#define OFF_SINV   240288u
#define OFF_WB     252624u
#define OFF_TB16   1694416u
#define OFF_POOL   4848592u
#define WS_FLOATS  9124816u   // 36.5 MB
// ---- ext1: fused u|v projection ----
#define OFF_XN16   9124816u   // 25088x512 bf16 = 6,422,528 fl
#define OFF_WUV    15547344u  // [8][256][512] bf16 = 524,288 fl
#define OFF_BUV    16071632u  // [2048] fp32
#define WS_EXT     16073680u  // 64.3 MB
// ---- ext2: single K=1024 output GEMM ----
#define OFF_UYF    16073680u  // 25088x1024 bf16 = 12,845,056 fl
#define WS_EXT2    28918736u  // 115.7 MB
// ---- ext3: batched all-heads g-spectrum pipeline ----
#define GH_STRIDE_US   1818624u   // 14208*128
#define TGF_STRIDE_US  1863680u   // 16640*112 (= 8320*224)
#define GHAT_STRIDE_US 2129920u   // 128*65*256
#define OFF_GHA    28918736u  // [8]*GH_STRIDE bf16 = 7,274,496 fl
#define OFF_GLA    36193232u  // 7,274,496 fl
#define OFF_TGFHA  43467728u  // [8]*TGF_STRIDE bf16 = 7,454,720 fl
#define OFF_TGFLA  50922448u  // 7,454,720 fl
#define OFF_GHATA  28918736u  // [8]*GHAT_STRIDE bf16 — ALIASES GhA/GlA (dead after stage1)
#define WS_EXT3    58377168u  // 233.5 MB
// ---- ext4: all-heads v buffer -> batched uv/vfft/fusey (3 launches for 24) ----
#define VCMA_HS    3211264u   // 1024*3136 (us) per-head stride
#define OFF_VCMA   58377168u  // [8][1024][3136] bf16 = 12,845,056 fl
#define WS_EXT4    71222224u  // 284.9 MB
// WB sub-offsets (ushort units)
#define WB_WU  0u
#define WB_WV  524288u
#define WB_WO  1048576u
#define WB_WH  1572864u
#define WB_WRO 2359296u
// pool sub-offsets (fl units) — fallback (non-ext3) per-head g-path:
#define POOL_U16   1064960u
#define POOL_VCM   2670592u
#define POOL_GH    0u
#define POOL_GL    909312u
#define POOL_TGFH  1818624u
#define POOL_TGFL  2750464u

typedef __attribute__((ext_vector_type(8))) short bf8_t;
typedef __attribute__((ext_vector_type(8))) unsigned short us8_t;
typedef __attribute__((ext_vector_type(4))) float f4_t;

__device__ inline float bf2f(unsigned short b) {
    union { unsigned u; float f; } v; v.u = ((unsigned)b) << 16; return v.f;
}
__device__ inline unsigned short f2bf(float f) {
    union { float f; unsigned u; } v; v.f = f;
    unsigned r = v.u + 0x7FFF + ((v.u >> 16) & 1);
    return (unsigned short)(r >> 16);
}

__global__ void probe_k(float* out, float code) { out[0] = code; }

// =====================================================================
// fp32 constants (gfft + vfft Nyquist tail). angle reduced: (a*b) mod 128
// =====================================================================
__global__ void consts_k(float* RTc, float* MvT, float* Mg, float* M2cT, float* RT2cT) {
    int idx = blockIdx.x * 256 + threadIdx.x;
    const float STEP = 0.049087385212340526f; // 2*pi/128
    if (idx < 14430) { // RTc[q*130+col]: gfft row DFT
        int q = idx / 130, col = idx % 130;
        int a = (col < 65) ? col : col - 65;
        float th = (float)((a * q) & 127) * STEP;
        RTc[idx] = (col < 65) ? cosf(th) : -sinf(th);
        return;
    }
    idx -= 14430;
    if (idx < 28672) { // MvT[s*256+r]
        int s = idx / 256, r = idx % 256;
        int kp = (r < 128) ? r : r - 128;
        int sp = (s < 56) ? s : s - 56;
        float th = (float)((kp * sp) & 127) * STEP;
        float cv = cosf(th), sv = sinf(th);
        MvT[idx] = (r < 128) ? ((s < 56) ? cv : sv) : ((s < 56) ? -sv : cv);
        return;
    }
    idx -= 28672;
    if (idx < 56832) { // Mg[r*222+s]: gfft col DFT
        int r = idx / 222, s = idx % 222;
        int kp = (r < 128) ? r : r - 128;
        int sp = (s < 111) ? s : s - 111;
        float th = (float)((kp * sp) & 127) * STEP;
        float cv = cosf(th), sv = sinf(th);
        Mg[idx] = (r < 128) ? ((s < 111) ? cv : sv) : ((s < 111) ? -sv : cv);
        return;
    }
    idx -= 56832;
    if (idx < 28672) { // M2cT[s*112+r]
        int s = idx / 112, r = idx % 112;
        int a = (r < 56) ? (r + 55) : (r - 1);
        int kp = (s < 128) ? s : s - 128;
        float th = (float)((kp * a) & 127) * STEP;
        float cv = cosf(th), sv = sinf(th);
        M2cT[idx] = (r < 56) ? ((s < 128) ? cv : -sv) : ((s < 128) ? sv : cv);
        return;
    }
    idx -= 28672;
    if (idx < 7616) { // RT2cT[b*136+col], w/L^2 folded
        int b = idx / 136, col = idx % 136;
        float val = 0.f;
        if (col < 65 || (col >= 68 && col < 133)) {
            int kq = (col < 65) ? col : col - 68;
            float w = (kq == 0 || kq == 64) ? 1.f : 2.f;
            float th = (float)((kq * (b + 55)) & 127) * STEP;
            val = ((col < 65) ? cosf(th) : -sinf(th)) * w * (1.f / 16384.f);
        }
        RT2cT[idx] = val;
    }
}

// =====================================================================
// bf16 hi/lo MFMA constants (derived from fp32 consts; run after consts_k)
// =====================================================================
__global__ void consts2_k(const float* __restrict__ MvT, const float* __restrict__ M2cT,
                          const float* __restrict__ RT2cT,
                          unsigned short* RTcAh, unsigned short* RTcAl,
                          unsigned short* MvAh, unsigned short* MvAl,
                          unsigned short* M2Ah, unsigned short* M2Al,
                          unsigned short* RT2Bh, unsigned short* RT2Bl) {
    int idx = blockIdx.x * 256 + threadIdx.x;
    const float STEP = 0.049087385212340526f;
    float v = 0.f; unsigned short *ph, *pl; int off;
    if (idx < 8320) {               // RTcA [130 rows (65 re | 65 im)][64]
        int row = idx >> 6, q = idx & 63;
        if (q < 56) {
            int kq = (row < 65) ? row : row - 65;
            float th = (float)((kq * q) & 127) * STEP;
            v = (row < 65) ? cosf(th) : -sinf(th);
        }
        ph = RTcAh; pl = RTcAl; off = idx;
    } else if (idx < 41088) {       // MvA [256][128] (cols 112..127 zero)
        int i = idx - 8320; int r = i >> 7, s = i & 127;
        if (s < 112) v = MvT[s * 256 + r];
        ph = MvAh; pl = MvAl; off = i;
    } else if (idx < 69760) {       // M2A [112][256]
        int i = idx - 41088; int a = i >> 8, r = i & 255;
        v = M2cT[r * 112 + a];
        ph = M2Ah; pl = M2Al; off = i;
    } else if (idx < 78976) {       // RT2B [64][144]: 0..64 re | 72..136 im
        int i = idx - 69760; int bq = i / 144, col = i % 144;
        if (bq < 56) {
            if (col < 65) v = RT2cT[bq * 136 + col];
            else if (col >= 72 && col < 137) v = RT2cT[bq * 136 + 68 + (col - 72)];
        }
        ph = RT2Bh; pl = RT2Bl; off = i;
    } else return;
    unsigned short h = f2bf(v);
    ph[off] = h;
    pl[off] = f2bf(v - bf2f(h));
}

// =====================================================================
// row L2 norms -> inverse simple-rms scale, D=512
// =====================================================================
__global__ void norms_k(const float* __restrict__ X, float* __restrict__ out, int rows) {
    int row = blockIdx.x * 4 + (threadIdx.x >> 6);
    int lane = threadIdx.x & 63;
    if (row >= rows) return;
    const float* p = X + (size_t)row * 512;
    float s = 0.f;
    #pragma unroll
    for (int i = 0; i < 8; ++i) { float v = p[lane + 64 * i]; s += v * v; }
    #pragma unroll
    for (int o = 32; o > 0; o >>= 1) s += __shfl_down(s, o, 64);
    if (lane == 0) out[row] = 1.f / (sqrtf(s) * 0.04419417382415922f + 1e-8f);
}

__global__ void t0_k(const float* __restrict__ w, const float* __restrict__ b, float* __restrict__ out) {
    int idx = blockIdx.x * 256 + threadIdx.x;
    if (idx >= GROWS * 512) return;
    int r = idx >> 9, c = idx & 511;
    int i = r / 111, j = r % 111;
    float dp = (float)(i - 55), dq = (float)(j - 55);
    out[idx] = dp * w[c * 2] + dq * w[c * 2 + 1] + b[c];
}

__global__ void convw_k(const float* __restrict__ src, unsigned short* __restrict__ dst, int n) {
    int i = blockIdx.x * 256 + threadIdx.x;
    if (i < n) dst[i] = f2bf(src[i]);
}
__global__ void convt_k(const float* __restrict__ t, const float* __restrict__ sinv,
                        unsigned short* __restrict__ dst) {
    int i = blockIdx.x * 256 + threadIdx.x;
    if (i >= GROWS * 512) return;
    int r = i >> 9;
    dst[i] = f2bf(fmaxf(t[i], 0.f) * sinv[r]);
}

// =====================================================================
// xn16 = bf16(x * ninv) precompute — identical value to amode-0 staging
// =====================================================================
__global__ void convx_k(const float* __restrict__ x, const float* __restrict__ ninv,
                        unsigned short* __restrict__ xn) {
    int i = blockIdx.x * 256 + threadIdx.x;      // 25088*64 = 1,605,632 exact
    if (i >= ROWS * 64) return;
    int r = i >> 6, c8 = (i & 63) << 3;
    float s = ninv[r];
    const float* p = x + (size_t)r * 512 + c8;
    float4 f1 = *(const float4*)p, f2 = *(const float4*)(p + 4);
    us8_t o;
    o[0] = f2bf(f1.x * s); o[1] = f2bf(f1.y * s);
    o[2] = f2bf(f1.z * s); o[3] = f2bf(f1.w * s);
    o[4] = f2bf(f2.x * s); o[5] = f2bf(f2.y * s);
    o[6] = f2bf(f2.z * s); o[7] = f2bf(f2.w * s);
    *(us8_t*)(xn + (size_t)i * 8) = o;
}

// wuv[h*256 + j][k]: j<128 -> W_u row h*128+j; else W_v row h*128+j-128.
__global__ void convuv_k(const float* __restrict__ Wu, const float* __restrict__ Wv,
                         const float* __restrict__ bu, const float* __restrict__ bv,
                         unsigned short* __restrict__ wuv, float* __restrict__ buv) {
    int i = blockIdx.x * 256 + threadIdx.x;      // 1,048,576 exact -> 4096 blocks
    if (i < 1048576) {
        int row = i >> 9, k = i & 511;
        int h = row >> 8, j = row & 255;
        float v = (j < 128) ? Wu[(size_t)(h * 128 + j) * 512 + k]
                            : Wv[(size_t)(h * 128 + j - 128) * 512 + k];
        wuv[i] = f2bf(v);
    }
    if (i < 2048) {
        int h = i >> 8, j = i & 255;
        buv[i] = (j < 128) ? bu[h * 128 + j] : bv[h * 128 + j - 128];
    }
}

// =====================================================================
// bf16 MFMA GEMM (verified fragment pattern), epilogue/amode variants
//  amode 0: A fp32 rm -> relu?*scale -> bf16 ; amode 1: A bf16 rm
//  amode 2: A = bf16(u*y gather) — legacy
//  emode 0: fp32 rm +bias ; emode 2: bf16 rm +bias+silu
//  emode 3: out accum (+bias+xres if first) ; emode 4: bf16 cm +bias+silu
//  emode 5: split u|v one head: c<128 -> u16 rm +silu; c>=128 -> vcm cm (via yv)
//  emode 6: split u|v ALL heads (N=2048): h=c>>8, j=c&255;
//           j<128 -> uyf[r*1024+h*128+j]; j>=128 -> vcmA[(h*1024+bb*128+j-128)*POS+pos]
// =====================================================================
__global__ __launch_bounds__(256) void mgemm_k(
    const void* __restrict__ Aptr, const unsigned short* __restrict__ B, int ldb,
    const unsigned short* __restrict__ yv, const float* __restrict__ scale,
    int relu_in, int amode,
    void* __restrict__ Cptr, const float* __restrict__ bias,
    const float* __restrict__ xres, float* __restrict__ outAcc, int first,
    int emode, int M, int N, int K)
{
    __shared__ __align__(16) unsigned short As[4096];
    __shared__ __align__(16) unsigned short Bs[4096];
    const int t = threadIdx.x;
    const int lane = t & 63;
    const int quad = lane >> 4, ln = lane & 15;
    const int wave = t >> 6;
    const int wm = (wave >> 1) << 6, wn = (wave & 1) << 6;
    const int row0 = blockIdx.y << 7, col0 = blockIdx.x << 7;
    const int sc = t & 3;
    const int sm = t >> 2;
    const float* Af = (const float*)Aptr;
    const unsigned short* Au = (const unsigned short*)Aptr;
    f4_t acc[4][4];
    #pragma unroll
    for (int i = 0; i < 4; ++i)
        #pragma unroll
        for (int j = 0; j < 4; ++j)
            acc[i][j] = (f4_t){0.f, 0.f, 0.f, 0.f};

    for (int k0 = 0; k0 < K; k0 += 32) {
        #pragma unroll
        for (int rep = 0; rep < 2; ++rep) {
            const int m = sm + (rep << 6);
            const int am = row0 + m;
            us8_t av = {0, 0, 0, 0, 0, 0, 0, 0};
            if (am < M) {
                if (amode == 0) {
                    const float s = scale ? scale[am] : 1.f;
                    const float* ap = Af + (size_t)am * K + k0 + (sc << 3);
                    float4 f1 = *(const float4*)ap;
                    float4 f2 = *(const float4*)(ap + 4);
                    if (relu_in) {
                        f1.x = fmaxf(f1.x, 0.f); f1.y = fmaxf(f1.y, 0.f);
                        f1.z = fmaxf(f1.z, 0.f); f1.w = fmaxf(f1.w, 0.f);
                        f2.x = fmaxf(f2.x, 0.f); f2.y = fmaxf(f2.y, 0.f);
                        f2.z = fmaxf(f2.z, 0.f); f2.w = fmaxf(f2.w, 0.f);
                    }
                    av[0] = f2bf(f1.x * s); av[1] = f2bf(f1.y * s);
                    av[2] = f2bf(f1.z * s); av[3] = f2bf(f1.w * s);
                    av[4] = f2bf(f2.x * s); av[5] = f2bf(f2.y * s);
                    av[6] = f2bf(f2.z * s); av[7] = f2bf(f2.w * s);
                } else if (amode == 1) {
                    av = *(const us8_t*)(Au + (size_t)am * K + k0 + (sc << 3));
                } else {
                    const unsigned short* up = Au + (size_t)am * K + k0 + (sc << 3);
                    const int bb = am / POS, pos = am - bb * POS;
                    const unsigned short* yb = yv + ((size_t)(bb * 128 + k0 + (sc << 3))) * POS + pos;
                    #pragma unroll
                    for (int j = 0; j < 8; ++j)
                        av[j] = f2bf(bf2f(up[j]) * bf2f(yb[(size_t)j * POS]));
                }
            }
            *(us8_t*)&As[(sc << 10) + (m << 3)] = av;
        }
        #pragma unroll
        for (int rep = 0; rep < 2; ++rep) {
            const int n = sm + (rep << 6);
            us8_t bv = *(const us8_t*)(B + (size_t)(col0 + n) * ldb + k0 + (sc << 3));
            *(us8_t*)&Bs[(sc << 10) + (n << 3)] = bv;
        }
        __syncthreads();
        bf8_t af[4], bfr[4];
        #pragma unroll
        for (int i = 0; i < 4; ++i)
            af[i] = *(const bf8_t*)&As[(quad << 10) + ((wm + (i << 4) + ln) << 3)];
        #pragma unroll
        for (int i = 0; i < 4; ++i)
            bfr[i] = *(const bf8_t*)&Bs[(quad << 10) + ((wn + (i << 4) + ln) << 3)];
        #pragma unroll
        for (int i = 0; i < 4; ++i)
            #pragma unroll
            for (int j = 0; j < 4; ++j)
                acc[i][j] = __builtin_amdgcn_mfma_f32_16x16x32_bf16(af[i], bfr[j], acc[i][j], 0, 0, 0);
        __syncthreads();
    }
    #pragma unroll
    for (int i = 0; i < 4; ++i) {
        #pragma unroll
        for (int j = 0; j < 4; ++j) {
            #pragma unroll
            for (int rr = 0; rr < 4; ++rr) {
                const int r = row0 + wm + (i << 4) + (quad << 2) + rr;
                const int c = col0 + wn + (j << 4) + ln;
                if (r >= M) continue;
                float v = acc[i][j][rr];
                if (emode == 0) {
                    v += bias[c];
                    ((float*)Cptr)[(size_t)r * N + c] = v;
                } else if (emode == 2) {
                    v += bias[c]; v = v / (1.f + expf(-v));
                    ((unsigned short*)Cptr)[(size_t)r * N + c] = f2bf(v);
                } else if (emode == 4) {
                    v += bias[c]; v = v / (1.f + expf(-v));
                    const int bb = r / POS, pos = r - bb * POS;
                    ((unsigned short*)Cptr)[((size_t)(bb * 128 + c)) * POS + pos] = f2bf(v);
                } else if (emode == 5) {
                    v += bias[c]; v = v / (1.f + expf(-v));
                    unsigned short bv16 = f2bf(v);
                    if (c < 128) {
                        ((unsigned short*)Cptr)[(size_t)r * 128 + c] = bv16;
                    } else {
                        const int bb = r / POS, pos = r - bb * POS;
                        ((unsigned short*)yv)[((size_t)(bb * 128 + (c - 128))) * POS + pos] = bv16;
                    }
                } else if (emode == 6) {
                    v += bias[c]; v = v / (1.f + expf(-v));
                    unsigned short bv16 = f2bf(v);
                    const int hh = c >> 8, j2 = c & 255;
                    if (j2 < 128) {
                        ((unsigned short*)Cptr)[(size_t)r * 1024 + hh * 128 + j2] = bv16;
                    } else {
                        const int bb = r / POS, pos = r - bb * POS;
                        ((unsigned short*)yv)[((size_t)(hh * 1024 + bb * 128 + (j2 - 128))) * POS + pos] = bv16;
                    }
                } else {
                    const size_t oi = (size_t)r * 512 + c;
                    v += first ? (bias[c] + xres[oi]) : outAcc[oi];
                    outAcc[oi] = v;
                }
            }
        }
    }
}

// =====================================================================
// fused transpose + bf16 hi/lo split (head-batched via blockIdx.z)
// =====================================================================
__global__ void gtr_k(const float* __restrict__ src, int ld,
                      unsigned short* __restrict__ Gh, unsigned short* __restrict__ Gl) {
    __shared__ float tile[32][33];
    const int z = blockIdx.z;
    src += (size_t)z * 128;
    Gh += (size_t)z * GH_STRIDE_US;
    Gl += (size_t)z * GH_STRIDE_US;
    int s0 = blockIdx.x * 32, d0 = blockIdx.y * 32;
    int tx = threadIdx.x, ty = threadIdx.y;
    #pragma unroll
    for (int i = 0; i < 32; i += 8) {
        int s = s0 + ty + i;
        if (s < GROWS) tile[ty + i][tx] = src[(size_t)s * ld + d0 + tx];
    }
    __syncthreads();
    int s = s0 + tx;
    if (s < GROWS) {
        int p = s / 111, q = s - p * 111;
        #pragma unroll
        for (int i = 0; i < 32; i += 8) {
            int d = d0 + ty + i;
            float v = tile[tx][ty + i];
            unsigned short h = f2bf(v);
            size_t o = (size_t)(d * 111 + p) * 128 + q;
            Gh[o] = h;
            Gl[o] = f2bf(v - bf2f(h));
        }
    }
}

// zero GEMM pad slots for nh heads (head-strided)
__global__ void pads_k(unsigned short* __restrict__ Gh, unsigned short* __restrict__ Gl,
                       unsigned short* __restrict__ TgFh, unsigned short* __restrict__ TgFl,
                       int nh) {
    int i = blockIdx.x * 256 + threadIdx.x;
    if (i < nh * 16640) {
        int h = i / 16640, r = i % 16640;
        size_t o = (size_t)h * TGF_STRIDE_US + (size_t)r * 112 + 111;
        TgFh[o] = 0; TgFl[o] = 0;
    }
    if (i < nh * 241536) {
        int h = i / 241536, j = i % 241536;
        int r = j / 17, c = 111 + j % 17;
        size_t o = (size_t)h * GH_STRIDE_US + (size_t)r * 128 + c;
        Gh[o] = 0; Gl[o] = 0;
    }
}

// =====================================================================
// fuse u *= y  (in place on u16) — fallback path.
// =====================================================================
__global__ void fusey_k(unsigned short* __restrict__ u, const unsigned short* __restrict__ y) {
    __shared__ unsigned short yt[32][34];
    const int pos0 = blockIdx.x * 32, k0 = blockIdx.y * 32, bb = blockIdx.z;
    const int tx = threadIdx.x, ty = threadIdx.y;
    #pragma unroll
    for (int i = 0; i < 32; i += 8) {
        int k = k0 + ty + i;
        yt[ty + i][tx] = y[((size_t)(bb * 128 + k)) * POS + pos0 + tx];
    }
    __syncthreads();
    #pragma unroll
    for (int i = 0; i < 32; i += 8) {
        size_t r = (size_t)bb * POS + pos0 + ty + i;
        size_t idx = r * 128 + k0 + tx;
        u[idx] = f2bf(bf2f(u[idx]) * bf2f(yt[tx][ty + i]));
    }
}

// =====================================================================
// fuse u*y -> uyf[r][h*128+k]  (per-head, fallback ext2 path).
// =====================================================================
__global__ void fusey2_k(const unsigned short* __restrict__ u, const unsigned short* __restrict__ y,
                         unsigned short* __restrict__ uyf, int h) {
    __shared__ unsigned short yt[32][34];
    const int pos0 = blockIdx.x * 32, k0 = blockIdx.y * 32, bb = blockIdx.z;
    const int tx = threadIdx.x, ty = threadIdx.y;
    #pragma unroll
    for (int i = 0; i < 32; i += 8) {
        int k = k0 + ty + i;
        yt[ty + i][tx] = y[((size_t)(bb * 128 + k)) * POS + pos0 + tx];
    }
    __syncthreads();
    #pragma unroll
    for (int i = 0; i < 32; i += 8) {
        size_t r = (size_t)bb * POS + pos0 + ty + i;
        unsigned short uv = u[r * 128 + k0 + tx];
        uyf[r * 1024 + h * 128 + k0 + tx] = f2bf(bf2f(uv) * bf2f(yt[tx][ty + i]));
    }
}

// =====================================================================
// batched fuse (ext4): uyf[r][h*128+k] *= y from vcmA[h][bb*128+k][pos].
// z = h*8 + bb. u was pre-stored in uyf by the emode-6 uv GEMM.
// =====================================================================
__global__ void fusey3_k(unsigned short* __restrict__ uyf, const unsigned short* __restrict__ vcmA) {
    __shared__ unsigned short yt[32][34];
    const int pos0 = blockIdx.x * 32, k0 = blockIdx.y * 32;
    const int z = blockIdx.z;
    const int h = z >> 3, bb = z & 7;
    const unsigned short* y = vcmA + (size_t)h * VCMA_HS;
    const int tx = threadIdx.x, ty = threadIdx.y;
    #pragma unroll
    for (int i = 0; i < 32; i += 8) {
        int k = k0 + ty + i;
        yt[ty + i][tx] = y[((size_t)(bb * 128 + k)) * POS + pos0 + tx];
    }
    __syncthreads();
    #pragma unroll
    for (int i = 0; i < 32; i += 8) {
        size_t r = (size_t)bb * POS + pos0 + ty + i;
        size_t idx = r * 1024 + h * 128 + k0 + tx;
        uyf[idx] = f2bf(bf2f(uyf[idx]) * bf2f(yt[tx][ty + i]));
    }
}

// =====================================================================
// hi/lo bf16 GEMM (3-product). Head-batched via blockIdx.z (zD/zC strides).
// =====================================================================
__device__ inline float cval(const float* __restrict__ Csrc, int cmode, int row, int kk) {
    if (cmode == 0)
        return (kk < 111 && row < 130) ? Csrc[kk * 130 + row] : 0.f;
    int s = (kk < 112) ? kk : (111 + (kk - 112));
    bool ok = (kk < 112) ? (kk < 111) : (kk < 223);
    return ok ? Csrc[(size_t)row * 222 + s] : 0.f;
}

__global__ __launch_bounds__(256) void hilo_gemm_k(
    const unsigned short* __restrict__ Dh, const unsigned short* __restrict__ Dl,
    const float* __restrict__ Csrc, int cmode, int constIsA,
    unsigned short* __restrict__ C0, unsigned short* __restrict__ C1,
    int omode, int K, unsigned zD, unsigned zC)
{
    __shared__ __align__(16) unsigned short Ash[4096];
    __shared__ __align__(16) unsigned short Asl[4096];
    __shared__ __align__(16) unsigned short Bsh[4096];
    __shared__ __align__(16) unsigned short Bsl[4096];
    const int t = threadIdx.x;
    const int lane = t & 63;
    const int quad = lane >> 4, ln = lane & 15;
    const int wave = t >> 6;
    const int wm = (wave >> 1) << 6, wn = (wave & 1) << 6;
    const int row0 = blockIdx.y << 7, col0 = blockIdx.x << 7;
    const int sc = t & 3, sm = t >> 2;
    const size_t zoffD = (size_t)blockIdx.z * zD, zoffC = (size_t)blockIdx.z * zC;
    Dh += zoffD; Dl += zoffD;
    C0 += zoffC; if (C1) C1 += zoffC;
    f4_t acc[4][4];
    #pragma unroll
    for (int i = 0; i < 4; ++i)
        #pragma unroll
        for (int j = 0; j < 4; ++j)
            acc[i][j] = (f4_t){0.f, 0.f, 0.f, 0.f};

    for (int k0 = 0; k0 < K; k0 += 32) {
        #pragma unroll
        for (int rep = 0; rep < 2; ++rep) {
            const int m = sm + (rep << 6);
            // ---- A tile ----
            {
                const int gr = row0 + m;
                us8_t hv, lv;
                if (constIsA) {
                    #pragma unroll
                    for (int j = 0; j < 8; ++j) {
                        int kk = k0 + (sc << 3) + j;
                        float v = cval(Csrc, cmode, gr, kk);
                        unsigned short h = f2bf(v);
                        hv[j] = h; lv[j] = f2bf(v - bf2f(h));
                    }
                } else {
                    hv = *(const us8_t*)(Dh + (size_t)gr * K + k0 + (sc << 3));
                    lv = *(const us8_t*)(Dl + (size_t)gr * K + k0 + (sc << 3));
                }
                *(us8_t*)&Ash[(sc << 10) + (m << 3)] = hv;
                *(us8_t*)&Asl[(sc << 10) + (m << 3)] = lv;
            }
            // ---- B tile ----
            {
                const int gc = col0 + m;
                us8_t hv, lv;
                if (constIsA) {
                    hv = *(const us8_t*)(Dh + (size_t)gc * K + k0 + (sc << 3));
                    lv = *(const us8_t*)(Dl + (size_t)gc * K + k0 + (sc << 3));
                } else {
                    #pragma unroll
                    for (int j = 0; j < 8; ++j) {
                        int kk = k0 + (sc << 3) + j;
                        float v = cval(Csrc, cmode, gc, kk);
                        unsigned short h = f2bf(v);
                        hv[j] = h; lv[j] = f2bf(v - bf2f(h));
                    }
                }
                *(us8_t*)&Bsh[(sc << 10) + (m << 3)] = hv;
                *(us8_t*)&Bsl[(sc << 10) + (m << 3)] = lv;
            }
        }
        __syncthreads();
        bf8_t ah[4], al[4], bh[4], bl[4];
        #pragma unroll
        for (int i = 0; i < 4; ++i) {
            ah[i] = *(const bf8_t*)&Ash[(quad << 10) + ((wm + (i << 4) + ln) << 3)];
            al[i] = *(const bf8_t*)&Asl[(quad << 10) + ((wm + (i << 4) + ln) << 3)];
            bh[i] = *(const bf8_t*)&Bsh[(quad << 10) + ((wn + (i << 4) + ln) << 3)];
            bl[i] = *(const bf8_t*)&Bsl[(quad << 10) + ((wn + (i << 4) + ln) << 3)];
        }
        #pragma unroll
        for (int i = 0; i < 4; ++i)
            #pragma unroll
            for (int j = 0; j < 4; ++j) {
                acc[i][j] = __builtin_amdgcn_mfma_f32_16x16x32_bf16(ah[i], bh[j], acc[i][j], 0, 0, 0);
                acc[i][j] = __builtin_amdgcn_mfma_f32_16x16x32_bf16(ah[i], bl[j], acc[i][j], 0, 0, 0);
                acc[i][j] = __builtin_amdgcn_mfma_f32_16x16x32_bf16(al[i], bh[j], acc[i][j], 0, 0, 0);
            }
        __syncthreads();
    }
    #pragma unroll
    for (int i = 0; i < 4; ++i) {
        #pragma unroll
        for (int j = 0; j < 4; ++j) {
            #pragma unroll
            for (int rr = 0; rr < 4; ++rr) {
                const int r = row0 + wm + (i << 4) + (quad << 2) + rr;
                const int c = col0 + wn + (j << 4) + ln;
                float v = acc[i][j][rr];
                if (omode == 1) {
                    C0[(size_t)r * 256 + c] = f2bf(v);
                } else {
                    if (r < 130) {
                        int kq = (r < 65) ? r : r - 65;
                        int im = (r < 65) ? 0 : 1;
                        int d = c / 111, p = c - d * 111;
                        size_t o = ((size_t)((d * 65 + kq) * 2 + im)) * 112 + p;
                        unsigned short h = f2bf(v);
                        C0[o] = h;
                        C1[o] = f2bf(v - bf2f(h));
                    }
                }
            }
        }
    }
}

// =====================================================================
// v conv (bf16, in place): MFMA DFT stages per channel workgroup.
// Round-0 body (VGPR 88, 2 blocks/CU, no spill). Head-batched via
// blockIdx.x>>10 with strides vcmHS/ghatHS (0 strides + grid 1024 =
// single-head). Body untouched — all restructurings regressed (r2/r3/r8).
// =====================================================================
__global__ __launch_bounds__(512) void vfft_k(
    unsigned short* __restrict__ vcm, const unsigned short* __restrict__ Ghat,
    const unsigned short* __restrict__ RTcAh, const unsigned short* __restrict__ RTcAl,
    const unsigned short* __restrict__ MvAh,  const unsigned short* __restrict__ MvAl,
    const unsigned short* __restrict__ M2Ah,  const unsigned short* __restrict__ M2Al,
    const unsigned short* __restrict__ RT2Bh, const unsigned short* __restrict__ RT2Bl,
    const float* __restrict__ MvT, const float* __restrict__ M2cT,
    const float* __restrict__ RT2cT, unsigned vcmHS, unsigned ghatHS)
{
    __shared__ __align__(16) unsigned short Vs[64 * 72];    // [p][q] bf16, zero-pad
    __shared__ __align__(16) unsigned short TqT[32 * 136];  // [kqL][s(112)+pad]
    __shared__ __align__(16) unsigned short VhT[32 * 264];  // [kqL][r(256)+pad]
    __shared__ __align__(16) unsigned short QA[64 * 72];    // [p][k(64)+pad]
    __shared__ float tmp[424];                              // Nyquist temps
    const int tid = threadIdx.x;
    const int lane = tid & 63, wave = tid >> 6;
    const int quad = lane >> 4, ln = lane & 15;
    const int zz = blockIdx.x >> 10;
    const int bid = blockIdx.x & 1023;
    const int d = bid >> 3, b = bid & 7;
    unsigned short* chan = vcm + (size_t)zz * vcmHS + (size_t)(b * 128 + d) * POS;
    const unsigned short* ghd = Ghat + (size_t)zz * ghatHS + (size_t)d * FREQ;

    for (int i = tid; i < 64 * 72; i += 512) { Vs[i] = 0; QA[i] = 0; }
    {   // TqT K-pad cols 112..127 zero (rows 0..31)
        int rr = tid >> 4, cc = 112 + (tid & 15);
        if (tid < 512) TqT[rr * 136 + cc] = 0;
    }
    __syncthreads();
    for (int i = tid; i < POS; i += 512) {
        int p = i / 56, q = i - p * 56;
        Vs[p * 72 + q] = chan[i];
    }
    f4_t acc5[2] = { (f4_t){0,0,0,0}, (f4_t){0,0,0,0} };
    __syncthreads();

    // ===== Nyquist kq=64 tail (fp32 VALU, tiny) =====
    if (tid < 56) {
        const unsigned short* vp = Vs + tid * 72;
        float a = 0.f;
        for (int q = 0; q < 56; q += 2) a += bf2f(vp[q]) - bf2f(vp[q + 1]);
        tmp[tid] = a;
    }
    __syncthreads();
    if (tid < 256) {
        float a = 0.f;
        for (int s = 0; s < 56; ++s) a = fmaf(MvT[s * 256 + tid], tmp[s], a);
        tmp[56 + tid] = a;
    }
    __syncthreads();
    if (tid < 128) {
        float vr = tmp[56 + tid], vi = tmp[184 + tid];
        float gr = bf2f(ghd[64 * 256 + tid]), gm = bf2f(ghd[64 * 256 + 128 + tid]);
        tmp[56 + tid] = vr * gr - vi * gm;
        tmp[184 + tid] = vr * gm + vi * gr;
    }
    __syncthreads();
    if (tid < 112) {
        float a = 0.f;
        for (int r = 0; r < 256; ++r) a = fmaf(M2cT[r * 112 + tid], tmp[56 + r], a);
        tmp[312 + tid] = a;
    }
    __syncthreads();
    #pragma unroll
    for (int ti = 0; ti < 2; ++ti) {
        int t = wave * 2 + ti, mt = t >> 2, nt = t & 3;
        int bq = nt * 16 + ln;
        if (bq < 56) {
            float r1 = RT2cT[bq * 136 + 64], r2 = RT2cT[bq * 136 + 132];
            #pragma unroll
            for (int rr = 0; rr < 4; ++rr) {
                int p = mt * 16 + quad * 4 + rr;
                if (p < 56) acc5[ti][rr] += tmp[312 + p] * r1 + tmp[368 + p] * r2;
            }
        }
    }

    // ===== main chunks kq0 = 0, 32 =====
    for (int ck = 0; ck < 2; ++ck) {
        const int kq0 = ck * 32;
        __syncthreads();
        // ---- S1: D[c'][p] = RTcA[c'][q] . Vs[p][q], K=64 ----
        #pragma unroll
        for (int ti = 0; ti < 2; ++ti) {
            int t = wave * 2 + ti, mt = t >> 2, nt = t & 3;
            int m = mt * 16 + ln;
            int arow = (m >> 5) * 65 + kq0 + (m & 31);
            int pcol = nt * 16 + ln;
            f4_t a = (f4_t){0, 0, 0, 0};
            #pragma unroll
            for (int ks = 0; ks < 2; ++ks) {
                int k0 = ks * 32 + quad * 8;
                bf8_t Ah = *(const bf8_t*)(RTcAh + arow * 64 + k0);
                bf8_t Al = *(const bf8_t*)(RTcAl + arow * 64 + k0);
                bf8_t Bv = *(const bf8_t*)&Vs[pcol * 72 + k0];
                a = __builtin_amdgcn_mfma_f32_16x16x32_bf16(Ah, Bv, a, 0, 0, 0);
                a = __builtin_amdgcn_mfma_f32_16x16x32_bf16(Al, Bv, a, 0, 0, 0);
            }
            if (pcol < 56) {
                #pragma unroll
                for (int rr = 0; rr < 4; ++rr) {
                    int cp = mt * 16 + quad * 4 + rr;
                    TqT[(cp & 31) * 136 + (cp >> 5) * 56 + pcol] = f2bf(a[rr]);
                }
            }
        }
        __syncthreads();
        // ---- S2: D[r][c] = MvA[r][s] . TqT[c][s], K=128 ----
        #pragma unroll
        for (int ti = 0; ti < 4; ++ti) {
            int t = wave * 4 + ti, mt = t >> 1, nt = t & 1;
            int r = mt * 16 + ln, c = nt * 16 + ln;
            f4_t a = (f4_t){0, 0, 0, 0};
            #pragma unroll
            for (int ks = 0; ks < 4; ++ks) {
                int k0 = ks * 32 + quad * 8;
                bf8_t Ah = *(const bf8_t*)(MvAh + r * 128 + k0);
                bf8_t Al = *(const bf8_t*)(MvAl + r * 128 + k0);
                bf8_t Bv = *(const bf8_t*)&TqT[c * 136 + k0];
                a = __builtin_amdgcn_mfma_f32_16x16x32_bf16(Ah, Bv, a, 0, 0, 0);
                a = __builtin_amdgcn_mfma_f32_16x16x32_bf16(Al, Bv, a, 0, 0, 0);
            }
            int r0 = mt * 16 + quad * 4;
            ushort4 st;
            st.x = f2bf(a[0]); st.y = f2bf(a[1]); st.z = f2bf(a[2]); st.w = f2bf(a[3]);
            *(ushort4*)&VhT[c * 264 + r0] = st;
        }
        __syncthreads();
        // ---- S3: complex multiply with Ghat ----
        #pragma unroll
        for (int i = 0; i < 8; ++i) {
            int o = tid + 512 * i;
            int c = o >> 7, kp = o & 127;
            float vr = bf2f(VhT[c * 264 + kp]), vi = bf2f(VhT[c * 264 + 128 + kp]);
            int gi = (kq0 + c) * 256 + kp;
            float gr = bf2f(ghd[gi]), gm = bf2f(ghd[gi + 128]);
            VhT[c * 264 + kp] = f2bf(vr * gr - vi * gm);
            VhT[c * 264 + 128 + kp] = f2bf(vr * gm + vi * gr);
        }
        __syncthreads();
        // ---- S4: D[a][c] = M2A[a][r] . VhT[c][r], K=256 ----
        #pragma unroll
        for (int ti = 0; ti < 2; ++ti) {
            int t = wave * 2 + ti;
            if (t < 14) {
                int mt = t >> 1, nt = t & 1;
                int aa = mt * 16 + ln, c = nt * 16 + ln;
                f4_t a = (f4_t){0, 0, 0, 0};
                #pragma unroll
                for (int ks = 0; ks < 8; ++ks) {
                    int k0 = ks * 32 + quad * 8;
                    bf8_t Ah = *(const bf8_t*)(M2Ah + aa * 256 + k0);
                    bf8_t Al = *(const bf8_t*)(M2Al + aa * 256 + k0);
                    bf8_t Bv = *(const bf8_t*)&VhT[c * 264 + k0];
                    a = __builtin_amdgcn_mfma_f32_16x16x32_bf16(Ah, Bv, a, 0, 0, 0);
                    a = __builtin_amdgcn_mfma_f32_16x16x32_bf16(Al, Bv, a, 0, 0, 0);
                }
                #pragma unroll
                for (int rr = 0; rr < 4; ++rr) {
                    int av_ = mt * 16 + quad * 4 + rr;
                    int p = (av_ < 56) ? av_ : av_ - 56;
                    int reg = (av_ < 56) ? 0 : 32;
                    QA[p * 72 + reg + c] = f2bf(a[rr]);
                }
            }
        }
        __syncthreads();
        // ---- S5: acc[p][bq] += QA[p][k] . RT2B[bq][k], K=64 ----
        #pragma unroll
        for (int ti = 0; ti < 2; ++ti) {
            int t = wave * 2 + ti, mt = t >> 2, nt = t & 3;
            int p = mt * 16 + ln, bq = nt * 16 + ln;
            #pragma unroll
            for (int ks = 0; ks < 2; ++ks) {
                int k0 = ks * 32 + quad * 8;
                bf8_t Aq = *(const bf8_t*)&QA[p * 72 + k0];
                int col = (ks ? 72 : 0) + kq0 + quad * 8;
                bf8_t Bh = *(const bf8_t*)(RT2Bh + bq * 144 + col);
                bf8_t Bl = *(const bf8_t*)(RT2Bl + bq * 144 + col);
                acc5[ti] = __builtin_amdgcn_mfma_f32_16x16x32_bf16(Aq, Bh, acc5[ti], 0, 0, 0);
                acc5[ti] = __builtin_amdgcn_mfma_f32_16x16x32_bf16(Aq, Bl, acc5[ti], 0, 0, 0);
            }
        }
    }
    // ===== store y (bf16, in place) =====
    #pragma unroll
    for (int ti = 0; ti < 2; ++ti) {
        int t = wave * 2 + ti, mt = t >> 2, nt = t & 3;
        int bq = nt * 16 + ln;
        if (bq < 56) {
            #pragma unroll
            for (int rr = 0; rr < 4; ++rr) {
                int p = mt * 16 + quad * 4 + rr;
                if (p < 56) chan[p * 56 + bq] = f2bf(acc5[ti][rr]);
            }
        }
    }
}

// =====================================================================
extern "C" void kernel_launch(void* const* d_in, const int* in_sizes, int n_in,
                              void* d_out, int out_size, void* d_ws, size_t ws_size,
                              hipStream_t stream) {
    (void)in_sizes; (void)n_in; (void)out_size;
    const float* x         = (const float*)d_in[0];
    const float* W_u       = (const float*)d_in[1];
    const float* b_u       = (const float*)d_in[2];
    const float* W_v       = (const float*)d_in[3];
    const float* b_v       = (const float*)d_in[4];
    const float* W_o       = (const float*)d_in[5];
    const float* b_o       = (const float*)d_in[6];
    const float* rpe_in_w  = (const float*)d_in[7];
    const float* rpe_in_b  = (const float*)d_in[8];
    const float* rpe_h_w   = (const float*)d_in[9];
    const float* rpe_h_b   = (const float*)d_in[10];
    const float* rpe_out_w = (const float*)d_in[11];
    const float* rpe_out_b = (const float*)d_in[12];
    float* out = (float*)d_out;

    if (ws_size < (size_t)WS_FLOATS * 4) {
        probe_k<<<1, 1, 0, stream>>>(out, 1000.0f + (float)((double)ws_size * 1e-6));
        return;
    }
    const bool ext  = ws_size >= (size_t)WS_EXT * 4;
    const bool ext2 = ws_size >= (size_t)WS_EXT2 * 4;
    const bool ext3 = ws_size >= (size_t)WS_EXT3 * 4;
    const bool ext4 = ws_size >= (size_t)WS_EXT4 * 4;
    float* ws    = (float*)d_ws;
    float* MvT   = ws + OFF_MVT;
    float* M2cT  = ws + OFF_M2T;
    float* RT2cT = ws + OFF_RT2T;
    float* RTc   = ws + OFF_RTC;
    float* Mg    = ws + OFF_MG;
    unsigned short* RTcAh = (unsigned short*)(ws + OFF_RTCAH);
    unsigned short* RTcAl = (unsigned short*)(ws + OFF_RTCAL);
    unsigned short* MvAh  = (unsigned short*)(ws + OFF_MVAH);
    unsigned short* MvAl  = (unsigned short*)(ws + OFF_MVAL);
    unsigned short* M2Ah  = (unsigned short*)(ws + OFF_M2AH);
    unsigned short* M2Al  = (unsigned short*)(ws + OFF_M2AL);
    unsigned short* RT2Bh = (unsigned short*)(ws + OFF_RT2BH);
    unsigned short* RT2Bl = (unsigned short*)(ws + OFF_RT2BL);
    float* ninv  = ws + OFF_NINV;
    float* sinv  = ws + OFF_SINV;
    unsigned short* WB  = (unsigned short*)(ws + OFF_WB);
    unsigned short* wub = WB + WB_WU;
    unsigned short* wvb = WB + WB_WV;
    unsigned short* wob = WB + WB_WO;
    unsigned short* whb = WB + WB_WH;
    unsigned short* wrob= WB + WB_WRO;
    unsigned short* tb16= (unsigned short*)(ws + OFF_TB16);
    float* pool  = ws + OFF_POOL;
    unsigned short* Ghat16 = (unsigned short*)pool;
    unsigned short* u16    = (unsigned short*)(pool + POOL_U16);
    unsigned short* vcm16  = (unsigned short*)(pool + POOL_VCM);
    unsigned short* Gh   = (unsigned short*)(pool + POOL_GH);
    unsigned short* Gl   = (unsigned short*)(pool + POOL_GL);
    unsigned short* TgFh = (unsigned short*)(pool + POOL_TGFH);
    unsigned short* TgFl = (unsigned short*)(pool + POOL_TGFL);
    unsigned short* xn16 = (unsigned short*)(ws + OFF_XN16);
    unsigned short* wuv  = (unsigned short*)(ws + OFF_WUV);
    float* buv   = ws + OFF_BUV;
    unsigned short* uyf  = (unsigned short*)(ws + OFF_UYF);
    unsigned short* GhA   = (unsigned short*)(ws + OFF_GHA);
    unsigned short* GlA   = (unsigned short*)(ws + OFF_GLA);
    unsigned short* TgFhA = (unsigned short*)(ws + OFF_TGFHA);
    unsigned short* TgFlA = (unsigned short*)(ws + OFF_TGFLA);
    unsigned short* GhatA = (unsigned short*)(ws + OFF_GHATA); // aliases GhA/GlA
    unsigned short* vcmA  = (unsigned short*)(ws + OFF_VCMA);
    float* tA    = out;                // rpe fp32 ping-pong in d_out
    float* tBf   = out + 6308352u;
    float* g_row_all = out;            // [12321][1024] fp32 in d_out scratch

    consts_k<<<533, 256, 0, stream>>>(RTc, MvT, Mg, M2cT, RT2cT);
    consts2_k<<<309, 256, 0, stream>>>(MvT, M2cT, RT2cT, RTcAh, RTcAl,
                                       MvAh, MvAl, M2Ah, M2Al, RT2Bh, RT2Bl);

    // weights -> bf16
    if (ext) {
        convuv_k<<<4096, 256, 0, stream>>>(W_u, W_v, b_u, b_v, wuv, buv);
    } else {
        convw_k<<<2048, 256, 0, stream>>>(W_u, wub, 524288);
        convw_k<<<2048, 256, 0, stream>>>(W_v, wvb, 524288);
    }
    convw_k<<<2048, 256, 0, stream>>>(W_o, wob, 524288);
    convw_k<<<3072, 256, 0, stream>>>(rpe_h_w, whb, 786432);
    convw_k<<<2048, 256, 0, stream>>>(rpe_out_w, wrob, 524288);

    // ---- RPE MLP hidden ladder ----
    t0_k<<<24642, 256, 0, stream>>>(rpe_in_w, rpe_in_b, tA);
    norms_k<<<3081, 256, 0, stream>>>(tA, sinv, GROWS);
    mgemm_k<<<dim3(4, 97), 256, 0, stream>>>(tA, whb, 512, nullptr, sinv, 1, 0,
        tBf, rpe_h_b, nullptr, nullptr, 0, 0, GROWS, 512, 512);
    norms_k<<<3081, 256, 0, stream>>>(tBf, sinv, GROWS);
    mgemm_k<<<dim3(4, 97), 256, 0, stream>>>(tBf, whb + 262144, 512, nullptr, sinv, 1, 0,
        tA, rpe_h_b + 512, nullptr, nullptr, 0, 0, GROWS, 512, 512);
    norms_k<<<3081, 256, 0, stream>>>(tA, sinv, GROWS);
    mgemm_k<<<dim3(4, 97), 256, 0, stream>>>(tA, whb + 524288, 512, nullptr, sinv, 1, 0,
        tBf, rpe_h_b + 1024, nullptr, nullptr, 0, 0, GROWS, 512, 512);
    norms_k<<<3081, 256, 0, stream>>>(tBf, sinv, GROWS);
    convt_k<<<24642, 256, 0, stream>>>(tBf, sinv, tb16);

    norms_k<<<6272, 256, 0, stream>>>(x, ninv, ROWS);
    if (ext) convx_k<<<6272, 256, 0, stream>>>(x, ninv, xn16);

    // batched RPE-out GEMM for all heads: tb16 @ wrob^T -> g_row_all[12321][1024]
    mgemm_k<<<dim3(8, 97), 256, 0, stream>>>(tb16, wrob, 512, nullptr, nullptr, 0, 1,
        g_row_all, rpe_out_b, nullptr, nullptr, 0, 0, GROWS, 1024, 512);

    if (ext3) {
        // ---- batched all-heads g-spectrum: 4 launches ----
        gtr_k<<<dim3(386, 4, 8), dim3(32, 8), 0, stream>>>(g_row_all, 1024, GhA, GlA);
        pads_k<<<7548, 256, 0, stream>>>(GhA, GlA, TgFhA, TgFlA, 8);
        hilo_gemm_k<<<dim3(111, 2, 8), 256, 0, stream>>>(GhA, GlA, RTc, 0, 1,
            TgFhA, TgFlA, 0, 128, GH_STRIDE_US, TGF_STRIDE_US);
        hilo_gemm_k<<<dim3(2, 65, 8), 256, 0, stream>>>(TgFhA, TgFlA, Mg, 1, 0,
            GhatA, nullptr, 1, 224, TGF_STRIDE_US, GHAT_STRIDE_US);
    }

    if (ext4) {
        // ---- fully batched main path: 24 launches -> 3 ----
        // 1) all-heads u|v projection (emode 6): u -> uyf cols, v -> vcmA
        mgemm_k<<<dim3(16, 196), 256, 0, stream>>>(xn16, wuv, 512, vcmA, nullptr, 0, 1,
            uyf, buv, nullptr, nullptr, 0, 6, ROWS, 2048, 512);
        // 2) all-heads v conv (y written in place into vcmA)
        vfft_k<<<8192, 512, 0, stream>>>(vcmA, GhatA, RTcAh, RTcAl, MvAh, MvAl,
            M2Ah, M2Al, RT2Bh, RT2Bl, MvT, M2cT, RT2cT, VCMA_HS, GHAT_STRIDE_US);
        // 3) all-heads uyf *= y
        fusey3_k<<<dim3(98, 4, 64), dim3(32, 8), 0, stream>>>(uyf, vcmA);
    } else {
        // ---- per-head main path (round-9) ----
        for (int h = 0; h < 8; ++h) {
            const size_t wo = (size_t)h * 65536;
            const unsigned short* ghat_h = ext3 ? (GhatA + (size_t)h * GHAT_STRIDE_US) : Ghat16;
            if (!ext3) {
                gtr_k<<<dim3(386, 4), dim3(32, 8), 0, stream>>>(g_row_all + h * 128, 1024, Gh, Gl);
                pads_k<<<944, 256, 0, stream>>>(Gh, Gl, TgFh, TgFl, 1);
                hilo_gemm_k<<<dim3(111, 2), 256, 0, stream>>>(Gh, Gl, RTc, 0, 1,
                    TgFh, TgFl, 0, 128, 0, 0);
                hilo_gemm_k<<<dim3(2, 65), 256, 0, stream>>>(TgFh, TgFl, Mg, 1, 0,
                    Ghat16, nullptr, 1, 224, 0, 0);
            }
            if (ext) {
                mgemm_k<<<dim3(2, 196), 256, 0, stream>>>(xn16, wuv + (size_t)h * 131072, 512,
                    vcm16, nullptr, 0, 1,
                    u16, buv + h * 256, nullptr, nullptr, 0, 5, ROWS, 256, 512);
            } else {
                mgemm_k<<<dim3(1, 196), 256, 0, stream>>>(x, wvb + wo, 512, nullptr, ninv, 0, 0,
                    vcm16, b_v + h * 128, nullptr, nullptr, 0, 4, ROWS, 128, 512);
            }
            vfft_k<<<1024, 512, 0, stream>>>(vcm16, ghat_h, RTcAh, RTcAl, MvAh, MvAl,
                M2Ah, M2Al, RT2Bh, RT2Bl, MvT, M2cT, RT2cT, 0, 0);
            if (!ext) {
                mgemm_k<<<dim3(1, 196), 256, 0, stream>>>(x, wub + wo, 512, nullptr, ninv, 0, 0,
                    u16, b_u + h * 128, nullptr, nullptr, 0, 2, ROWS, 128, 512);
            }
            if (ext2) {
                fusey2_k<<<dim3(98, 4, 8), dim3(32, 8), 0, stream>>>(u16, vcm16, uyf, h);
            } else {
                fusey_k<<<dim3(98, 4, 8), dim3(32, 8), 0, stream>>>(u16, vcm16);
                mgemm_k<<<dim3(4, 196), 256, 0, stream>>>(u16, wob + h * 128, 1024, nullptr, nullptr, 0, 1,
                    nullptr, b_o, x, out, (h == 0) ? 1 : 0, 3, ROWS, 512, 128);
            }
        }
    }
    if (ext2) {
        // single output GEMM: out = uyf[25088x1024] @ W_o^T + b_o + x
        mgemm_k<<<dim3(4, 196), 256, 0, stream>>>(uyf, wob, 1024, nullptr, nullptr, 0, 1,
            nullptr, b_o, x, out, 1, 3, ROWS, 512, 1024);
    }
}

// Round 11
// 2375.825 us; speedup vs baseline: 1.5330x; 1.5330x over previous
//
#include <hip/hip_runtime.h>
#include <math.h>

// ---------------- problem sizes ----------------
#define NB 8
#define NN 56
#define POS 3136             // 56*56
#define ROWS 25088           // 8*3136
#define GR 111               // 2N-1
#define GROWS 12321          // 111*111
#define FREQ 16640           // per-channel spectrum: [kq 65][256] (re 128 | im 128)

// ---------------- workspace layout (float offsets), base 36.5 MB ----------------
#define OFF_MVT    0u
#define OFF_M2T    28672u
#define OFF_RT2T   57344u
#define OFF_RTC    64960u
#define OFF_MG     79392u
#define OFF_RTCAH  136224u
#define OFF_RTCAL  140384u
#define OFF_MVAH   144544u
#define OFF_MVAL   160928u
#define OFF_M2AH   177312u
#define OFF_M2AL   191648u
#define OFF_RT2BH  205984u
#define OFF_RT2BL  210592u
#define OFF_NINV   215200u
#define OFF_SINV   240288u
#define OFF_WB     252624u
#define OFF_TB16   1694416u
#define OFF_POOL   4848592u
#define WS_FLOATS  9124816u   // 36.5 MB
// ---- ext1: fused u|v projection ----
#define OFF_XN16   9124816u   // 25088x512 bf16 = 6,422,528 fl
#define OFF_WUV    15547344u  // [8][256][512] bf16 = 524,288 fl
#define OFF_BUV    16071632u  // [2048] fp32
#define WS_EXT     16073680u  // 64.3 MB
// ---- ext2: single K=1024 output GEMM ----
#define OFF_UYF    16073680u  // 25088x1024 bf16 = 12,845,056 fl
#define WS_EXT2    28918736u  // 115.7 MB
// ---- ext3: batched all-heads g-spectrum pipeline ----
#define GH_STRIDE_US   1818624u   // 14208*128
#define TGF_STRIDE_US  1863680u   // 16640*112 (= 8320*224)
#define GHAT_STRIDE_US 2129920u   // 128*65*256
#define OFF_GHA    28918736u  // [8]*GH_STRIDE bf16 = 7,274,496 fl
#define OFF_GLA    36193232u  // 7,274,496 fl
#define OFF_TGFHA  43467728u  // [8]*TGF_STRIDE bf16 = 7,454,720 fl
#define OFF_TGFLA  50922448u  // 7,454,720 fl
#define OFF_GHATA  28918736u  // [8]*GHAT_STRIDE bf16 — ALIASES GhA/GlA (dead after stage1)
#define WS_EXT3    58377168u  // 233.5 MB
// NOTE (r10 post-mortem): ext4 (all-heads vcmA + emode-6 scatter) REMOVED.
// The v-half channel-major scatter into a 51 MB buffer blew past L2 ->
// 32x write amplification (1.6 GB WRITE_SIZE, 460 us GEMM). Scatter
// writes are only cheap when the active window is L2-resident (6.4 MB
// per-head vcm16 is; 51 MB vcmA is not). Keep the per-head main path.
// WB sub-offsets (ushort units)
#define WB_WU  0u
#define WB_WV  524288u
#define WB_WO  1048576u
#define WB_WH  1572864u
#define WB_WRO 2359296u
// pool sub-offsets (fl units) — fallback (non-ext3) per-head g-path:
#define POOL_U16   1064960u
#define POOL_VCM   2670592u
#define POOL_GH    0u
#define POOL_GL    909312u
#define POOL_TGFH  1818624u
#define POOL_TGFL  2750464u

typedef __attribute__((ext_vector_type(8))) short bf8_t;
typedef __attribute__((ext_vector_type(8))) unsigned short us8_t;
typedef __attribute__((ext_vector_type(4))) float f4_t;

__device__ inline float bf2f(unsigned short b) {
    union { unsigned u; float f; } v; v.u = ((unsigned)b) << 16; return v.f;
}
__device__ inline unsigned short f2bf(float f) {
    union { float f; unsigned u; } v; v.f = f;
    unsigned r = v.u + 0x7FFF + ((v.u >> 16) & 1);
    return (unsigned short)(r >> 16);
}

__global__ void probe_k(float* out, float code) { out[0] = code; }

// =====================================================================
// fp32 constants (gfft + vfft Nyquist tail). angle reduced: (a*b) mod 128
// =====================================================================
__global__ void consts_k(float* RTc, float* MvT, float* Mg, float* M2cT, float* RT2cT) {
    int idx = blockIdx.x * 256 + threadIdx.x;
    const float STEP = 0.049087385212340526f; // 2*pi/128
    if (idx < 14430) { // RTc[q*130+col]: gfft row DFT
        int q = idx / 130, col = idx % 130;
        int a = (col < 65) ? col : col - 65;
        float th = (float)((a * q) & 127) * STEP;
        RTc[idx] = (col < 65) ? cosf(th) : -sinf(th);
        return;
    }
    idx -= 14430;
    if (idx < 28672) { // MvT[s*256+r]
        int s = idx / 256, r = idx % 256;
        int kp = (r < 128) ? r : r - 128;
        int sp = (s < 56) ? s : s - 56;
        float th = (float)((kp * sp) & 127) * STEP;
        float cv = cosf(th), sv = sinf(th);
        MvT[idx] = (r < 128) ? ((s < 56) ? cv : sv) : ((s < 56) ? -sv : cv);
        return;
    }
    idx -= 28672;
    if (idx < 56832) { // Mg[r*222+s]: gfft col DFT
        int r = idx / 222, s = idx % 222;
        int kp = (r < 128) ? r : r - 128;
        int sp = (s < 111) ? s : s - 111;
        float th = (float)((kp * sp) & 127) * STEP;
        float cv = cosf(th), sv = sinf(th);
        Mg[idx] = (r < 128) ? ((s < 111) ? cv : sv) : ((s < 111) ? -sv : cv);
        return;
    }
    idx -= 56832;
    if (idx < 28672) { // M2cT[s*112+r]
        int s = idx / 112, r = idx % 112;
        int a = (r < 56) ? (r + 55) : (r - 1);
        int kp = (s < 128) ? s : s - 128;
        float th = (float)((kp * a) & 127) * STEP;
        float cv = cosf(th), sv = sinf(th);
        M2cT[idx] = (r < 56) ? ((s < 128) ? cv : -sv) : ((s < 128) ? sv : cv);
        return;
    }
    idx -= 28672;
    if (idx < 7616) { // RT2cT[b*136+col], w/L^2 folded
        int b = idx / 136, col = idx % 136;
        float val = 0.f;
        if (col < 65 || (col >= 68 && col < 133)) {
            int kq = (col < 65) ? col : col - 68;
            float w = (kq == 0 || kq == 64) ? 1.f : 2.f;
            float th = (float)((kq * (b + 55)) & 127) * STEP;
            val = ((col < 65) ? cosf(th) : -sinf(th)) * w * (1.f / 16384.f);
        }
        RT2cT[idx] = val;
    }
}

// =====================================================================
// bf16 hi/lo MFMA constants (derived from fp32 consts; run after consts_k)
// =====================================================================
__global__ void consts2_k(const float* __restrict__ MvT, const float* __restrict__ M2cT,
                          const float* __restrict__ RT2cT,
                          unsigned short* RTcAh, unsigned short* RTcAl,
                          unsigned short* MvAh, unsigned short* MvAl,
                          unsigned short* M2Ah, unsigned short* M2Al,
                          unsigned short* RT2Bh, unsigned short* RT2Bl) {
    int idx = blockIdx.x * 256 + threadIdx.x;
    const float STEP = 0.049087385212340526f;
    float v = 0.f; unsigned short *ph, *pl; int off;
    if (idx < 8320) {               // RTcA [130 rows (65 re | 65 im)][64]
        int row = idx >> 6, q = idx & 63;
        if (q < 56) {
            int kq = (row < 65) ? row : row - 65;
            float th = (float)((kq * q) & 127) * STEP;
            v = (row < 65) ? cosf(th) : -sinf(th);
        }
        ph = RTcAh; pl = RTcAl; off = idx;
    } else if (idx < 41088) {       // MvA [256][128] (cols 112..127 zero)
        int i = idx - 8320; int r = i >> 7, s = i & 127;
        if (s < 112) v = MvT[s * 256 + r];
        ph = MvAh; pl = MvAl; off = i;
    } else if (idx < 69760) {       // M2A [112][256]
        int i = idx - 41088; int a = i >> 8, r = i & 255;
        v = M2cT[r * 112 + a];
        ph = M2Ah; pl = M2Al; off = i;
    } else if (idx < 78976) {       // RT2B [64][144]: 0..64 re | 72..136 im
        int i = idx - 69760; int bq = i / 144, col = i % 144;
        if (bq < 56) {
            if (col < 65) v = RT2cT[bq * 136 + col];
            else if (col >= 72 && col < 137) v = RT2cT[bq * 136 + 68 + (col - 72)];
        }
        ph = RT2Bh; pl = RT2Bl; off = i;
    } else return;
    unsigned short h = f2bf(v);
    ph[off] = h;
    pl[off] = f2bf(v - bf2f(h));
}

// =====================================================================
// row L2 norms -> inverse simple-rms scale, D=512
// =====================================================================
__global__ void norms_k(const float* __restrict__ X, float* __restrict__ out, int rows) {
    int row = blockIdx.x * 4 + (threadIdx.x >> 6);
    int lane = threadIdx.x & 63;
    if (row >= rows) return;
    const float* p = X + (size_t)row * 512;
    float s = 0.f;
    #pragma unroll
    for (int i = 0; i < 8; ++i) { float v = p[lane + 64 * i]; s += v * v; }
    #pragma unroll
    for (int o = 32; o > 0; o >>= 1) s += __shfl_down(s, o, 64);
    if (lane == 0) out[row] = 1.f / (sqrtf(s) * 0.04419417382415922f + 1e-8f);
}

// =====================================================================
// fused row-norm + bf16(x*ninv): one pass over x (replaces norms_k(x)+convx_k;
// values held in registers between the reduce and the convert).
// One wave per row; lane holds x[row][lane*8 .. lane*8+7].
// =====================================================================
__global__ void normx_k(const float* __restrict__ X, unsigned short* __restrict__ xn) {
    int row = blockIdx.x * 4 + (threadIdx.x >> 6);
    int lane = threadIdx.x & 63;
    if (row >= ROWS) return;
    const float* p = X + (size_t)row * 512 + lane * 8;
    float4 f1 = *(const float4*)p, f2 = *(const float4*)(p + 4);
    float s = f1.x * f1.x + f1.y * f1.y + f1.z * f1.z + f1.w * f1.w
            + f2.x * f2.x + f2.y * f2.y + f2.z * f2.z + f2.w * f2.w;
    #pragma unroll
    for (int o = 32; o > 0; o >>= 1) s += __shfl_down(s, o, 64);
    s = __shfl(s, 0, 64);
    float inv = 1.f / (sqrtf(s) * 0.04419417382415922f + 1e-8f);
    us8_t o;
    o[0] = f2bf(f1.x * inv); o[1] = f2bf(f1.y * inv);
    o[2] = f2bf(f1.z * inv); o[3] = f2bf(f1.w * inv);
    o[4] = f2bf(f2.x * inv); o[5] = f2bf(f2.y * inv);
    o[6] = f2bf(f2.z * inv); o[7] = f2bf(f2.w * inv);
    *(us8_t*)(xn + (size_t)row * 512 + lane * 8) = o;
}

__global__ void t0_k(const float* __restrict__ w, const float* __restrict__ b, float* __restrict__ out) {
    int idx = blockIdx.x * 256 + threadIdx.x;
    if (idx >= GROWS * 512) return;
    int r = idx >> 9, c = idx & 511;
    int i = r / 111, j = r % 111;
    float dp = (float)(i - 55), dq = (float)(j - 55);
    out[idx] = dp * w[c * 2] + dq * w[c * 2 + 1] + b[c];
}

__global__ void convw_k(const float* __restrict__ src, unsigned short* __restrict__ dst, int n) {
    int i = blockIdx.x * 256 + threadIdx.x;
    if (i < n) dst[i] = f2bf(src[i]);
}
__global__ void convt_k(const float* __restrict__ t, const float* __restrict__ sinv,
                        unsigned short* __restrict__ dst) {
    int i = blockIdx.x * 256 + threadIdx.x;
    if (i >= GROWS * 512) return;
    int r = i >> 9;
    dst[i] = f2bf(fmaxf(t[i], 0.f) * sinv[r]);
}

// wuv[h*256 + j][k]: j<128 -> W_u row h*128+j; else W_v row h*128+j-128.
__global__ void convuv_k(const float* __restrict__ Wu, const float* __restrict__ Wv,
                         const float* __restrict__ bu, const float* __restrict__ bv,
                         unsigned short* __restrict__ wuv, float* __restrict__ buv) {
    int i = blockIdx.x * 256 + threadIdx.x;      // 1,048,576 exact -> 4096 blocks
    if (i < 1048576) {
        int row = i >> 9, k = i & 511;
        int h = row >> 8, j = row & 255;
        float v = (j < 128) ? Wu[(size_t)(h * 128 + j) * 512 + k]
                            : Wv[(size_t)(h * 128 + j - 128) * 512 + k];
        wuv[i] = f2bf(v);
    }
    if (i < 2048) {
        int h = i >> 8, j = i & 255;
        buv[i] = (j < 128) ? bu[h * 128 + j] : bv[h * 128 + j - 128];
    }
}

// =====================================================================
// bf16 MFMA GEMM (verified fragment pattern), epilogue/amode variants
//  amode 0: A fp32 rm -> relu?*scale -> bf16 ; amode 1: A bf16 rm
//  amode 2: A = bf16(u*y gather) — legacy
//  emode 0: fp32 rm +bias ; emode 2: bf16 rm +bias+silu
//  emode 3: out accum (+bias+xres if first) ; emode 4: bf16 cm +bias+silu
//  emode 5: split u|v one head: c<128 -> u16 rm +silu; c>=128 -> vcm cm (via yv)
// =====================================================================
__global__ __launch_bounds__(256) void mgemm_k(
    const void* __restrict__ Aptr, const unsigned short* __restrict__ B, int ldb,
    const unsigned short* __restrict__ yv, const float* __restrict__ scale,
    int relu_in, int amode,
    void* __restrict__ Cptr, const float* __restrict__ bias,
    const float* __restrict__ xres, float* __restrict__ outAcc, int first,
    int emode, int M, int N, int K)
{
    __shared__ __align__(16) unsigned short As[4096];
    __shared__ __align__(16) unsigned short Bs[4096];
    const int t = threadIdx.x;
    const int lane = t & 63;
    const int quad = lane >> 4, ln = lane & 15;
    const int wave = t >> 6;
    const int wm = (wave >> 1) << 6, wn = (wave & 1) << 6;
    const int row0 = blockIdx.y << 7, col0 = blockIdx.x << 7;
    const int sc = t & 3;
    const int sm = t >> 2;
    const float* Af = (const float*)Aptr;
    const unsigned short* Au = (const unsigned short*)Aptr;
    f4_t acc[4][4];
    #pragma unroll
    for (int i = 0; i < 4; ++i)
        #pragma unroll
        for (int j = 0; j < 4; ++j)
            acc[i][j] = (f4_t){0.f, 0.f, 0.f, 0.f};

    for (int k0 = 0; k0 < K; k0 += 32) {
        #pragma unroll
        for (int rep = 0; rep < 2; ++rep) {
            const int m = sm + (rep << 6);
            const int am = row0 + m;
            us8_t av = {0, 0, 0, 0, 0, 0, 0, 0};
            if (am < M) {
                if (amode == 0) {
                    const float s = scale ? scale[am] : 1.f;
                    const float* ap = Af + (size_t)am * K + k0 + (sc << 3);
                    float4 f1 = *(const float4*)ap;
                    float4 f2 = *(const float4*)(ap + 4);
                    if (relu_in) {
                        f1.x = fmaxf(f1.x, 0.f); f1.y = fmaxf(f1.y, 0.f);
                        f1.z = fmaxf(f1.z, 0.f); f1.w = fmaxf(f1.w, 0.f);
                        f2.x = fmaxf(f2.x, 0.f); f2.y = fmaxf(f2.y, 0.f);
                        f2.z = fmaxf(f2.z, 0.f); f2.w = fmaxf(f2.w, 0.f);
                    }
                    av[0] = f2bf(f1.x * s); av[1] = f2bf(f1.y * s);
                    av[2] = f2bf(f1.z * s); av[3] = f2bf(f1.w * s);
                    av[4] = f2bf(f2.x * s); av[5] = f2bf(f2.y * s);
                    av[6] = f2bf(f2.z * s); av[7] = f2bf(f2.w * s);
                } else if (amode == 1) {
                    av = *(const us8_t*)(Au + (size_t)am * K + k0 + (sc << 3));
                } else {
                    const unsigned short* up = Au + (size_t)am * K + k0 + (sc << 3);
                    const int bb = am / POS, pos = am - bb * POS;
                    const unsigned short* yb = yv + ((size_t)(bb * 128 + k0 + (sc << 3))) * POS + pos;
                    #pragma unroll
                    for (int j = 0; j < 8; ++j)
                        av[j] = f2bf(bf2f(up[j]) * bf2f(yb[(size_t)j * POS]));
                }
            }
            *(us8_t*)&As[(sc << 10) + (m << 3)] = av;
        }
        #pragma unroll
        for (int rep = 0; rep < 2; ++rep) {
            const int n = sm + (rep << 6);
            us8_t bv = *(const us8_t*)(B + (size_t)(col0 + n) * ldb + k0 + (sc << 3));
            *(us8_t*)&Bs[(sc << 10) + (n << 3)] = bv;
        }
        __syncthreads();
        bf8_t af[4], bfr[4];
        #pragma unroll
        for (int i = 0; i < 4; ++i)
            af[i] = *(const bf8_t*)&As[(quad << 10) + ((wm + (i << 4) + ln) << 3)];
        #pragma unroll
        for (int i = 0; i < 4; ++i)
            bfr[i] = *(const bf8_t*)&Bs[(quad << 10) + ((wn + (i << 4) + ln) << 3)];
        #pragma unroll
        for (int i = 0; i < 4; ++i)
            #pragma unroll
            for (int j = 0; j < 4; ++j)
                acc[i][j] = __builtin_amdgcn_mfma_f32_16x16x32_bf16(af[i], bfr[j], acc[i][j], 0, 0, 0);
        __syncthreads();
    }
    #pragma unroll
    for (int i = 0; i < 4; ++i) {
        #pragma unroll
        for (int j = 0; j < 4; ++j) {
            #pragma unroll
            for (int rr = 0; rr < 4; ++rr) {
                const int r = row0 + wm + (i << 4) + (quad << 2) + rr;
                const int c = col0 + wn + (j << 4) + ln;
                if (r >= M) continue;
                float v = acc[i][j][rr];
                if (emode == 0) {
                    v += bias[c];
                    ((float*)Cptr)[(size_t)r * N + c] = v;
                } else if (emode == 2) {
                    v += bias[c]; v = v / (1.f + expf(-v));
                    ((unsigned short*)Cptr)[(size_t)r * N + c] = f2bf(v);
                } else if (emode == 4) {
                    v += bias[c]; v = v / (1.f + expf(-v));
                    const int bb = r / POS, pos = r - bb * POS;
                    ((unsigned short*)Cptr)[((size_t)(bb * 128 + c)) * POS + pos] = f2bf(v);
                } else if (emode == 5) {
                    v += bias[c]; v = v / (1.f + expf(-v));
                    unsigned short bv16 = f2bf(v);
                    if (c < 128) {
                        ((unsigned short*)Cptr)[(size_t)r * 128 + c] = bv16;
                    } else {
                        const int bb = r / POS, pos = r - bb * POS;
                        ((unsigned short*)yv)[((size_t)(bb * 128 + (c - 128))) * POS + pos] = bv16;
                    }
                } else {
                    const size_t oi = (size_t)r * 512 + c;
                    v += first ? (bias[c] + xres[oi]) : outAcc[oi];
                    outAcc[oi] = v;
                }
            }
        }
    }
}

// =====================================================================
// fused transpose + bf16 hi/lo split (head-batched via blockIdx.z)
// =====================================================================
__global__ void gtr_k(const float* __restrict__ src, int ld,
                      unsigned short* __restrict__ Gh, unsigned short* __restrict__ Gl) {
    __shared__ float tile[32][33];
    const int z = blockIdx.z;
    src += (size_t)z * 128;
    Gh += (size_t)z * GH_STRIDE_US;
    Gl += (size_t)z * GH_STRIDE_US;
    int s0 = blockIdx.x * 32, d0 = blockIdx.y * 32;
    int tx = threadIdx.x, ty = threadIdx.y;
    #pragma unroll
    for (int i = 0; i < 32; i += 8) {
        int s = s0 + ty + i;
        if (s < GROWS) tile[ty + i][tx] = src[(size_t)s * ld + d0 + tx];
    }
    __syncthreads();
    int s = s0 + tx;
    if (s < GROWS) {
        int p = s / 111, q = s - p * 111;
        #pragma unroll
        for (int i = 0; i < 32; i += 8) {
            int d = d0 + ty + i;
            float v = tile[tx][ty + i];
            unsigned short h = f2bf(v);
            size_t o = (size_t)(d * 111 + p) * 128 + q;
            Gh[o] = h;
            Gl[o] = f2bf(v - bf2f(h));
        }
    }
}

// zero GEMM pad slots for nh heads (head-strided)
__global__ void pads_k(unsigned short* __restrict__ Gh, unsigned short* __restrict__ Gl,
                       unsigned short* __restrict__ TgFh, unsigned short* __restrict__ TgFl,
                       int nh) {
    int i = blockIdx.x * 256 + threadIdx.x;
    if (i < nh * 16640) {
        int h = i / 16640, r = i % 16640;
        size_t o = (size_t)h * TGF_STRIDE_US + (size_t)r * 112 + 111;
        TgFh[o] = 0; TgFl[o] = 0;
    }
    if (i < nh * 241536) {
        int h = i / 241536, j = i % 241536;
        int r = j / 17, c = 111 + j % 17;
        size_t o = (size_t)h * GH_STRIDE_US + (size_t)r * 128 + c;
        Gh[o] = 0; Gl[o] = 0;
    }
}

// =====================================================================
// fuse u *= y  (in place on u16) — fallback path.
// =====================================================================
__global__ void fusey_k(unsigned short* __restrict__ u, const unsigned short* __restrict__ y) {
    __shared__ unsigned short yt[32][34];
    const int pos0 = blockIdx.x * 32, k0 = blockIdx.y * 32, bb = blockIdx.z;
    const int tx = threadIdx.x, ty = threadIdx.y;
    #pragma unroll
    for (int i = 0; i < 32; i += 8) {
        int k = k0 + ty + i;
        yt[ty + i][tx] = y[((size_t)(bb * 128 + k)) * POS + pos0 + tx];
    }
    __syncthreads();
    #pragma unroll
    for (int i = 0; i < 32; i += 8) {
        size_t r = (size_t)bb * POS + pos0 + ty + i;
        size_t idx = r * 128 + k0 + tx;
        u[idx] = f2bf(bf2f(u[idx]) * bf2f(yt[tx][ty + i]));
    }
}

// =====================================================================
// fuse u*y -> uyf[r][h*128+k]  (per-head; ext2 path).
// =====================================================================
__global__ void fusey2_k(const unsigned short* __restrict__ u, const unsigned short* __restrict__ y,
                         unsigned short* __restrict__ uyf, int h) {
    __shared__ unsigned short yt[32][34];
    const int pos0 = blockIdx.x * 32, k0 = blockIdx.y * 32, bb = blockIdx.z;
    const int tx = threadIdx.x, ty = threadIdx.y;
    #pragma unroll
    for (int i = 0; i < 32; i += 8) {
        int k = k0 + ty + i;
        yt[ty + i][tx] = y[((size_t)(bb * 128 + k)) * POS + pos0 + tx];
    }
    __syncthreads();
    #pragma unroll
    for (int i = 0; i < 32; i += 8) {
        size_t r = (size_t)bb * POS + pos0 + ty + i;
        unsigned short uv = u[r * 128 + k0 + tx];
        uyf[r * 1024 + h * 128 + k0 + tx] = f2bf(bf2f(uv) * bf2f(yt[tx][ty + i]));
    }
}

// =====================================================================
// hi/lo bf16 GEMM (3-product). Head-batched via blockIdx.z (zD/zC strides).
// =====================================================================
__device__ inline float cval(const float* __restrict__ Csrc, int cmode, int row, int kk) {
    if (cmode == 0)
        return (kk < 111 && row < 130) ? Csrc[kk * 130 + row] : 0.f;
    int s = (kk < 112) ? kk : (111 + (kk - 112));
    bool ok = (kk < 112) ? (kk < 111) : (kk < 223);
    return ok ? Csrc[(size_t)row * 222 + s] : 0.f;
}

__global__ __launch_bounds__(256) void hilo_gemm_k(
    const unsigned short* __restrict__ Dh, const unsigned short* __restrict__ Dl,
    const float* __restrict__ Csrc, int cmode, int constIsA,
    unsigned short* __restrict__ C0, unsigned short* __restrict__ C1,
    int omode, int K, unsigned zD, unsigned zC)
{
    __shared__ __align__(16) unsigned short Ash[4096];
    __shared__ __align__(16) unsigned short Asl[4096];
    __shared__ __align__(16) unsigned short Bsh[4096];
    __shared__ __align__(16) unsigned short Bsl[4096];
    const int t = threadIdx.x;
    const int lane = t & 63;
    const int quad = lane >> 4, ln = lane & 15;
    const int wave = t >> 6;
    const int wm = (wave >> 1) << 6, wn = (wave & 1) << 6;
    const int row0 = blockIdx.y << 7, col0 = blockIdx.x << 7;
    const int sc = t & 3, sm = t >> 2;
    const size_t zoffD = (size_t)blockIdx.z * zD, zoffC = (size_t)blockIdx.z * zC;
    Dh += zoffD; Dl += zoffD;
    C0 += zoffC; if (C1) C1 += zoffC;
    f4_t acc[4][4];
    #pragma unroll
    for (int i = 0; i < 4; ++i)
        #pragma unroll
        for (int j = 0; j < 4; ++j)
            acc[i][j] = (f4_t){0.f, 0.f, 0.f, 0.f};

    for (int k0 = 0; k0 < K; k0 += 32) {
        #pragma unroll
        for (int rep = 0; rep < 2; ++rep) {
            const int m = sm + (rep << 6);
            // ---- A tile ----
            {
                const int gr = row0 + m;
                us8_t hv, lv;
                if (constIsA) {
                    #pragma unroll
                    for (int j = 0; j < 8; ++j) {
                        int kk = k0 + (sc << 3) + j;
                        float v = cval(Csrc, cmode, gr, kk);
                        unsigned short h = f2bf(v);
                        hv[j] = h; lv[j] = f2bf(v - bf2f(h));
                    }
                } else {
                    hv = *(const us8_t*)(Dh + (size_t)gr * K + k0 + (sc << 3));
                    lv = *(const us8_t*)(Dl + (size_t)gr * K + k0 + (sc << 3));
                }
                *(us8_t*)&Ash[(sc << 10) + (m << 3)] = hv;
                *(us8_t*)&Asl[(sc << 10) + (m << 3)] = lv;
            }
            // ---- B tile ----
            {
                const int gc = col0 + m;
                us8_t hv, lv;
                if (constIsA) {
                    hv = *(const us8_t*)(Dh + (size_t)gc * K + k0 + (sc << 3));
                    lv = *(const us8_t*)(Dl + (size_t)gc * K + k0 + (sc << 3));
                } else {
                    #pragma unroll
                    for (int j = 0; j < 8; ++j) {
                        int kk = k0 + (sc << 3) + j;
                        float v = cval(Csrc, cmode, gc, kk);
                        unsigned short h = f2bf(v);
                        hv[j] = h; lv[j] = f2bf(v - bf2f(h));
                    }
                }
                *(us8_t*)&Bsh[(sc << 10) + (m << 3)] = hv;
                *(us8_t*)&Bsl[(sc << 10) + (m << 3)] = lv;
            }
        }
        __syncthreads();
        bf8_t ah[4], al[4], bh[4], bl[4];
        #pragma unroll
        for (int i = 0; i < 4; ++i) {
            ah[i] = *(const bf8_t*)&Ash[(quad << 10) + ((wm + (i << 4) + ln) << 3)];
            al[i] = *(const bf8_t*)&Asl[(quad << 10) + ((wm + (i << 4) + ln) << 3)];
            bh[i] = *(const bf8_t*)&Bsh[(quad << 10) + ((wn + (i << 4) + ln) << 3)];
            bl[i] = *(const bf8_t*)&Bsl[(quad << 10) + ((wn + (i << 4) + ln) << 3)];
        }
        #pragma unroll
        for (int i = 0; i < 4; ++i)
            #pragma unroll
            for (int j = 0; j < 4; ++j) {
                acc[i][j] = __builtin_amdgcn_mfma_f32_16x16x32_bf16(ah[i], bh[j], acc[i][j], 0, 0, 0);
                acc[i][j] = __builtin_amdgcn_mfma_f32_16x16x32_bf16(ah[i], bl[j], acc[i][j], 0, 0, 0);
                acc[i][j] = __builtin_amdgcn_mfma_f32_16x16x32_bf16(al[i], bh[j], acc[i][j], 0, 0, 0);
            }
        __syncthreads();
    }
    #pragma unroll
    for (int i = 0; i < 4; ++i) {
        #pragma unroll
        for (int j = 0; j < 4; ++j) {
            #pragma unroll
            for (int rr = 0; rr < 4; ++rr) {
                const int r = row0 + wm + (i << 4) + (quad << 2) + rr;
                const int c = col0 + wn + (j << 4) + ln;
                float v = acc[i][j][rr];
                if (omode == 1) {
                    C0[(size_t)r * 256 + c] = f2bf(v);
                } else {
                    if (r < 130) {
                        int kq = (r < 65) ? r : r - 65;
                        int im = (r < 65) ? 0 : 1;
                        int d = c / 111, p = c - d * 111;
                        size_t o = ((size_t)((d * 65 + kq) * 2 + im)) * 112 + p;
                        unsigned short h = f2bf(v);
                        C0[o] = h;
                        C1[o] = f2bf(v - bf2f(h));
                    }
                }
            }
        }
    }
}

// =====================================================================
// v conv (one head, in-place bf16): MFMA DFT stages per channel workgroup.
// Round-0 body, plain __launch_bounds__(512): VGPR 88, 2 blocks/CU,
// no spill, ~142-149 us. All restructurings regressed (r2/r3/r8/r10).
// =====================================================================
__global__ __launch_bounds__(512) void vfft_k(
    unsigned short* __restrict__ vcm, const unsigned short* __restrict__ Ghat,
    const unsigned short* __restrict__ RTcAh, const unsigned short* __restrict__ RTcAl,
    const unsigned short* __restrict__ MvAh,  const unsigned short* __restrict__ MvAl,
    const unsigned short* __restrict__ M2Ah,  const unsigned short* __restrict__ M2Al,
    const unsigned short* __restrict__ RT2Bh, const unsigned short* __restrict__ RT2Bl,
    const float* __restrict__ MvT, const float* __restrict__ M2cT,
    const float* __restrict__ RT2cT)
{
    __shared__ __align__(16) unsigned short Vs[64 * 72];    // [p][q] bf16, zero-pad
    __shared__ __align__(16) unsigned short TqT[32 * 136];  // [kqL][s(112)+pad]
    __shared__ __align__(16) unsigned short VhT[32 * 264];  // [kqL][r(256)+pad]
    __shared__ __align__(16) unsigned short QA[64 * 72];    // [p][k(64)+pad]
    __shared__ float tmp[424];                              // Nyquist temps
    const int tid = threadIdx.x;
    const int lane = tid & 63, wave = tid >> 6;
    const int quad = lane >> 4, ln = lane & 15;
    const int d = blockIdx.x >> 3, b = blockIdx.x & 7;
    unsigned short* chan = vcm + (size_t)(b * 128 + d) * POS;
    const unsigned short* ghd = Ghat + (size_t)d * FREQ;

    for (int i = tid; i < 64 * 72; i += 512) { Vs[i] = 0; QA[i] = 0; }
    {   // TqT K-pad cols 112..127 zero (rows 0..31)
        int rr = tid >> 4, cc = 112 + (tid & 15);
        if (tid < 512) TqT[rr * 136 + cc] = 0;
    }
    __syncthreads();
    for (int i = tid; i < POS; i += 512) {
        int p = i / 56, q = i - p * 56;
        Vs[p * 72 + q] = chan[i];
    }
    f4_t acc5[2] = { (f4_t){0,0,0,0}, (f4_t){0,0,0,0} };
    __syncthreads();

    // ===== Nyquist kq=64 tail (fp32 VALU, tiny) =====
    if (tid < 56) {
        const unsigned short* vp = Vs + tid * 72;
        float a = 0.f;
        for (int q = 0; q < 56; q += 2) a += bf2f(vp[q]) - bf2f(vp[q + 1]);
        tmp[tid] = a;
    }
    __syncthreads();
    if (tid < 256) {
        float a = 0.f;
        for (int s = 0; s < 56; ++s) a = fmaf(MvT[s * 256 + tid], tmp[s], a);
        tmp[56 + tid] = a;
    }
    __syncthreads();
    if (tid < 128) {
        float vr = tmp[56 + tid], vi = tmp[184 + tid];
        float gr = bf2f(ghd[64 * 256 + tid]), gm = bf2f(ghd[64 * 256 + 128 + tid]);
        tmp[56 + tid] = vr * gr - vi * gm;
        tmp[184 + tid] = vr * gm + vi * gr;
    }
    __syncthreads();
    if (tid < 112) {
        float a = 0.f;
        for (int r = 0; r < 256; ++r) a = fmaf(M2cT[r * 112 + tid], tmp[56 + r], a);
        tmp[312 + tid] = a;
    }
    __syncthreads();
    #pragma unroll
    for (int ti = 0; ti < 2; ++ti) {
        int t = wave * 2 + ti, mt = t >> 2, nt = t & 3;
        int bq = nt * 16 + ln;
        if (bq < 56) {
            float r1 = RT2cT[bq * 136 + 64], r2 = RT2cT[bq * 136 + 132];
            #pragma unroll
            for (int rr = 0; rr < 4; ++rr) {
                int p = mt * 16 + quad * 4 + rr;
                if (p < 56) acc5[ti][rr] += tmp[312 + p] * r1 + tmp[368 + p] * r2;
            }
        }
    }

    // ===== main chunks kq0 = 0, 32 =====
    for (int ck = 0; ck < 2; ++ck) {
        const int kq0 = ck * 32;
        __syncthreads();
        // ---- S1: D[c'][p] = RTcA[c'][q] . Vs[p][q], K=64 ----
        #pragma unroll
        for (int ti = 0; ti < 2; ++ti) {
            int t = wave * 2 + ti, mt = t >> 2, nt = t & 3;
            int m = mt * 16 + ln;
            int arow = (m >> 5) * 65 + kq0 + (m & 31);
            int pcol = nt * 16 + ln;
            f4_t a = (f4_t){0, 0, 0, 0};
            #pragma unroll
            for (int ks = 0; ks < 2; ++ks) {
                int k0 = ks * 32 + quad * 8;
                bf8_t Ah = *(const bf8_t*)(RTcAh + arow * 64 + k0);
                bf8_t Al = *(const bf8_t*)(RTcAl + arow * 64 + k0);
                bf8_t Bv = *(const bf8_t*)&Vs[pcol * 72 + k0];
                a = __builtin_amdgcn_mfma_f32_16x16x32_bf16(Ah, Bv, a, 0, 0, 0);
                a = __builtin_amdgcn_mfma_f32_16x16x32_bf16(Al, Bv, a, 0, 0, 0);
            }
            if (pcol < 56) {
                #pragma unroll
                for (int rr = 0; rr < 4; ++rr) {
                    int cp = mt * 16 + quad * 4 + rr;
                    TqT[(cp & 31) * 136 + (cp >> 5) * 56 + pcol] = f2bf(a[rr]);
                }
            }
        }
        __syncthreads();
        // ---- S2: D[r][c] = MvA[r][s] . TqT[c][s], K=128 ----
        #pragma unroll
        for (int ti = 0; ti < 4; ++ti) {
            int t = wave * 4 + ti, mt = t >> 1, nt = t & 1;
            int r = mt * 16 + ln, c = nt * 16 + ln;
            f4_t a = (f4_t){0, 0, 0, 0};
            #pragma unroll
            for (int ks = 0; ks < 4; ++ks) {
                int k0 = ks * 32 + quad * 8;
                bf8_t Ah = *(const bf8_t*)(MvAh + r * 128 + k0);
                bf8_t Al = *(const bf8_t*)(MvAl + r * 128 + k0);
                bf8_t Bv = *(const bf8_t*)&TqT[c * 136 + k0];
                a = __builtin_amdgcn_mfma_f32_16x16x32_bf16(Ah, Bv, a, 0, 0, 0);
                a = __builtin_amdgcn_mfma_f32_16x16x32_bf16(Al, Bv, a, 0, 0, 0);
            }
            int r0 = mt * 16 + quad * 4;
            ushort4 st;
            st.x = f2bf(a[0]); st.y = f2bf(a[1]); st.z = f2bf(a[2]); st.w = f2bf(a[3]);
            *(ushort4*)&VhT[c * 264 + r0] = st;
        }
        __syncthreads();
        // ---- S3: complex multiply with Ghat ----
        #pragma unroll
        for (int i = 0; i < 8; ++i) {
            int o = tid + 512 * i;
            int c = o >> 7, kp = o & 127;
            float vr = bf2f(VhT[c * 264 + kp]), vi = bf2f(VhT[c * 264 + 128 + kp]);
            int gi = (kq0 + c) * 256 + kp;
            float gr = bf2f(ghd[gi]), gm = bf2f(ghd[gi + 128]);
            VhT[c * 264 + kp] = f2bf(vr * gr - vi * gm);
            VhT[c * 264 + 128 + kp] = f2bf(vr * gm + vi * gr);
        }
        __syncthreads();
        // ---- S4: D[a][c] = M2A[a][r] . VhT[c][r], K=256 ----
        #pragma unroll
        for (int ti = 0; ti < 2; ++ti) {
            int t = wave * 2 + ti;
            if (t < 14) {
                int mt = t >> 1, nt = t & 1;
                int aa = mt * 16 + ln, c = nt * 16 + ln;
                f4_t a = (f4_t){0, 0, 0, 0};
                #pragma unroll
                for (int ks = 0; ks < 8; ++ks) {
                    int k0 = ks * 32 + quad * 8;
                    bf8_t Ah = *(const bf8_t*)(M2Ah + aa * 256 + k0);
                    bf8_t Al = *(const bf8_t*)(M2Al + aa * 256 + k0);
                    bf8_t Bv = *(const bf8_t*)&VhT[c * 264 + k0];
                    a = __builtin_amdgcn_mfma_f32_16x16x32_bf16(Ah, Bv, a, 0, 0, 0);
                    a = __builtin_amdgcn_mfma_f32_16x16x32_bf16(Al, Bv, a, 0, 0, 0);
                }
                #pragma unroll
                for (int rr = 0; rr < 4; ++rr) {
                    int av_ = mt * 16 + quad * 4 + rr;
                    int p = (av_ < 56) ? av_ : av_ - 56;
                    int reg = (av_ < 56) ? 0 : 32;
                    QA[p * 72 + reg + c] = f2bf(a[rr]);
                }
            }
        }
        __syncthreads();
        // ---- S5: acc[p][bq] += QA[p][k] . RT2B[bq][k], K=64 ----
        #pragma unroll
        for (int ti = 0; ti < 2; ++ti) {
            int t = wave * 2 + ti, mt = t >> 2, nt = t & 3;
            int p = mt * 16 + ln, bq = nt * 16 + ln;
            #pragma unroll
            for (int ks = 0; ks < 2; ++ks) {
                int k0 = ks * 32 + quad * 8;
                bf8_t Aq = *(const bf8_t*)&QA[p * 72 + k0];
                int col = (ks ? 72 : 0) + kq0 + quad * 8;
                bf8_t Bh = *(const bf8_t*)(RT2Bh + bq * 144 + col);
                bf8_t Bl = *(const bf8_t*)(RT2Bl + bq * 144 + col);
                acc5[ti] = __builtin_amdgcn_mfma_f32_16x16x32_bf16(Aq, Bh, acc5[ti], 0, 0, 0);
                acc5[ti] = __builtin_amdgcn_mfma_f32_16x16x32_bf16(Aq, Bl, acc5[ti], 0, 0, 0);
            }
        }
    }
    // ===== store y (bf16, in place) =====
    #pragma unroll
    for (int ti = 0; ti < 2; ++ti) {
        int t = wave * 2 + ti, mt = t >> 2, nt = t & 3;
        int bq = nt * 16 + ln;
        if (bq < 56) {
            #pragma unroll
            for (int rr = 0; rr < 4; ++rr) {
                int p = mt * 16 + quad * 4 + rr;
                if (p < 56) chan[p * 56 + bq] = f2bf(acc5[ti][rr]);
            }
        }
    }
}

// =====================================================================
extern "C" void kernel_launch(void* const* d_in, const int* in_sizes, int n_in,
                              void* d_out, int out_size, void* d_ws, size_t ws_size,
                              hipStream_t stream) {
    (void)in_sizes; (void)n_in; (void)out_size;
    const float* x         = (const float*)d_in[0];
    const float* W_u       = (const float*)d_in[1];
    const float* b_u       = (const float*)d_in[2];
    const float* W_v       = (const float*)d_in[3];
    const float* b_v       = (const float*)d_in[4];
    const float* W_o       = (const float*)d_in[5];
    const float* b_o       = (const float*)d_in[6];
    const float* rpe_in_w  = (const float*)d_in[7];
    const float* rpe_in_b  = (const float*)d_in[8];
    const float* rpe_h_w   = (const float*)d_in[9];
    const float* rpe_h_b   = (const float*)d_in[10];
    const float* rpe_out_w = (const float*)d_in[11];
    const float* rpe_out_b = (const float*)d_in[12];
    float* out = (float*)d_out;

    if (ws_size < (size_t)WS_FLOATS * 4) {
        probe_k<<<1, 1, 0, stream>>>(out, 1000.0f + (float)((double)ws_size * 1e-6));
        return;
    }
    const bool ext  = ws_size >= (size_t)WS_EXT * 4;
    const bool ext2 = ws_size >= (size_t)WS_EXT2 * 4;
    const bool ext3 = ws_size >= (size_t)WS_EXT3 * 4;
    float* ws    = (float*)d_ws;
    float* MvT   = ws + OFF_MVT;
    float* M2cT  = ws + OFF_M2T;
    float* RT2cT = ws + OFF_RT2T;
    float* RTc   = ws + OFF_RTC;
    float* Mg    = ws + OFF_MG;
    unsigned short* RTcAh = (unsigned short*)(ws + OFF_RTCAH);
    unsigned short* RTcAl = (unsigned short*)(ws + OFF_RTCAL);
    unsigned short* MvAh  = (unsigned short*)(ws + OFF_MVAH);
    unsigned short* MvAl  = (unsigned short*)(ws + OFF_MVAL);
    unsigned short* M2Ah  = (unsigned short*)(ws + OFF_M2AH);
    unsigned short* M2Al  = (unsigned short*)(ws + OFF_M2AL);
    unsigned short* RT2Bh = (unsigned short*)(ws + OFF_RT2BH);
    unsigned short* RT2Bl = (unsigned short*)(ws + OFF_RT2BL);
    float* ninv  = ws + OFF_NINV;
    float* sinv  = ws + OFF_SINV;
    unsigned short* WB  = (unsigned short*)(ws + OFF_WB);
    unsigned short* wub = WB + WB_WU;
    unsigned short* wvb = WB + WB_WV;
    unsigned short* wob = WB + WB_WO;
    unsigned short* whb = WB + WB_WH;
    unsigned short* wrob= WB + WB_WRO;
    unsigned short* tb16= (unsigned short*)(ws + OFF_TB16);
    float* pool  = ws + OFF_POOL;
    unsigned short* Ghat16 = (unsigned short*)pool;
    unsigned short* u16    = (unsigned short*)(pool + POOL_U16);
    unsigned short* vcm16  = (unsigned short*)(pool + POOL_VCM);
    unsigned short* Gh   = (unsigned short*)(pool + POOL_GH);
    unsigned short* Gl   = (unsigned short*)(pool + POOL_GL);
    unsigned short* TgFh = (unsigned short*)(pool + POOL_TGFH);
    unsigned short* TgFl = (unsigned short*)(pool + POOL_TGFL);
    unsigned short* xn16 = (unsigned short*)(ws + OFF_XN16);
    unsigned short* wuv  = (unsigned short*)(ws + OFF_WUV);
    float* buv   = ws + OFF_BUV;
    unsigned short* uyf  = (unsigned short*)(ws + OFF_UYF);
    unsigned short* GhA   = (unsigned short*)(ws + OFF_GHA);
    unsigned short* GlA   = (unsigned short*)(ws + OFF_GLA);
    unsigned short* TgFhA = (unsigned short*)(ws + OFF_TGFHA);
    unsigned short* TgFlA = (unsigned short*)(ws + OFF_TGFLA);
    unsigned short* GhatA = (unsigned short*)(ws + OFF_GHATA); // aliases GhA/GlA
    float* tA    = out;                // rpe fp32 ping-pong in d_out
    float* tBf   = out + 6308352u;
    float* g_row_all = out;            // [12321][1024] fp32 in d_out scratch

    consts_k<<<533, 256, 0, stream>>>(RTc, MvT, Mg, M2cT, RT2cT);
    consts2_k<<<309, 256, 0, stream>>>(MvT, M2cT, RT2cT, RTcAh, RTcAl,
                                       MvAh, MvAl, M2Ah, M2Al, RT2Bh, RT2Bl);

    // weights -> bf16
    if (ext) {
        convuv_k<<<4096, 256, 0, stream>>>(W_u, W_v, b_u, b_v, wuv, buv);
    } else {
        convw_k<<<2048, 256, 0, stream>>>(W_u, wub, 524288);
        convw_k<<<2048, 256, 0, stream>>>(W_v, wvb, 524288);
    }
    convw_k<<<2048, 256, 0, stream>>>(W_o, wob, 524288);
    convw_k<<<3072, 256, 0, stream>>>(rpe_h_w, whb, 786432);
    convw_k<<<2048, 256, 0, stream>>>(rpe_out_w, wrob, 524288);

    // ---- RPE MLP hidden ladder ----
    t0_k<<<24642, 256, 0, stream>>>(rpe_in_w, rpe_in_b, tA);
    norms_k<<<3081, 256, 0, stream>>>(tA, sinv, GROWS);
    mgemm_k<<<dim3(4, 97), 256, 0, stream>>>(tA, whb, 512, nullptr, sinv, 1, 0,
        tBf, rpe_h_b, nullptr, nullptr, 0, 0, GROWS, 512, 512);
    norms_k<<<3081, 256, 0, stream>>>(tBf, sinv, GROWS);
    mgemm_k<<<dim3(4, 97), 256, 0, stream>>>(tBf, whb + 262144, 512, nullptr, sinv, 1, 0,
        tA, rpe_h_b + 512, nullptr, nullptr, 0, 0, GROWS, 512, 512);
    norms_k<<<3081, 256, 0, stream>>>(tA, sinv, GROWS);
    mgemm_k<<<dim3(4, 97), 256, 0, stream>>>(tA, whb + 524288, 512, nullptr, sinv, 1, 0,
        tBf, rpe_h_b + 1024, nullptr, nullptr, 0, 0, GROWS, 512, 512);
    norms_k<<<3081, 256, 0, stream>>>(tBf, sinv, GROWS);
    convt_k<<<24642, 256, 0, stream>>>(tBf, sinv, tb16);

    if (ext) {
        // fused: row-norm + bf16(x*ninv) in one pass over x
        normx_k<<<6272, 256, 0, stream>>>(x, xn16);
    } else {
        norms_k<<<6272, 256, 0, stream>>>(x, ninv, ROWS);
    }

    // batched RPE-out GEMM for all heads: tb16 @ wrob^T -> g_row_all[12321][1024]
    mgemm_k<<<dim3(8, 97), 256, 0, stream>>>(tb16, wrob, 512, nullptr, nullptr, 0, 1,
        g_row_all, rpe_out_b, nullptr, nullptr, 0, 0, GROWS, 1024, 512);

    if (ext3) {
        // ---- batched all-heads g-spectrum: 4 launches ----
        gtr_k<<<dim3(386, 4, 8), dim3(32, 8), 0, stream>>>(g_row_all, 1024, GhA, GlA);
        pads_k<<<7548, 256, 0, stream>>>(GhA, GlA, TgFhA, TgFlA, 8);
        hilo_gemm_k<<<dim3(111, 2, 8), 256, 0, stream>>>(GhA, GlA, RTc, 0, 1,
            TgFhA, TgFlA, 0, 128, GH_STRIDE_US, TGF_STRIDE_US);
        hilo_gemm_k<<<dim3(2, 65, 8), 256, 0, stream>>>(TgFhA, TgFlA, Mg, 1, 0,
            GhatA, nullptr, 1, 224, TGF_STRIDE_US, GHAT_STRIDE_US);
    }

    // ---- per-head main path (round-9 proven config) ----
    for (int h = 0; h < 8; ++h) {
        const size_t wo = (size_t)h * 65536;
        const unsigned short* ghat_h = ext3 ? (GhatA + (size_t)h * GHAT_STRIDE_US) : Ghat16;
        if (!ext3) {
            gtr_k<<<dim3(386, 4), dim3(32, 8), 0, stream>>>(g_row_all + h * 128, 1024, Gh, Gl);
            pads_k<<<944, 256, 0, stream>>>(Gh, Gl, TgFh, TgFl, 1);
            hilo_gemm_k<<<dim3(111, 2), 256, 0, stream>>>(Gh, Gl, RTc, 0, 1,
                TgFh, TgFl, 0, 128, 0, 0);
            hilo_gemm_k<<<dim3(2, 65), 256, 0, stream>>>(TgFh, TgFl, Mg, 1, 0,
                Ghat16, nullptr, 1, 224, 0, 0);
        }
        if (ext) {
            // fused u+v projection: emode 5 splits c<128 -> u16 rm, c>=128 -> vcm16 cm
            // (vcm16 scatter stays L2-resident at 6.4 MB — see r10 note)
            mgemm_k<<<dim3(2, 196), 256, 0, stream>>>(xn16, wuv + (size_t)h * 131072, 512,
                vcm16, nullptr, 0, 1,
                u16, buv + h * 256, nullptr, nullptr, 0, 5, ROWS, 256, 512);
        } else {
            mgemm_k<<<dim3(1, 196), 256, 0, stream>>>(x, wvb + wo, 512, nullptr, ninv, 0, 0,
                vcm16, b_v + h * 128, nullptr, nullptr, 0, 4, ROWS, 128, 512);
        }
        vfft_k<<<1024, 512, 0, stream>>>(vcm16, ghat_h, RTcAh, RTcAl, MvAh, MvAl,
            M2Ah, M2Al, RT2Bh, RT2Bl, MvT, M2cT, RT2cT);
        if (!ext) {
            mgemm_k<<<dim3(1, 196), 256, 0, stream>>>(x, wub + wo, 512, nullptr, ninv, 0, 0,
                u16, b_u + h * 128, nullptr, nullptr, 0, 2, ROWS, 128, 512);
        }
        if (ext2) {
            fusey2_k<<<dim3(98, 4, 8), dim3(32, 8), 0, stream>>>(u16, vcm16, uyf, h);
        } else {
            fusey_k<<<dim3(98, 4, 8), dim3(32, 8), 0, stream>>>(u16, vcm16);
            mgemm_k<<<dim3(4, 196), 256, 0, stream>>>(u16, wob + h * 128, 1024, nullptr, nullptr, 0, 1,
                nullptr, b_o, x, out, (h == 0) ? 1 : 0, 3, ROWS, 512, 128);
        }
    }
    if (ext2) {
        // single output GEMM: out = uyf[25088x1024] @ W_o^T + b_o + x
        mgemm_k<<<dim3(4, 196), 256, 0, stream>>>(uyf, wob, 1024, nullptr, nullptr, 0, 1,
            nullptr, b_o, x, out, 1, 3, ROWS, 512, 1024);
    }
}

// Round 12
// 2317.246 us; speedup vs baseline: 1.5718x; 1.0253x over previous
//
#include <hip/hip_runtime.h>
#include <math.h>

// ---------------- problem sizes ----------------
#define NB 8
#define NN 56
#define POS 3136             // 56*56
#define ROWS 25088           // 8*3136
#define GR 111               // 2N-1
#define GROWS 12321          // 111*111
#define FREQ 16640           // per-channel spectrum: [kq 65][256] (re 128 | im 128)

// ---------------- workspace layout (float offsets), base 36.5 MB ----------------
#define OFF_MVT    0u
#define OFF_M2T    28672u
#define OFF_RT2T   57344u
#define OFF_RTC    64960u
#define OFF_MG     79392u
#define OFF_RTCAH  136224u
#define OFF_RTCAL  140384u
#define OFF_MVAH   144544u
#define OFF_MVAL   160928u
#define OFF_M2AH   177312u
#define OFF_M2AL   191648u
#define OFF_RT2BH  205984u
#define OFF_RT2BL  210592u
#define OFF_NINV   215200u
#define OFF_SINV   240288u
#define OFF_WB     252624u
#define OFF_TB16   1694416u
#define OFF_POOL   4848592u
#define WS_FLOATS  9124816u   // 36.5 MB
// ---- ext1: fused u|v projection ----
#define OFF_XN16   9124816u   // 25088x512 bf16 = 6,422,528 fl
#define OFF_WUV    15547344u  // [8][256][512] bf16 = 524,288 fl
#define OFF_BUV    16071632u  // [2048] fp32
#define WS_EXT     16073680u  // 64.3 MB
// ---- ext2: single K=1024 output GEMM ----
#define OFF_UYF    16073680u  // 25088x1024 bf16 = 12,845,056 fl
#define WS_EXT2    28918736u  // 115.7 MB
// ---- ext3: batched all-heads g-spectrum pipeline ----
#define GH_STRIDE_US   1818624u   // 14208*128
#define TGF_STRIDE_US  1863680u   // 16640*112 (= 8320*224)
#define GHAT_STRIDE_US 2129920u   // 128*65*256
#define OFF_GHA    28918736u  // [8]*GH_STRIDE bf16 = 7,274,496 fl
#define OFF_GLA    36193232u  // 7,274,496 fl
#define OFF_TGFHA  43467728u  // [8]*TGF_STRIDE bf16 = 7,454,720 fl
#define OFF_TGFLA  50922448u  // 7,454,720 fl
#define OFF_GHATA  28918736u  // [8]*GHAT_STRIDE bf16 — ALIASES GhA/GlA (dead after stage1)
#define WS_EXT3    58377168u  // 233.5 MB
// ---- ext5: row-major uv16 staging (kills emode-5 scatter amplification) ----
// r11 PMC: per-head uv GEMM FETCH 134.8 MB / WRITE 51.6 MB vs 51.4/12.9
// logical -> partial-line scatter thrash (r10 lesson, milder form). Fix:
// GEMM writes row-major uv16; vtr_k LDS-transposes v-half into vcm16.
#define OFF_UV16   58377168u  // [25088][256] bf16 = 6,422,528 fl
#define WS_EXT5    64799696u  // 259.2 MB (r10 proved ws >= 284.9 MB)
// WB sub-offsets (ushort units)
#define WB_WU  0u
#define WB_WV  524288u
#define WB_WO  1048576u
#define WB_WH  1572864u
#define WB_WRO 2359296u
// pool sub-offsets (fl units) — fallback (non-ext3) per-head g-path:
#define POOL_U16   1064960u
#define POOL_VCM   2670592u
#define POOL_GH    0u
#define POOL_GL    909312u
#define POOL_TGFH  1818624u
#define POOL_TGFL  2750464u

typedef __attribute__((ext_vector_type(8))) short bf8_t;
typedef __attribute__((ext_vector_type(8))) unsigned short us8_t;
typedef __attribute__((ext_vector_type(4))) float f4_t;

__device__ inline float bf2f(unsigned short b) {
    union { unsigned u; float f; } v; v.u = ((unsigned)b) << 16; return v.f;
}
__device__ inline unsigned short f2bf(float f) {
    union { float f; unsigned u; } v; v.f = f;
    unsigned r = v.u + 0x7FFF + ((v.u >> 16) & 1);
    return (unsigned short)(r >> 16);
}

__global__ void probe_k(float* out, float code) { out[0] = code; }

// =====================================================================
// fp32 constants (gfft + vfft Nyquist tail). angle reduced: (a*b) mod 128
// =====================================================================
__global__ void consts_k(float* RTc, float* MvT, float* Mg, float* M2cT, float* RT2cT) {
    int idx = blockIdx.x * 256 + threadIdx.x;
    const float STEP = 0.049087385212340526f; // 2*pi/128
    if (idx < 14430) { // RTc[q*130+col]: gfft row DFT
        int q = idx / 130, col = idx % 130;
        int a = (col < 65) ? col : col - 65;
        float th = (float)((a * q) & 127) * STEP;
        RTc[idx] = (col < 65) ? cosf(th) : -sinf(th);
        return;
    }
    idx -= 14430;
    if (idx < 28672) { // MvT[s*256+r]
        int s = idx / 256, r = idx % 256;
        int kp = (r < 128) ? r : r - 128;
        int sp = (s < 56) ? s : s - 56;
        float th = (float)((kp * sp) & 127) * STEP;
        float cv = cosf(th), sv = sinf(th);
        MvT[idx] = (r < 128) ? ((s < 56) ? cv : sv) : ((s < 56) ? -sv : cv);
        return;
    }
    idx -= 28672;
    if (idx < 56832) { // Mg[r*222+s]: gfft col DFT
        int r = idx / 222, s = idx % 222;
        int kp = (r < 128) ? r : r - 128;
        int sp = (s < 111) ? s : s - 111;
        float th = (float)((kp * sp) & 127) * STEP;
        float cv = cosf(th), sv = sinf(th);
        Mg[idx] = (r < 128) ? ((s < 111) ? cv : sv) : ((s < 111) ? -sv : cv);
        return;
    }
    idx -= 56832;
    if (idx < 28672) { // M2cT[s*112+r]
        int s = idx / 112, r = idx % 112;
        int a = (r < 56) ? (r + 55) : (r - 1);
        int kp = (s < 128) ? s : s - 128;
        float th = (float)((kp * a) & 127) * STEP;
        float cv = cosf(th), sv = sinf(th);
        M2cT[idx] = (r < 56) ? ((s < 128) ? cv : -sv) : ((s < 128) ? sv : cv);
        return;
    }
    idx -= 28672;
    if (idx < 7616) { // RT2cT[b*136+col], w/L^2 folded
        int b = idx / 136, col = idx % 136;
        float val = 0.f;
        if (col < 65 || (col >= 68 && col < 133)) {
            int kq = (col < 65) ? col : col - 68;
            float w = (kq == 0 || kq == 64) ? 1.f : 2.f;
            float th = (float)((kq * (b + 55)) & 127) * STEP;
            val = ((col < 65) ? cosf(th) : -sinf(th)) * w * (1.f / 16384.f);
        }
        RT2cT[idx] = val;
    }
}

// =====================================================================
// bf16 hi/lo MFMA constants (derived from fp32 consts; run after consts_k)
// =====================================================================
__global__ void consts2_k(const float* __restrict__ MvT, const float* __restrict__ M2cT,
                          const float* __restrict__ RT2cT,
                          unsigned short* RTcAh, unsigned short* RTcAl,
                          unsigned short* MvAh, unsigned short* MvAl,
                          unsigned short* M2Ah, unsigned short* M2Al,
                          unsigned short* RT2Bh, unsigned short* RT2Bl) {
    int idx = blockIdx.x * 256 + threadIdx.x;
    const float STEP = 0.049087385212340526f;
    float v = 0.f; unsigned short *ph, *pl; int off;
    if (idx < 8320) {               // RTcA [130 rows (65 re | 65 im)][64]
        int row = idx >> 6, q = idx & 63;
        if (q < 56) {
            int kq = (row < 65) ? row : row - 65;
            float th = (float)((kq * q) & 127) * STEP;
            v = (row < 65) ? cosf(th) : -sinf(th);
        }
        ph = RTcAh; pl = RTcAl; off = idx;
    } else if (idx < 41088) {       // MvA [256][128] (cols 112..127 zero)
        int i = idx - 8320; int r = i >> 7, s = i & 127;
        if (s < 112) v = MvT[s * 256 + r];
        ph = MvAh; pl = MvAl; off = i;
    } else if (idx < 69760) {       // M2A [112][256]
        int i = idx - 41088; int a = i >> 8, r = i & 255;
        v = M2cT[r * 112 + a];
        ph = M2Ah; pl = M2Al; off = i;
    } else if (idx < 78976) {       // RT2B [64][144]: 0..64 re | 72..136 im
        int i = idx - 69760; int bq = i / 144, col = i % 144;
        if (bq < 56) {
            if (col < 65) v = RT2cT[bq * 136 + col];
            else if (col >= 72 && col < 137) v = RT2cT[bq * 136 + 68 + (col - 72)];
        }
        ph = RT2Bh; pl = RT2Bl; off = i;
    } else return;
    unsigned short h = f2bf(v);
    ph[off] = h;
    pl[off] = f2bf(v - bf2f(h));
}

// =====================================================================
// row L2 norms -> inverse simple-rms scale, D=512
// =====================================================================
__global__ void norms_k(const float* __restrict__ X, float* __restrict__ out, int rows) {
    int row = blockIdx.x * 4 + (threadIdx.x >> 6);
    int lane = threadIdx.x & 63;
    if (row >= rows) return;
    const float* p = X + (size_t)row * 512;
    float s = 0.f;
    #pragma unroll
    for (int i = 0; i < 8; ++i) { float v = p[lane + 64 * i]; s += v * v; }
    #pragma unroll
    for (int o = 32; o > 0; o >>= 1) s += __shfl_down(s, o, 64);
    if (lane == 0) out[row] = 1.f / (sqrtf(s) * 0.04419417382415922f + 1e-8f);
}

// =====================================================================
// fused row-norm + bf16(x*ninv): one pass over x.
// =====================================================================
__global__ void normx_k(const float* __restrict__ X, unsigned short* __restrict__ xn) {
    int row = blockIdx.x * 4 + (threadIdx.x >> 6);
    int lane = threadIdx.x & 63;
    if (row >= ROWS) return;
    const float* p = X + (size_t)row * 512 + lane * 8;
    float4 f1 = *(const float4*)p, f2 = *(const float4*)(p + 4);
    float s = f1.x * f1.x + f1.y * f1.y + f1.z * f1.z + f1.w * f1.w
            + f2.x * f2.x + f2.y * f2.y + f2.z * f2.z + f2.w * f2.w;
    #pragma unroll
    for (int o = 32; o > 0; o >>= 1) s += __shfl_down(s, o, 64);
    s = __shfl(s, 0, 64);
    float inv = 1.f / (sqrtf(s) * 0.04419417382415922f + 1e-8f);
    us8_t o;
    o[0] = f2bf(f1.x * inv); o[1] = f2bf(f1.y * inv);
    o[2] = f2bf(f1.z * inv); o[3] = f2bf(f1.w * inv);
    o[4] = f2bf(f2.x * inv); o[5] = f2bf(f2.y * inv);
    o[6] = f2bf(f2.z * inv); o[7] = f2bf(f2.w * inv);
    *(us8_t*)(xn + (size_t)row * 512 + lane * 8) = o;
}

__global__ void t0_k(const float* __restrict__ w, const float* __restrict__ b, float* __restrict__ out) {
    int idx = blockIdx.x * 256 + threadIdx.x;
    if (idx >= GROWS * 512) return;
    int r = idx >> 9, c = idx & 511;
    int i = r / 111, j = r % 111;
    float dp = (float)(i - 55), dq = (float)(j - 55);
    out[idx] = dp * w[c * 2] + dq * w[c * 2 + 1] + b[c];
}

__global__ void convw_k(const float* __restrict__ src, unsigned short* __restrict__ dst, int n) {
    int i = blockIdx.x * 256 + threadIdx.x;
    if (i < n) dst[i] = f2bf(src[i]);
}
__global__ void convt_k(const float* __restrict__ t, const float* __restrict__ sinv,
                        unsigned short* __restrict__ dst) {
    int i = blockIdx.x * 256 + threadIdx.x;
    if (i >= GROWS * 512) return;
    int r = i >> 9;
    dst[i] = f2bf(fmaxf(t[i], 0.f) * sinv[r]);
}

// wuv[h*256 + j][k]: j<128 -> W_u row h*128+j; else W_v row h*128+j-128.
__global__ void convuv_k(const float* __restrict__ Wu, const float* __restrict__ Wv,
                         const float* __restrict__ bu, const float* __restrict__ bv,
                         unsigned short* __restrict__ wuv, float* __restrict__ buv) {
    int i = blockIdx.x * 256 + threadIdx.x;      // 1,048,576 exact -> 4096 blocks
    if (i < 1048576) {
        int row = i >> 9, k = i & 511;
        int h = row >> 8, j = row & 255;
        float v = (j < 128) ? Wu[(size_t)(h * 128 + j) * 512 + k]
                            : Wv[(size_t)(h * 128 + j - 128) * 512 + k];
        wuv[i] = f2bf(v);
    }
    if (i < 2048) {
        int h = i >> 8, j = i & 255;
        buv[i] = (j < 128) ? bu[h * 128 + j] : bv[h * 128 + j - 128];
    }
}

// =====================================================================
// bf16 MFMA GEMM (verified fragment pattern), epilogue/amode variants
//  amode 0: A fp32 rm -> relu?*scale -> bf16 ; amode 1: A bf16 rm
//  amode 2: A = bf16(u*y gather) — legacy
//  emode 0: fp32 rm +bias ; emode 2: bf16 rm +bias+silu (row-major, clean)
//  emode 3: out accum (+bias+xres if first) ; emode 4: bf16 cm +bias+silu
//  emode 5: split u|v one head (scatter — superseded by emode 2 + vtr_k)
// =====================================================================
__global__ __launch_bounds__(256) void mgemm_k(
    const void* __restrict__ Aptr, const unsigned short* __restrict__ B, int ldb,
    const unsigned short* __restrict__ yv, const float* __restrict__ scale,
    int relu_in, int amode,
    void* __restrict__ Cptr, const float* __restrict__ bias,
    const float* __restrict__ xres, float* __restrict__ outAcc, int first,
    int emode, int M, int N, int K)
{
    __shared__ __align__(16) unsigned short As[4096];
    __shared__ __align__(16) unsigned short Bs[4096];
    const int t = threadIdx.x;
    const int lane = t & 63;
    const int quad = lane >> 4, ln = lane & 15;
    const int wave = t >> 6;
    const int wm = (wave >> 1) << 6, wn = (wave & 1) << 6;
    const int row0 = blockIdx.y << 7, col0 = blockIdx.x << 7;
    const int sc = t & 3;
    const int sm = t >> 2;
    const float* Af = (const float*)Aptr;
    const unsigned short* Au = (const unsigned short*)Aptr;
    f4_t acc[4][4];
    #pragma unroll
    for (int i = 0; i < 4; ++i)
        #pragma unroll
        for (int j = 0; j < 4; ++j)
            acc[i][j] = (f4_t){0.f, 0.f, 0.f, 0.f};

    for (int k0 = 0; k0 < K; k0 += 32) {
        #pragma unroll
        for (int rep = 0; rep < 2; ++rep) {
            const int m = sm + (rep << 6);
            const int am = row0 + m;
            us8_t av = {0, 0, 0, 0, 0, 0, 0, 0};
            if (am < M) {
                if (amode == 0) {
                    const float s = scale ? scale[am] : 1.f;
                    const float* ap = Af + (size_t)am * K + k0 + (sc << 3);
                    float4 f1 = *(const float4*)ap;
                    float4 f2 = *(const float4*)(ap + 4);
                    if (relu_in) {
                        f1.x = fmaxf(f1.x, 0.f); f1.y = fmaxf(f1.y, 0.f);
                        f1.z = fmaxf(f1.z, 0.f); f1.w = fmaxf(f1.w, 0.f);
                        f2.x = fmaxf(f2.x, 0.f); f2.y = fmaxf(f2.y, 0.f);
                        f2.z = fmaxf(f2.z, 0.f); f2.w = fmaxf(f2.w, 0.f);
                    }
                    av[0] = f2bf(f1.x * s); av[1] = f2bf(f1.y * s);
                    av[2] = f2bf(f1.z * s); av[3] = f2bf(f1.w * s);
                    av[4] = f2bf(f2.x * s); av[5] = f2bf(f2.y * s);
                    av[6] = f2bf(f2.z * s); av[7] = f2bf(f2.w * s);
                } else if (amode == 1) {
                    av = *(const us8_t*)(Au + (size_t)am * K + k0 + (sc << 3));
                } else {
                    const unsigned short* up = Au + (size_t)am * K + k0 + (sc << 3);
                    const int bb = am / POS, pos = am - bb * POS;
                    const unsigned short* yb = yv + ((size_t)(bb * 128 + k0 + (sc << 3))) * POS + pos;
                    #pragma unroll
                    for (int j = 0; j < 8; ++j)
                        av[j] = f2bf(bf2f(up[j]) * bf2f(yb[(size_t)j * POS]));
                }
            }
            *(us8_t*)&As[(sc << 10) + (m << 3)] = av;
        }
        #pragma unroll
        for (int rep = 0; rep < 2; ++rep) {
            const int n = sm + (rep << 6);
            us8_t bv = *(const us8_t*)(B + (size_t)(col0 + n) * ldb + k0 + (sc << 3));
            *(us8_t*)&Bs[(sc << 10) + (n << 3)] = bv;
        }
        __syncthreads();
        bf8_t af[4], bfr[4];
        #pragma unroll
        for (int i = 0; i < 4; ++i)
            af[i] = *(const bf8_t*)&As[(quad << 10) + ((wm + (i << 4) + ln) << 3)];
        #pragma unroll
        for (int i = 0; i < 4; ++i)
            bfr[i] = *(const bf8_t*)&Bs[(quad << 10) + ((wn + (i << 4) + ln) << 3)];
        #pragma unroll
        for (int i = 0; i < 4; ++i)
            #pragma unroll
            for (int j = 0; j < 4; ++j)
                acc[i][j] = __builtin_amdgcn_mfma_f32_16x16x32_bf16(af[i], bfr[j], acc[i][j], 0, 0, 0);
        __syncthreads();
    }
    #pragma unroll
    for (int i = 0; i < 4; ++i) {
        #pragma unroll
        for (int j = 0; j < 4; ++j) {
            #pragma unroll
            for (int rr = 0; rr < 4; ++rr) {
                const int r = row0 + wm + (i << 4) + (quad << 2) + rr;
                const int c = col0 + wn + (j << 4) + ln;
                if (r >= M) continue;
                float v = acc[i][j][rr];
                if (emode == 0) {
                    v += bias[c];
                    ((float*)Cptr)[(size_t)r * N + c] = v;
                } else if (emode == 2) {
                    v += bias[c]; v = v / (1.f + expf(-v));
                    ((unsigned short*)Cptr)[(size_t)r * N + c] = f2bf(v);
                } else if (emode == 4) {
                    v += bias[c]; v = v / (1.f + expf(-v));
                    const int bb = r / POS, pos = r - bb * POS;
                    ((unsigned short*)Cptr)[((size_t)(bb * 128 + c)) * POS + pos] = f2bf(v);
                } else if (emode == 5) {
                    v += bias[c]; v = v / (1.f + expf(-v));
                    unsigned short bv16 = f2bf(v);
                    if (c < 128) {
                        ((unsigned short*)Cptr)[(size_t)r * 128 + c] = bv16;
                    } else {
                        const int bb = r / POS, pos = r - bb * POS;
                        ((unsigned short*)yv)[((size_t)(bb * 128 + (c - 128))) * POS + pos] = bv16;
                    }
                } else {
                    const size_t oi = (size_t)r * 512 + c;
                    v += first ? (bias[c] + xres[oi]) : outAcc[oi];
                    outAcc[oi] = v;
                }
            }
        }
    }
}

// =====================================================================
// fused transpose + bf16 hi/lo split (head-batched via blockIdx.z)
// =====================================================================
__global__ void gtr_k(const float* __restrict__ src, int ld,
                      unsigned short* __restrict__ Gh, unsigned short* __restrict__ Gl) {
    __shared__ float tile[32][33];
    const int z = blockIdx.z;
    src += (size_t)z * 128;
    Gh += (size_t)z * GH_STRIDE_US;
    Gl += (size_t)z * GH_STRIDE_US;
    int s0 = blockIdx.x * 32, d0 = blockIdx.y * 32;
    int tx = threadIdx.x, ty = threadIdx.y;
    #pragma unroll
    for (int i = 0; i < 32; i += 8) {
        int s = s0 + ty + i;
        if (s < GROWS) tile[ty + i][tx] = src[(size_t)s * ld + d0 + tx];
    }
    __syncthreads();
    int s = s0 + tx;
    if (s < GROWS) {
        int p = s / 111, q = s - p * 111;
        #pragma unroll
        for (int i = 0; i < 32; i += 8) {
            int d = d0 + ty + i;
            float v = tile[tx][ty + i];
            unsigned short h = f2bf(v);
            size_t o = (size_t)(d * 111 + p) * 128 + q;
            Gh[o] = h;
            Gl[o] = f2bf(v - bf2f(h));
        }
    }
}

// zero GEMM pad slots for nh heads (head-strided)
__global__ void pads_k(unsigned short* __restrict__ Gh, unsigned short* __restrict__ Gl,
                       unsigned short* __restrict__ TgFh, unsigned short* __restrict__ TgFl,
                       int nh) {
    int i = blockIdx.x * 256 + threadIdx.x;
    if (i < nh * 16640) {
        int h = i / 16640, r = i % 16640;
        size_t o = (size_t)h * TGF_STRIDE_US + (size_t)r * 112 + 111;
        TgFh[o] = 0; TgFl[o] = 0;
    }
    if (i < nh * 241536) {
        int h = i / 241536, j = i % 241536;
        int r = j / 17, c = 111 + j % 17;
        size_t o = (size_t)h * GH_STRIDE_US + (size_t)r * 128 + c;
        Gh[o] = 0; Gl[o] = 0;
    }
}

// =====================================================================
// v transpose (ext5): vcm16[(bb*128+ch)*POS+pos] = uv16[(bb*POS+pos)*256+128+ch]
// LDS 32x32 tile; both global sides are 64B-run coalesced (no partial lines).
// =====================================================================
__global__ void vtr_k(const unsigned short* __restrict__ uv, unsigned short* __restrict__ vcm) {
    __shared__ unsigned short tile[32][34];
    const int pos0 = blockIdx.x * 32, ch0 = blockIdx.y * 32, bb = blockIdx.z;
    const int tx = threadIdx.x, ty = threadIdx.y;
    #pragma unroll
    for (int i = 0; i < 32; i += 8) {
        tile[ty + i][tx] = uv[((size_t)(bb * POS + pos0 + ty + i)) * 256 + 128 + ch0 + tx];
    }
    __syncthreads();
    #pragma unroll
    for (int i = 0; i < 32; i += 8) {
        vcm[((size_t)(bb * 128 + ch0 + ty + i)) * POS + pos0 + tx] = tile[tx][ty + i];
    }
}

// =====================================================================
// fuse u *= y  (in place on u16) — fallback path.
// =====================================================================
__global__ void fusey_k(unsigned short* __restrict__ u, const unsigned short* __restrict__ y) {
    __shared__ unsigned short yt[32][34];
    const int pos0 = blockIdx.x * 32, k0 = blockIdx.y * 32, bb = blockIdx.z;
    const int tx = threadIdx.x, ty = threadIdx.y;
    #pragma unroll
    for (int i = 0; i < 32; i += 8) {
        int k = k0 + ty + i;
        yt[ty + i][tx] = y[((size_t)(bb * 128 + k)) * POS + pos0 + tx];
    }
    __syncthreads();
    #pragma unroll
    for (int i = 0; i < 32; i += 8) {
        size_t r = (size_t)bb * POS + pos0 + ty + i;
        size_t idx = r * 128 + k0 + tx;
        u[idx] = f2bf(bf2f(u[idx]) * bf2f(yt[tx][ty + i]));
    }
}

// =====================================================================
// fuse u*y -> uyf[r][h*128+k]. u has row stride lda (128 for u16, 256 for uv16).
// =====================================================================
__global__ void fusey2_k(const unsigned short* __restrict__ u, int lda,
                         const unsigned short* __restrict__ y,
                         unsigned short* __restrict__ uyf, int h) {
    __shared__ unsigned short yt[32][34];
    const int pos0 = blockIdx.x * 32, k0 = blockIdx.y * 32, bb = blockIdx.z;
    const int tx = threadIdx.x, ty = threadIdx.y;
    #pragma unroll
    for (int i = 0; i < 32; i += 8) {
        int k = k0 + ty + i;
        yt[ty + i][tx] = y[((size_t)(bb * 128 + k)) * POS + pos0 + tx];
    }
    __syncthreads();
    #pragma unroll
    for (int i = 0; i < 32; i += 8) {
        size_t r = (size_t)bb * POS + pos0 + ty + i;
        unsigned short uv = u[r * lda + k0 + tx];
        uyf[r * 1024 + h * 128 + k0 + tx] = f2bf(bf2f(uv) * bf2f(yt[tx][ty + i]));
    }
}

// =====================================================================
// hi/lo bf16 GEMM (3-product). Head-batched via blockIdx.z (zD/zC strides).
// =====================================================================
__device__ inline float cval(const float* __restrict__ Csrc, int cmode, int row, int kk) {
    if (cmode == 0)
        return (kk < 111 && row < 130) ? Csrc[kk * 130 + row] : 0.f;
    int s = (kk < 112) ? kk : (111 + (kk - 112));
    bool ok = (kk < 112) ? (kk < 111) : (kk < 223);
    return ok ? Csrc[(size_t)row * 222 + s] : 0.f;
}

__global__ __launch_bounds__(256) void hilo_gemm_k(
    const unsigned short* __restrict__ Dh, const unsigned short* __restrict__ Dl,
    const float* __restrict__ Csrc, int cmode, int constIsA,
    unsigned short* __restrict__ C0, unsigned short* __restrict__ C1,
    int omode, int K, unsigned zD, unsigned zC)
{
    __shared__ __align__(16) unsigned short Ash[4096];
    __shared__ __align__(16) unsigned short Asl[4096];
    __shared__ __align__(16) unsigned short Bsh[4096];
    __shared__ __align__(16) unsigned short Bsl[4096];
    const int t = threadIdx.x;
    const int lane = t & 63;
    const int quad = lane >> 4, ln = lane & 15;
    const int wave = t >> 6;
    const int wm = (wave >> 1) << 6, wn = (wave & 1) << 6;
    const int row0 = blockIdx.y << 7, col0 = blockIdx.x << 7;
    const int sc = t & 3, sm = t >> 2;
    const size_t zoffD = (size_t)blockIdx.z * zD, zoffC = (size_t)blockIdx.z * zC;
    Dh += zoffD; Dl += zoffD;
    C0 += zoffC; if (C1) C1 += zoffC;
    f4_t acc[4][4];
    #pragma unroll
    for (int i = 0; i < 4; ++i)
        #pragma unroll
        for (int j = 0; j < 4; ++j)
            acc[i][j] = (f4_t){0.f, 0.f, 0.f, 0.f};

    for (int k0 = 0; k0 < K; k0 += 32) {
        #pragma unroll
        for (int rep = 0; rep < 2; ++rep) {
            const int m = sm + (rep << 6);
            // ---- A tile ----
            {
                const int gr = row0 + m;
                us8_t hv, lv;
                if (constIsA) {
                    #pragma unroll
                    for (int j = 0; j < 8; ++j) {
                        int kk = k0 + (sc << 3) + j;
                        float v = cval(Csrc, cmode, gr, kk);
                        unsigned short h = f2bf(v);
                        hv[j] = h; lv[j] = f2bf(v - bf2f(h));
                    }
                } else {
                    hv = *(const us8_t*)(Dh + (size_t)gr * K + k0 + (sc << 3));
                    lv = *(const us8_t*)(Dl + (size_t)gr * K + k0 + (sc << 3));
                }
                *(us8_t*)&Ash[(sc << 10) + (m << 3)] = hv;
                *(us8_t*)&Asl[(sc << 10) + (m << 3)] = lv;
            }
            // ---- B tile ----
            {
                const int gc = col0 + m;
                us8_t hv, lv;
                if (constIsA) {
                    hv = *(const us8_t*)(Dh + (size_t)gc * K + k0 + (sc << 3));
                    lv = *(const us8_t*)(Dl + (size_t)gc * K + k0 + (sc << 3));
                } else {
                    #pragma unroll
                    for (int j = 0; j < 8; ++j) {
                        int kk = k0 + (sc << 3) + j;
                        float v = cval(Csrc, cmode, gc, kk);
                        unsigned short h = f2bf(v);
                        hv[j] = h; lv[j] = f2bf(v - bf2f(h));
                    }
                }
                *(us8_t*)&Bsh[(sc << 10) + (m << 3)] = hv;
                *(us8_t*)&Bsl[(sc << 10) + (m << 3)] = lv;
            }
        }
        __syncthreads();
        bf8_t ah[4], al[4], bh[4], bl[4];
        #pragma unroll
        for (int i = 0; i < 4; ++i) {
            ah[i] = *(const bf8_t*)&Ash[(quad << 10) + ((wm + (i << 4) + ln) << 3)];
            al[i] = *(const bf8_t*)&Asl[(quad << 10) + ((wm + (i << 4) + ln) << 3)];
            bh[i] = *(const bf8_t*)&Bsh[(quad << 10) + ((wn + (i << 4) + ln) << 3)];
            bl[i] = *(const bf8_t*)&Bsl[(quad << 10) + ((wn + (i << 4) + ln) << 3)];
        }
        #pragma unroll
        for (int i = 0; i < 4; ++i)
            #pragma unroll
            for (int j = 0; j < 4; ++j) {
                acc[i][j] = __builtin_amdgcn_mfma_f32_16x16x32_bf16(ah[i], bh[j], acc[i][j], 0, 0, 0);
                acc[i][j] = __builtin_amdgcn_mfma_f32_16x16x32_bf16(ah[i], bl[j], acc[i][j], 0, 0, 0);
                acc[i][j] = __builtin_amdgcn_mfma_f32_16x16x32_bf16(al[i], bh[j], acc[i][j], 0, 0, 0);
            }
        __syncthreads();
    }
    #pragma unroll
    for (int i = 0; i < 4; ++i) {
        #pragma unroll
        for (int j = 0; j < 4; ++j) {
            #pragma unroll
            for (int rr = 0; rr < 4; ++rr) {
                const int r = row0 + wm + (i << 4) + (quad << 2) + rr;
                const int c = col0 + wn + (j << 4) + ln;
                float v = acc[i][j][rr];
                if (omode == 1) {
                    C0[(size_t)r * 256 + c] = f2bf(v);
                } else {
                    if (r < 130) {
                        int kq = (r < 65) ? r : r - 65;
                        int im = (r < 65) ? 0 : 1;
                        int d = c / 111, p = c - d * 111;
                        size_t o = ((size_t)((d * 65 + kq) * 2 + im)) * 112 + p;
                        unsigned short h = f2bf(v);
                        C0[o] = h;
                        C1[o] = f2bf(v - bf2f(h));
                    }
                }
            }
        }
    }
}

// =====================================================================
// v conv (one head, in-place bf16): MFMA DFT stages per channel workgroup.
// Round-0 body, plain __launch_bounds__(512): VGPR 88, 2 blocks/CU,
// no spill, ~142-149 us. All restructurings regressed (r2/r3/r8/r10).
// =====================================================================
__global__ __launch_bounds__(512) void vfft_k(
    unsigned short* __restrict__ vcm, const unsigned short* __restrict__ Ghat,
    const unsigned short* __restrict__ RTcAh, const unsigned short* __restrict__ RTcAl,
    const unsigned short* __restrict__ MvAh,  const unsigned short* __restrict__ MvAl,
    const unsigned short* __restrict__ M2Ah,  const unsigned short* __restrict__ M2Al,
    const unsigned short* __restrict__ RT2Bh, const unsigned short* __restrict__ RT2Bl,
    const float* __restrict__ MvT, const float* __restrict__ M2cT,
    const float* __restrict__ RT2cT)
{
    __shared__ __align__(16) unsigned short Vs[64 * 72];    // [p][q] bf16, zero-pad
    __shared__ __align__(16) unsigned short TqT[32 * 136];  // [kqL][s(112)+pad]
    __shared__ __align__(16) unsigned short VhT[32 * 264];  // [kqL][r(256)+pad]
    __shared__ __align__(16) unsigned short QA[64 * 72];    // [p][k(64)+pad]
    __shared__ float tmp[424];                              // Nyquist temps
    const int tid = threadIdx.x;
    const int lane = tid & 63, wave = tid >> 6;
    const int quad = lane >> 4, ln = lane & 15;
    const int d = blockIdx.x >> 3, b = blockIdx.x & 7;
    unsigned short* chan = vcm + (size_t)(b * 128 + d) * POS;
    const unsigned short* ghd = Ghat + (size_t)d * FREQ;

    for (int i = tid; i < 64 * 72; i += 512) { Vs[i] = 0; QA[i] = 0; }
    {   // TqT K-pad cols 112..127 zero (rows 0..31)
        int rr = tid >> 4, cc = 112 + (tid & 15);
        if (tid < 512) TqT[rr * 136 + cc] = 0;
    }
    __syncthreads();
    for (int i = tid; i < POS; i += 512) {
        int p = i / 56, q = i - p * 56;
        Vs[p * 72 + q] = chan[i];
    }
    f4_t acc5[2] = { (f4_t){0,0,0,0}, (f4_t){0,0,0,0} };
    __syncthreads();

    // ===== Nyquist kq=64 tail (fp32 VALU, tiny) =====
    if (tid < 56) {
        const unsigned short* vp = Vs + tid * 72;
        float a = 0.f;
        for (int q = 0; q < 56; q += 2) a += bf2f(vp[q]) - bf2f(vp[q + 1]);
        tmp[tid] = a;
    }
    __syncthreads();
    if (tid < 256) {
        float a = 0.f;
        for (int s = 0; s < 56; ++s) a = fmaf(MvT[s * 256 + tid], tmp[s], a);
        tmp[56 + tid] = a;
    }
    __syncthreads();
    if (tid < 128) {
        float vr = tmp[56 + tid], vi = tmp[184 + tid];
        float gr = bf2f(ghd[64 * 256 + tid]), gm = bf2f(ghd[64 * 256 + 128 + tid]);
        tmp[56 + tid] = vr * gr - vi * gm;
        tmp[184 + tid] = vr * gm + vi * gr;
    }
    __syncthreads();
    if (tid < 112) {
        float a = 0.f;
        for (int r = 0; r < 256; ++r) a = fmaf(M2cT[r * 112 + tid], tmp[56 + r], a);
        tmp[312 + tid] = a;
    }
    __syncthreads();
    #pragma unroll
    for (int ti = 0; ti < 2; ++ti) {
        int t = wave * 2 + ti, mt = t >> 2, nt = t & 3;
        int bq = nt * 16 + ln;
        if (bq < 56) {
            float r1 = RT2cT[bq * 136 + 64], r2 = RT2cT[bq * 136 + 132];
            #pragma unroll
            for (int rr = 0; rr < 4; ++rr) {
                int p = mt * 16 + quad * 4 + rr;
                if (p < 56) acc5[ti][rr] += tmp[312 + p] * r1 + tmp[368 + p] * r2;
            }
        }
    }

    // ===== main chunks kq0 = 0, 32 =====
    for (int ck = 0; ck < 2; ++ck) {
        const int kq0 = ck * 32;
        __syncthreads();
        // ---- S1: D[c'][p] = RTcA[c'][q] . Vs[p][q], K=64 ----
        #pragma unroll
        for (int ti = 0; ti < 2; ++ti) {
            int t = wave * 2 + ti, mt = t >> 2, nt = t & 3;
            int m = mt * 16 + ln;
            int arow = (m >> 5) * 65 + kq0 + (m & 31);
            int pcol = nt * 16 + ln;
            f4_t a = (f4_t){0, 0, 0, 0};
            #pragma unroll
            for (int ks = 0; ks < 2; ++ks) {
                int k0 = ks * 32 + quad * 8;
                bf8_t Ah = *(const bf8_t*)(RTcAh + arow * 64 + k0);
                bf8_t Al = *(const bf8_t*)(RTcAl + arow * 64 + k0);
                bf8_t Bv = *(const bf8_t*)&Vs[pcol * 72 + k0];
                a = __builtin_amdgcn_mfma_f32_16x16x32_bf16(Ah, Bv, a, 0, 0, 0);
                a = __builtin_amdgcn_mfma_f32_16x16x32_bf16(Al, Bv, a, 0, 0, 0);
            }
            if (pcol < 56) {
                #pragma unroll
                for (int rr = 0; rr < 4; ++rr) {
                    int cp = mt * 16 + quad * 4 + rr;
                    TqT[(cp & 31) * 136 + (cp >> 5) * 56 + pcol] = f2bf(a[rr]);
                }
            }
        }
        __syncthreads();
        // ---- S2: D[r][c] = MvA[r][s] . TqT[c][s], K=128 ----
        #pragma unroll
        for (int ti = 0; ti < 4; ++ti) {
            int t = wave * 4 + ti, mt = t >> 1, nt = t & 1;
            int r = mt * 16 + ln, c = nt * 16 + ln;
            f4_t a = (f4_t){0, 0, 0, 0};
            #pragma unroll
            for (int ks = 0; ks < 4; ++ks) {
                int k0 = ks * 32 + quad * 8;
                bf8_t Ah = *(const bf8_t*)(MvAh + r * 128 + k0);
                bf8_t Al = *(const bf8_t*)(MvAl + r * 128 + k0);
                bf8_t Bv = *(const bf8_t*)&TqT[c * 136 + k0];
                a = __builtin_amdgcn_mfma_f32_16x16x32_bf16(Ah, Bv, a, 0, 0, 0);
                a = __builtin_amdgcn_mfma_f32_16x16x32_bf16(Al, Bv, a, 0, 0, 0);
            }
            int r0 = mt * 16 + quad * 4;
            ushort4 st;
            st.x = f2bf(a[0]); st.y = f2bf(a[1]); st.z = f2bf(a[2]); st.w = f2bf(a[3]);
            *(ushort4*)&VhT[c * 264 + r0] = st;
        }
        __syncthreads();
        // ---- S3: complex multiply with Ghat ----
        #pragma unroll
        for (int i = 0; i < 8; ++i) {
            int o = tid + 512 * i;
            int c = o >> 7, kp = o & 127;
            float vr = bf2f(VhT[c * 264 + kp]), vi = bf2f(VhT[c * 264 + 128 + kp]);
            int gi = (kq0 + c) * 256 + kp;
            float gr = bf2f(ghd[gi]), gm = bf2f(ghd[gi + 128]);
            VhT[c * 264 + kp] = f2bf(vr * gr - vi * gm);
            VhT[c * 264 + 128 + kp] = f2bf(vr * gm + vi * gr);
        }
        __syncthreads();
        // ---- S4: D[a][c] = M2A[a][r] . VhT[c][r], K=256 ----
        #pragma unroll
        for (int ti = 0; ti < 2; ++ti) {
            int t = wave * 2 + ti;
            if (t < 14) {
                int mt = t >> 1, nt = t & 1;
                int aa = mt * 16 + ln, c = nt * 16 + ln;
                f4_t a = (f4_t){0, 0, 0, 0};
                #pragma unroll
                for (int ks = 0; ks < 8; ++ks) {
                    int k0 = ks * 32 + quad * 8;
                    bf8_t Ah = *(const bf8_t*)(M2Ah + aa * 256 + k0);
                    bf8_t Al = *(const bf8_t*)(M2Al + aa * 256 + k0);
                    bf8_t Bv = *(const bf8_t*)&VhT[c * 264 + k0];
                    a = __builtin_amdgcn_mfma_f32_16x16x32_bf16(Ah, Bv, a, 0, 0, 0);
                    a = __builtin_amdgcn_mfma_f32_16x16x32_bf16(Al, Bv, a, 0, 0, 0);
                }
                #pragma unroll
                for (int rr = 0; rr < 4; ++rr) {
                    int av_ = mt * 16 + quad * 4 + rr;
                    int p = (av_ < 56) ? av_ : av_ - 56;
                    int reg = (av_ < 56) ? 0 : 32;
                    QA[p * 72 + reg + c] = f2bf(a[rr]);
                }
            }
        }
        __syncthreads();
        // ---- S5: acc[p][bq] += QA[p][k] . RT2B[bq][k], K=64 ----
        #pragma unroll
        for (int ti = 0; ti < 2; ++ti) {
            int t = wave * 2 + ti, mt = t >> 2, nt = t & 3;
            int p = mt * 16 + ln, bq = nt * 16 + ln;
            #pragma unroll
            for (int ks = 0; ks < 2; ++ks) {
                int k0 = ks * 32 + quad * 8;
                bf8_t Aq = *(const bf8_t*)&QA[p * 72 + k0];
                int col = (ks ? 72 : 0) + kq0 + quad * 8;
                bf8_t Bh = *(const bf8_t*)(RT2Bh + bq * 144 + col);
                bf8_t Bl = *(const bf8_t*)(RT2Bl + bq * 144 + col);
                acc5[ti] = __builtin_amdgcn_mfma_f32_16x16x32_bf16(Aq, Bh, acc5[ti], 0, 0, 0);
                acc5[ti] = __builtin_amdgcn_mfma_f32_16x16x32_bf16(Aq, Bl, acc5[ti], 0, 0, 0);
            }
        }
    }
    // ===== store y (bf16, in place) =====
    #pragma unroll
    for (int ti = 0; ti < 2; ++ti) {
        int t = wave * 2 + ti, mt = t >> 2, nt = t & 3;
        int bq = nt * 16 + ln;
        if (bq < 56) {
            #pragma unroll
            for (int rr = 0; rr < 4; ++rr) {
                int p = mt * 16 + quad * 4 + rr;
                if (p < 56) chan[p * 56 + bq] = f2bf(acc5[ti][rr]);
            }
        }
    }
}

// =====================================================================
extern "C" void kernel_launch(void* const* d_in, const int* in_sizes, int n_in,
                              void* d_out, int out_size, void* d_ws, size_t ws_size,
                              hipStream_t stream) {
    (void)in_sizes; (void)n_in; (void)out_size;
    const float* x         = (const float*)d_in[0];
    const float* W_u       = (const float*)d_in[1];
    const float* b_u       = (const float*)d_in[2];
    const float* W_v       = (const float*)d_in[3];
    const float* b_v       = (const float*)d_in[4];
    const float* W_o       = (const float*)d_in[5];
    const float* b_o       = (const float*)d_in[6];
    const float* rpe_in_w  = (const float*)d_in[7];
    const float* rpe_in_b  = (const float*)d_in[8];
    const float* rpe_h_w   = (const float*)d_in[9];
    const float* rpe_h_b   = (const float*)d_in[10];
    const float* rpe_out_w = (const float*)d_in[11];
    const float* rpe_out_b = (const float*)d_in[12];
    float* out = (float*)d_out;

    if (ws_size < (size_t)WS_FLOATS * 4) {
        probe_k<<<1, 1, 0, stream>>>(out, 1000.0f + (float)((double)ws_size * 1e-6));
        return;
    }
    const bool ext  = ws_size >= (size_t)WS_EXT * 4;
    const bool ext2 = ws_size >= (size_t)WS_EXT2 * 4;
    const bool ext3 = ws_size >= (size_t)WS_EXT3 * 4;
    const bool ext5 = ws_size >= (size_t)WS_EXT5 * 4;
    float* ws    = (float*)d_ws;
    float* MvT   = ws + OFF_MVT;
    float* M2cT  = ws + OFF_M2T;
    float* RT2cT = ws + OFF_RT2T;
    float* RTc   = ws + OFF_RTC;
    float* Mg    = ws + OFF_MG;
    unsigned short* RTcAh = (unsigned short*)(ws + OFF_RTCAH);
    unsigned short* RTcAl = (unsigned short*)(ws + OFF_RTCAL);
    unsigned short* MvAh  = (unsigned short*)(ws + OFF_MVAH);
    unsigned short* MvAl  = (unsigned short*)(ws + OFF_MVAL);
    unsigned short* M2Ah  = (unsigned short*)(ws + OFF_M2AH);
    unsigned short* M2Al  = (unsigned short*)(ws + OFF_M2AL);
    unsigned short* RT2Bh = (unsigned short*)(ws + OFF_RT2BH);
    unsigned short* RT2Bl = (unsigned short*)(ws + OFF_RT2BL);
    float* ninv  = ws + OFF_NINV;
    float* sinv  = ws + OFF_SINV;
    unsigned short* WB  = (unsigned short*)(ws + OFF_WB);
    unsigned short* wub = WB + WB_WU;
    unsigned short* wvb = WB + WB_WV;
    unsigned short* wob = WB + WB_WO;
    unsigned short* whb = WB + WB_WH;
    unsigned short* wrob= WB + WB_WRO;
    unsigned short* tb16= (unsigned short*)(ws + OFF_TB16);
    float* pool  = ws + OFF_POOL;
    unsigned short* Ghat16 = (unsigned short*)pool;
    unsigned short* u16    = (unsigned short*)(pool + POOL_U16);
    unsigned short* vcm16  = (unsigned short*)(pool + POOL_VCM);
    unsigned short* Gh   = (unsigned short*)(pool + POOL_GH);
    unsigned short* Gl   = (unsigned short*)(pool + POOL_GL);
    unsigned short* TgFh = (unsigned short*)(pool + POOL_TGFH);
    unsigned short* TgFl = (unsigned short*)(pool + POOL_TGFL);
    unsigned short* xn16 = (unsigned short*)(ws + OFF_XN16);
    unsigned short* wuv  = (unsigned short*)(ws + OFF_WUV);
    float* buv   = ws + OFF_BUV;
    unsigned short* uyf  = (unsigned short*)(ws + OFF_UYF);
    unsigned short* GhA   = (unsigned short*)(ws + OFF_GHA);
    unsigned short* GlA   = (unsigned short*)(ws + OFF_GLA);
    unsigned short* TgFhA = (unsigned short*)(ws + OFF_TGFHA);
    unsigned short* TgFlA = (unsigned short*)(ws + OFF_TGFLA);
    unsigned short* GhatA = (unsigned short*)(ws + OFF_GHATA); // aliases GhA/GlA
    unsigned short* uv16  = (unsigned short*)(ws + OFF_UV16);
    float* tA    = out;                // rpe fp32 ping-pong in d_out
    float* tBf   = out + 6308352u;
    float* g_row_all = out;            // [12321][1024] fp32 in d_out scratch

    consts_k<<<533, 256, 0, stream>>>(RTc, MvT, Mg, M2cT, RT2cT);
    consts2_k<<<309, 256, 0, stream>>>(MvT, M2cT, RT2cT, RTcAh, RTcAl,
                                       MvAh, MvAl, M2Ah, M2Al, RT2Bh, RT2Bl);

    // weights -> bf16
    if (ext) {
        convuv_k<<<4096, 256, 0, stream>>>(W_u, W_v, b_u, b_v, wuv, buv);
    } else {
        convw_k<<<2048, 256, 0, stream>>>(W_u, wub, 524288);
        convw_k<<<2048, 256, 0, stream>>>(W_v, wvb, 524288);
    }
    convw_k<<<2048, 256, 0, stream>>>(W_o, wob, 524288);
    convw_k<<<3072, 256, 0, stream>>>(rpe_h_w, whb, 786432);
    convw_k<<<2048, 256, 0, stream>>>(rpe_out_w, wrob, 524288);

    // ---- RPE MLP hidden ladder ----
    t0_k<<<24642, 256, 0, stream>>>(rpe_in_w, rpe_in_b, tA);
    norms_k<<<3081, 256, 0, stream>>>(tA, sinv, GROWS);
    mgemm_k<<<dim3(4, 97), 256, 0, stream>>>(tA, whb, 512, nullptr, sinv, 1, 0,
        tBf, rpe_h_b, nullptr, nullptr, 0, 0, GROWS, 512, 512);
    norms_k<<<3081, 256, 0, stream>>>(tBf, sinv, GROWS);
    mgemm_k<<<dim3(4, 97), 256, 0, stream>>>(tBf, whb + 262144, 512, nullptr, sinv, 1, 0,
        tA, rpe_h_b + 512, nullptr, nullptr, 0, 0, GROWS, 512, 512);
    norms_k<<<3081, 256, 0, stream>>>(tA, sinv, GROWS);
    mgemm_k<<<dim3(4, 97), 256, 0, stream>>>(tA, whb + 524288, 512, nullptr, sinv, 1, 0,
        tBf, rpe_h_b + 1024, nullptr, nullptr, 0, 0, GROWS, 512, 512);
    norms_k<<<3081, 256, 0, stream>>>(tBf, sinv, GROWS);
    convt_k<<<24642, 256, 0, stream>>>(tBf, sinv, tb16);

    if (ext) {
        normx_k<<<6272, 256, 0, stream>>>(x, xn16);
    } else {
        norms_k<<<6272, 256, 0, stream>>>(x, ninv, ROWS);
    }

    // batched RPE-out GEMM for all heads: tb16 @ wrob^T -> g_row_all[12321][1024]
    mgemm_k<<<dim3(8, 97), 256, 0, stream>>>(tb16, wrob, 512, nullptr, nullptr, 0, 1,
        g_row_all, rpe_out_b, nullptr, nullptr, 0, 0, GROWS, 1024, 512);

    if (ext3) {
        // ---- batched all-heads g-spectrum: 4 launches ----
        gtr_k<<<dim3(386, 4, 8), dim3(32, 8), 0, stream>>>(g_row_all, 1024, GhA, GlA);
        pads_k<<<7548, 256, 0, stream>>>(GhA, GlA, TgFhA, TgFlA, 8);
        hilo_gemm_k<<<dim3(111, 2, 8), 256, 0, stream>>>(GhA, GlA, RTc, 0, 1,
            TgFhA, TgFlA, 0, 128, GH_STRIDE_US, TGF_STRIDE_US);
        hilo_gemm_k<<<dim3(2, 65, 8), 256, 0, stream>>>(TgFhA, TgFlA, Mg, 1, 0,
            GhatA, nullptr, 1, 224, TGF_STRIDE_US, GHAT_STRIDE_US);
    }

    // ---- per-head main path ----
    for (int h = 0; h < 8; ++h) {
        const size_t wo = (size_t)h * 65536;
        const unsigned short* ghat_h = ext3 ? (GhatA + (size_t)h * GHAT_STRIDE_US) : Ghat16;
        if (!ext3) {
            gtr_k<<<dim3(386, 4, 1), dim3(32, 8), 0, stream>>>(g_row_all + h * 128, 1024, Gh, Gl);
            pads_k<<<944, 256, 0, stream>>>(Gh, Gl, TgFh, TgFl, 1);
            hilo_gemm_k<<<dim3(111, 2), 256, 0, stream>>>(Gh, Gl, RTc, 0, 1,
                TgFh, TgFl, 0, 128, 0, 0);
            hilo_gemm_k<<<dim3(2, 65), 256, 0, stream>>>(TgFh, TgFl, Mg, 1, 0,
                Ghat16, nullptr, 1, 224, 0, 0);
        }
        if (ext5) {
            // u|v GEMM with clean row-major writes (emode 2, N=256) -> uv16;
            // then LDS-transpose v-half into vcm16 (both sides full-line).
            mgemm_k<<<dim3(2, 196), 256, 0, stream>>>(xn16, wuv + (size_t)h * 131072, 512,
                nullptr, nullptr, 0, 1,
                uv16, buv + h * 256, nullptr, nullptr, 0, 2, ROWS, 256, 512);
            vtr_k<<<dim3(98, 4, 8), dim3(32, 8), 0, stream>>>(uv16, vcm16);
        } else if (ext) {
            mgemm_k<<<dim3(2, 196), 256, 0, stream>>>(xn16, wuv + (size_t)h * 131072, 512,
                vcm16, nullptr, 0, 1,
                u16, buv + h * 256, nullptr, nullptr, 0, 5, ROWS, 256, 512);
        } else {
            mgemm_k<<<dim3(1, 196), 256, 0, stream>>>(x, wvb + wo, 512, nullptr, ninv, 0, 0,
                vcm16, b_v + h * 128, nullptr, nullptr, 0, 4, ROWS, 128, 512);
        }
        vfft_k<<<1024, 512, 0, stream>>>(vcm16, ghat_h, RTcAh, RTcAl, MvAh, MvAl,
            M2Ah, M2Al, RT2Bh, RT2Bl, MvT, M2cT, RT2cT);
        if (!ext) {
            mgemm_k<<<dim3(1, 196), 256, 0, stream>>>(x, wub + wo, 512, nullptr, ninv, 0, 0,
                u16, b_u + h * 128, nullptr, nullptr, 0, 2, ROWS, 128, 512);
        }
        if (ext2) {
            if (ext5) {
                fusey2_k<<<dim3(98, 4, 8), dim3(32, 8), 0, stream>>>(uv16, 256, vcm16, uyf, h);
            } else {
                fusey2_k<<<dim3(98, 4, 8), dim3(32, 8), 0, stream>>>(u16, 128, vcm16, uyf, h);
            }
        } else {
            fusey_k<<<dim3(98, 4, 8), dim3(32, 8), 0, stream>>>(u16, vcm16);
            mgemm_k<<<dim3(4, 196), 256, 0, stream>>>(u16, wob + h * 128, 1024, nullptr, nullptr, 0, 1,
                nullptr, b_o, x, out, (h == 0) ? 1 : 0, 3, ROWS, 512, 128);
        }
    }
    if (ext2) {
        // single output GEMM: out = uyf[25088x1024] @ W_o^T + b_o + x
        mgemm_k<<<dim3(4, 196), 256, 0, stream>>>(uyf, wob, 1024, nullptr, nullptr, 0, 1,
            nullptr, b_o, x, out, 1, 3, ROWS, 512, 1024);
    }
}

// Round 14
// 2273.435 us; speedup vs baseline: 1.6021x; 1.0193x over previous
//
#include <hip/hip_runtime.h>
#include <math.h>

// ---------------- problem sizes ----------------
#define NB 8
#define NN 56
#define POS 3136             // 56*56
#define ROWS 25088           // 8*3136
#define GR 111               // 2N-1
#define GROWS 12321          // 111*111
#define FREQ 16640           // per-channel spectrum: [kq 65][256] (re 128 | im 128)

// ---------------- workspace layout (float offsets), base 36.5 MB ----------------
#define OFF_MVT    0u
#define OFF_M2T    28672u
#define OFF_RT2T   57344u
#define OFF_RTC    64960u
#define OFF_MG     79392u
#define OFF_RTCAH  136224u
#define OFF_RTCAL  140384u
#define OFF_MVAH   144544u
#define OFF_MVAL   160928u
#define OFF_M2AH   177312u
#define OFF_M2AL   191648u
#define OFF_RT2BH  205984u
#define OFF_RT2BL  210592u
#define OFF_NINV   215200u
#define OFF_SINV   240288u
#define OFF_WB     252624u
#define OFF_TB16   1694416u
#define OFF_POOL   4848592u
#define WS_FLOATS  9124816u   // 36.5 MB
// ---- ext1: fused u|v projection ----
#define OFF_XN16   9124816u   // 25088x512 bf16 = 6,422,528 fl
#define OFF_WUV    15547344u  // [8][256][512] bf16 = 524,288 fl
#define OFF_BUV    16071632u  // [2048] fp32
#define WS_EXT     16073680u  // 64.3 MB
// ---- ext2: single K=1024 output GEMM ----
#define OFF_UYF    16073680u  // 25088x1024 bf16 = 12,845,056 fl
#define WS_EXT2    28918736u  // 115.7 MB
// ---- ext3: batched all-heads g-spectrum pipeline ----
#define GH_STRIDE_US   1818624u   // 14208*128
#define TGF_STRIDE_US  1863680u   // 16640*112 (= 8320*224)
#define GHAT_STRIDE_US 2129920u   // 128*65*256
#define OFF_GHA    28918736u  // [8]*GH_STRIDE bf16 = 7,274,496 fl
#define OFF_GLA    36193232u  // 7,274,496 fl
#define OFF_TGFHA  43467728u  // [8]*TGF_STRIDE bf16 = 7,454,720 fl
#define OFF_TGFLA  50922448u  // 7,454,720 fl
#define OFF_GHATA  28918736u  // [8]*GHAT_STRIDE bf16 — ALIASES GhA/GlA (dead after stage1)
#define WS_EXT3    58377168u  // 233.5 MB
// ---- ext5: row-major uv16 staging ----
#define OFF_UV16   58377168u  // [25088][256] bf16 = 6,422,528 fl
#define WS_EXT5    64799696u  // 259.2 MB (r10 proved ws >= 284.9 MB)
// r12 post-mortem: the 151us/134.8MB dispatches are the RPE-ladder GEMMs
// (amode-0 fp32 A read 4x = 100.9 MB), NOT the uv GEMMs. Fix: normt_k
// pre-stages bf16(relu*sinv) once; ladder runs amode 1 (A traffic halved).
// WB sub-offsets (ushort units)
#define WB_WU  0u
#define WB_WV  524288u
#define WB_WO  1048576u
#define WB_WH  1572864u
#define WB_WRO 2359296u
// pool sub-offsets (fl units) — fallback (non-ext3) per-head g-path:
#define POOL_U16   1064960u
#define POOL_VCM   2670592u
#define POOL_GH    0u
#define POOL_GL    909312u
#define POOL_TGFH  1818624u
#define POOL_TGFL  2750464u
// ladder-time overlay: tbA bf16 [12321][512] = 3,154,176 fl at pool+0
// (pool is dead until the per-head loop starts)

typedef __attribute__((ext_vector_type(8))) short bf8_t;
typedef __attribute__((ext_vector_type(8))) unsigned short us8_t;
typedef __attribute__((ext_vector_type(4))) float f4_t;

__device__ inline float bf2f(unsigned short b) {
    union { unsigned u; float f; } v; v.u = ((unsigned)b) << 16; return v.f;
}
__device__ inline unsigned short f2bf(float f) {
    union { float f; unsigned u; } v; v.f = f;
    unsigned r = v.u + 0x7FFF + ((v.u >> 16) & 1);
    return (unsigned short)(r >> 16);
}

__global__ void probe_k(float* out, float code) { out[0] = code; }

// =====================================================================
// fp32 constants (gfft + vfft Nyquist tail). angle reduced: (a*b) mod 128
// =====================================================================
__global__ void consts_k(float* RTc, float* MvT, float* Mg, float* M2cT, float* RT2cT) {
    int idx = blockIdx.x * 256 + threadIdx.x;
    const float STEP = 0.049087385212340526f; // 2*pi/128
    if (idx < 14430) { // RTc[q*130+col]: gfft row DFT
        int q = idx / 130, col = idx % 130;
        int a = (col < 65) ? col : col - 65;
        float th = (float)((a * q) & 127) * STEP;
        RTc[idx] = (col < 65) ? cosf(th) : -sinf(th);
        return;
    }
    idx -= 14430;
    if (idx < 28672) { // MvT[s*256+r]
        int s = idx / 256, r = idx % 256;
        int kp = (r < 128) ? r : r - 128;
        int sp = (s < 56) ? s : s - 56;
        float th = (float)((kp * sp) & 127) * STEP;
        float cv = cosf(th), sv = sinf(th);
        MvT[idx] = (r < 128) ? ((s < 56) ? cv : sv) : ((s < 56) ? -sv : cv);
        return;
    }
    idx -= 28672;
    if (idx < 56832) { // Mg[r*222+s]: gfft col DFT
        int r = idx / 222, s = idx % 222;
        int kp = (r < 128) ? r : r - 128;
        int sp = (s < 111) ? s : s - 111;
        float th = (float)((kp * sp) & 127) * STEP;
        float cv = cosf(th), sv = sinf(th);
        Mg[idx] = (r < 128) ? ((s < 111) ? cv : sv) : ((s < 111) ? -sv : cv);
        return;
    }
    idx -= 56832;
    if (idx < 28672) { // M2cT[s*112+r]
        int s = idx / 112, r = idx % 112;
        int a = (r < 56) ? (r + 55) : (r - 1);
        int kp = (s < 128) ? s : s - 128;
        float th = (float)((kp * a) & 127) * STEP;
        float cv = cosf(th), sv = sinf(th);
        M2cT[idx] = (r < 56) ? ((s < 128) ? cv : -sv) : ((s < 128) ? sv : cv);
        return;
    }
    idx -= 28672;
    if (idx < 7616) { // RT2cT[b*136+col], w/L^2 folded
        int b = idx / 136, col = idx % 136;
        float val = 0.f;
        if (col < 65 || (col >= 68 && col < 133)) {
            int kq = (col < 65) ? col : col - 68;
            float w = (kq == 0 || kq == 64) ? 1.f : 2.f;
            float th = (float)((kq * (b + 55)) & 127) * STEP;
            val = ((col < 65) ? cosf(th) : -sinf(th)) * w * (1.f / 16384.f);
        }
        RT2cT[idx] = val;
    }
}

// =====================================================================
// bf16 hi/lo MFMA constants (derived from fp32 consts; run after consts_k)
// =====================================================================
__global__ void consts2_k(const float* __restrict__ MvT, const float* __restrict__ M2cT,
                          const float* __restrict__ RT2cT,
                          unsigned short* RTcAh, unsigned short* RTcAl,
                          unsigned short* MvAh, unsigned short* MvAl,
                          unsigned short* M2Ah, unsigned short* M2Al,
                          unsigned short* RT2Bh, unsigned short* RT2Bl) {
    int idx = blockIdx.x * 256 + threadIdx.x;
    const float STEP = 0.049087385212340526f;
    float v = 0.f; unsigned short *ph, *pl; int off;
    if (idx < 8320) {               // RTcA [130 rows (65 re | 65 im)][64]
        int row = idx >> 6, q = idx & 63;
        if (q < 56) {
            int kq = (row < 65) ? row : row - 65;
            float th = (float)((kq * q) & 127) * STEP;
            v = (row < 65) ? cosf(th) : -sinf(th);
        }
        ph = RTcAh; pl = RTcAl; off = idx;
    } else if (idx < 41088) {       // MvA [256][128] (cols 112..127 zero)
        int i = idx - 8320; int r = i >> 7, s = i & 127;
        if (s < 112) v = MvT[s * 256 + r];
        ph = MvAh; pl = MvAl; off = i;
    } else if (idx < 69760) {       // M2A [112][256]
        int i = idx - 41088; int a = i >> 8, r = i & 255;
        v = M2cT[r * 112 + a];
        ph = M2Ah; pl = M2Al; off = i;
    } else if (idx < 78976) {       // RT2B [64][144]: 0..64 re | 72..136 im
        int i = idx - 69760; int bq = i / 144, col = i % 144;
        if (bq < 56) {
            if (col < 65) v = RT2cT[bq * 136 + col];
            else if (col >= 72 && col < 137) v = RT2cT[bq * 136 + 68 + (col - 72)];
        }
        ph = RT2Bh; pl = RT2Bl; off = i;
    } else return;
    unsigned short h = f2bf(v);
    ph[off] = h;
    pl[off] = f2bf(v - bf2f(h));
}

// =====================================================================
// row L2 norms -> inverse simple-rms scale, D=512 (fallback path)
// =====================================================================
__global__ void norms_k(const float* __restrict__ X, float* __restrict__ out, int rows) {
    int row = blockIdx.x * 4 + (threadIdx.x >> 6);
    int lane = threadIdx.x & 63;
    if (row >= rows) return;
    const float* p = X + (size_t)row * 512;
    float s = 0.f;
    #pragma unroll
    for (int i = 0; i < 8; ++i) { float v = p[lane + 64 * i]; s += v * v; }
    #pragma unroll
    for (int o = 32; o > 0; o >>= 1) s += __shfl_down(s, o, 64);
    if (lane == 0) out[row] = 1.f / (sqrtf(s) * 0.04419417382415922f + 1e-8f);
}

// =====================================================================
// fused row-norm + bf16(x*ninv): one pass over x.
// =====================================================================
__global__ void normx_k(const float* __restrict__ X, unsigned short* __restrict__ xn) {
    int row = blockIdx.x * 4 + (threadIdx.x >> 6);
    int lane = threadIdx.x & 63;
    if (row >= ROWS) return;
    const float* p = X + (size_t)row * 512 + lane * 8;
    float4 f1 = *(const float4*)p, f2 = *(const float4*)(p + 4);
    float s = f1.x * f1.x + f1.y * f1.y + f1.z * f1.z + f1.w * f1.w
            + f2.x * f2.x + f2.y * f2.y + f2.z * f2.z + f2.w * f2.w;
    #pragma unroll
    for (int o = 32; o > 0; o >>= 1) s += __shfl_down(s, o, 64);
    s = __shfl(s, 0, 64);
    float inv = 1.f / (sqrtf(s) * 0.04419417382415922f + 1e-8f);
    us8_t o;
    o[0] = f2bf(f1.x * inv); o[1] = f2bf(f1.y * inv);
    o[2] = f2bf(f1.z * inv); o[3] = f2bf(f1.w * inv);
    o[4] = f2bf(f2.x * inv); o[5] = f2bf(f2.y * inv);
    o[6] = f2bf(f2.z * inv); o[7] = f2bf(f2.w * inv);
    *(us8_t*)(xn + (size_t)row * 512 + lane * 8) = o;
}

// =====================================================================
// fused row-norm + bf16(relu(t)*sinv): one pass over fp32 ladder output.
// Identical bits to the old norms_k + amode-0 staging (fmax then *s).
// =====================================================================
__global__ void normt_k(const float* __restrict__ T, unsigned short* __restrict__ tn) {
    int row = blockIdx.x * 4 + (threadIdx.x >> 6);
    int lane = threadIdx.x & 63;
    if (row >= GROWS) return;
    const float* p = T + (size_t)row * 512 + lane * 8;
    float4 f1 = *(const float4*)p, f2 = *(const float4*)(p + 4);
    float s = f1.x * f1.x + f1.y * f1.y + f1.z * f1.z + f1.w * f1.w
            + f2.x * f2.x + f2.y * f2.y + f2.z * f2.z + f2.w * f2.w;
    #pragma unroll
    for (int o = 32; o > 0; o >>= 1) s += __shfl_down(s, o, 64);
    s = __shfl(s, 0, 64);
    float inv = 1.f / (sqrtf(s) * 0.04419417382415922f + 1e-8f);
    us8_t o;
    o[0] = f2bf(fmaxf(f1.x, 0.f) * inv); o[1] = f2bf(fmaxf(f1.y, 0.f) * inv);
    o[2] = f2bf(fmaxf(f1.z, 0.f) * inv); o[3] = f2bf(fmaxf(f1.w, 0.f) * inv);
    o[4] = f2bf(fmaxf(f2.x, 0.f) * inv); o[5] = f2bf(fmaxf(f2.y, 0.f) * inv);
    o[6] = f2bf(fmaxf(f2.z, 0.f) * inv); o[7] = f2bf(fmaxf(f2.w, 0.f) * inv);
    *(us8_t*)(tn + (size_t)row * 512 + lane * 8) = o;
}

// =====================================================================
// fused t0 + row-norm + bf16(relu*sinv): computes t0 row in registers
// (never materializes fp32 t0). One wave per row; lane holds 8 cols.
// =====================================================================
__global__ void t0n_k(const float* __restrict__ w, const float* __restrict__ b,
                      unsigned short* __restrict__ tn) {
    int row = blockIdx.x * 4 + (threadIdx.x >> 6);
    int lane = threadIdx.x & 63;
    if (row >= GROWS) return;
    int i = row / 111, j = row % 111;
    float dp = (float)(i - 55), dq = (float)(j - 55);
    int c8 = lane * 8;
    float4 w0 = *(const float4*)(w + c8 * 2);       // w[c8..c8+1] pairs
    float4 w1 = *(const float4*)(w + c8 * 2 + 4);
    float4 w2 = *(const float4*)(w + c8 * 2 + 8);
    float4 w3 = *(const float4*)(w + c8 * 2 + 12);
    float4 b0 = *(const float4*)(b + c8);
    float4 b1 = *(const float4*)(b + c8 + 4);
    float v[8];
    v[0] = dp * w0.x + dq * w0.y + b0.x;
    v[1] = dp * w0.z + dq * w0.w + b0.y;
    v[2] = dp * w1.x + dq * w1.y + b0.z;
    v[3] = dp * w1.z + dq * w1.w + b0.w;
    v[4] = dp * w2.x + dq * w2.y + b1.x;
    v[5] = dp * w2.z + dq * w2.w + b1.y;
    v[6] = dp * w3.x + dq * w3.y + b1.z;
    v[7] = dp * w3.z + dq * w3.w + b1.w;
    float s = 0.f;
    #pragma unroll
    for (int k = 0; k < 8; ++k) s += v[k] * v[k];
    #pragma unroll
    for (int o = 32; o > 0; o >>= 1) s += __shfl_down(s, o, 64);
    s = __shfl(s, 0, 64);
    float inv = 1.f / (sqrtf(s) * 0.04419417382415922f + 1e-8f);
    us8_t o;
    #pragma unroll
    for (int k = 0; k < 8; ++k) o[k] = f2bf(fmaxf(v[k], 0.f) * inv);
    *(us8_t*)(tn + (size_t)row * 512 + c8) = o;
}

__global__ void convw_k(const float* __restrict__ src, unsigned short* __restrict__ dst, int n) {
    int i = blockIdx.x * 256 + threadIdx.x;
    if (i < n) dst[i] = f2bf(src[i]);
}

// wuv[h*256 + j][k]: j<128 -> W_u row h*128+j; else W_v row h*128+j-128.
__global__ void convuv_k(const float* __restrict__ Wu, const float* __restrict__ Wv,
                         const float* __restrict__ bu, const float* __restrict__ bv,
                         unsigned short* __restrict__ wuv, float* __restrict__ buv) {
    int i = blockIdx.x * 256 + threadIdx.x;      // 1,048,576 exact -> 4096 blocks
    if (i < 1048576) {
        int row = i >> 9, k = i & 511;
        int h = row >> 8, j = row & 255;
        float v = (j < 128) ? Wu[(size_t)(h * 128 + j) * 512 + k]
                            : Wv[(size_t)(h * 128 + j - 128) * 512 + k];
        wuv[i] = f2bf(v);
    }
    if (i < 2048) {
        int h = i >> 8, j = i & 255;
        buv[i] = (j < 128) ? bu[h * 128 + j] : bv[h * 128 + j - 128];
    }
}

// =====================================================================
// bf16 MFMA GEMM (verified fragment pattern), epilogue/amode variants
//  amode 0: A fp32 rm -> relu?*scale -> bf16 ; amode 1: A bf16 rm
//  amode 2: A = bf16(u*y gather) — legacy
//  emode 0: fp32 rm +bias ; emode 2: bf16 rm +bias+silu
//  emode 3: out accum (+bias+xres if first) ; emode 4: bf16 cm +bias+silu
//  emode 5: split u|v one head (scatter — superseded)
// =====================================================================
__global__ __launch_bounds__(256) void mgemm_k(
    const void* __restrict__ Aptr, const unsigned short* __restrict__ B, int ldb,
    const unsigned short* __restrict__ yv, const float* __restrict__ scale,
    int relu_in, int amode,
    void* __restrict__ Cptr, const float* __restrict__ bias,
    const float* __restrict__ xres, float* __restrict__ outAcc, int first,
    int emode, int M, int N, int K)
{
    __shared__ __align__(16) unsigned short As[4096];
    __shared__ __align__(16) unsigned short Bs[4096];
    const int t = threadIdx.x;
    const int lane = t & 63;
    const int quad = lane >> 4, ln = lane & 15;
    const int wave = t >> 6;
    const int wm = (wave >> 1) << 6, wn = (wave & 1) << 6;
    const int row0 = blockIdx.y << 7, col0 = blockIdx.x << 7;
    const int sc = t & 3;
    const int sm = t >> 2;
    const float* Af = (const float*)Aptr;
    const unsigned short* Au = (const unsigned short*)Aptr;
    f4_t acc[4][4];
    #pragma unroll
    for (int i = 0; i < 4; ++i)
        #pragma unroll
        for (int j = 0; j < 4; ++j)
            acc[i][j] = (f4_t){0.f, 0.f, 0.f, 0.f};

    for (int k0 = 0; k0 < K; k0 += 32) {
        #pragma unroll
        for (int rep = 0; rep < 2; ++rep) {
            const int m = sm + (rep << 6);
            const int am = row0 + m;
            us8_t av = {0, 0, 0, 0, 0, 0, 0, 0};
            if (am < M) {
                if (amode == 0) {
                    const float s = scale ? scale[am] : 1.f;
                    const float* ap = Af + (size_t)am * K + k0 + (sc << 3);
                    float4 f1 = *(const float4*)ap;
                    float4 f2 = *(const float4*)(ap + 4);
                    if (relu_in) {
                        f1.x = fmaxf(f1.x, 0.f); f1.y = fmaxf(f1.y, 0.f);
                        f1.z = fmaxf(f1.z, 0.f); f1.w = fmaxf(f1.w, 0.f);
                        f2.x = fmaxf(f2.x, 0.f); f2.y = fmaxf(f2.y, 0.f);
                        f2.z = fmaxf(f2.z, 0.f); f2.w = fmaxf(f2.w, 0.f);
                    }
                    av[0] = f2bf(f1.x * s); av[1] = f2bf(f1.y * s);
                    av[2] = f2bf(f1.z * s); av[3] = f2bf(f1.w * s);
                    av[4] = f2bf(f2.x * s); av[5] = f2bf(f2.y * s);
                    av[6] = f2bf(f2.z * s); av[7] = f2bf(f2.w * s);
                } else if (amode == 1) {
                    av = *(const us8_t*)(Au + (size_t)am * K + k0 + (sc << 3));
                } else {
                    const unsigned short* up = Au + (size_t)am * K + k0 + (sc << 3);
                    const int bb = am / POS, pos = am - bb * POS;
                    const unsigned short* yb = yv + ((size_t)(bb * 128 + k0 + (sc << 3))) * POS + pos;
                    #pragma unroll
                    for (int j = 0; j < 8; ++j)
                        av[j] = f2bf(bf2f(up[j]) * bf2f(yb[(size_t)j * POS]));
                }
            }
            *(us8_t*)&As[(sc << 10) + (m << 3)] = av;
        }
        #pragma unroll
        for (int rep = 0; rep < 2; ++rep) {
            const int n = sm + (rep << 6);
            us8_t bv = *(const us8_t*)(B + (size_t)(col0 + n) * ldb + k0 + (sc << 3));
            *(us8_t*)&Bs[(sc << 10) + (n << 3)] = bv;
        }
        __syncthreads();
        bf8_t af[4], bfr[4];
        #pragma unroll
        for (int i = 0; i < 4; ++i)
            af[i] = *(const bf8_t*)&As[(quad << 10) + ((wm + (i << 4) + ln) << 3)];
        #pragma unroll
        for (int i = 0; i < 4; ++i)
            bfr[i] = *(const bf8_t*)&Bs[(quad << 10) + ((wn + (i << 4) + ln) << 3)];
        #pragma unroll
        for (int i = 0; i < 4; ++i)
            #pragma unroll
            for (int j = 0; j < 4; ++j)
                acc[i][j] = __builtin_amdgcn_mfma_f32_16x16x32_bf16(af[i], bfr[j], acc[i][j], 0, 0, 0);
        __syncthreads();
    }
    #pragma unroll
    for (int i = 0; i < 4; ++i) {
        #pragma unroll
        for (int j = 0; j < 4; ++j) {
            #pragma unroll
            for (int rr = 0; rr < 4; ++rr) {
                const int r = row0 + wm + (i << 4) + (quad << 2) + rr;
                const int c = col0 + wn + (j << 4) + ln;
                if (r >= M) continue;
                float v = acc[i][j][rr];
                if (emode == 0) {
                    v += bias[c];
                    ((float*)Cptr)[(size_t)r * N + c] = v;
                } else if (emode == 2) {
                    v += bias[c]; v = v / (1.f + expf(-v));
                    ((unsigned short*)Cptr)[(size_t)r * N + c] = f2bf(v);
                } else if (emode == 4) {
                    v += bias[c]; v = v / (1.f + expf(-v));
                    const int bb = r / POS, pos = r - bb * POS;
                    ((unsigned short*)Cptr)[((size_t)(bb * 128 + c)) * POS + pos] = f2bf(v);
                } else if (emode == 5) {
                    v += bias[c]; v = v / (1.f + expf(-v));
                    unsigned short bv16 = f2bf(v);
                    if (c < 128) {
                        ((unsigned short*)Cptr)[(size_t)r * 128 + c] = bv16;
                    } else {
                        const int bb = r / POS, pos = r - bb * POS;
                        ((unsigned short*)yv)[((size_t)(bb * 128 + (c - 128))) * POS + pos] = bv16;
                    }
                } else {
                    const size_t oi = (size_t)r * 512 + c;
                    v += first ? (bias[c] + xres[oi]) : outAcc[oi];
                    outAcc[oi] = v;
                }
            }
        }
    }
}

// =====================================================================
// fused transpose + bf16 hi/lo split (head-batched via blockIdx.z)
// =====================================================================
__global__ void gtr_k(const float* __restrict__ src, int ld,
                      unsigned short* __restrict__ Gh, unsigned short* __restrict__ Gl) {
    __shared__ float tile[32][33];
    const int z = blockIdx.z;
    src += (size_t)z * 128;
    Gh += (size_t)z * GH_STRIDE_US;
    Gl += (size_t)z * GH_STRIDE_US;
    int s0 = blockIdx.x * 32, d0 = blockIdx.y * 32;
    int tx = threadIdx.x, ty = threadIdx.y;
    #pragma unroll
    for (int i = 0; i < 32; i += 8) {
        int s = s0 + ty + i;
        if (s < GROWS) tile[ty + i][tx] = src[(size_t)s * ld + d0 + tx];
    }
    __syncthreads();
    int s = s0 + tx;
    if (s < GROWS) {
        int p = s / 111, q = s - p * 111;
        #pragma unroll
        for (int i = 0; i < 32; i += 8) {
            int d = d0 + ty + i;
            float v = tile[tx][ty + i];
            unsigned short h = f2bf(v);
            size_t o = (size_t)(d * 111 + p) * 128 + q;
            Gh[o] = h;
            Gl[o] = f2bf(v - bf2f(h));
        }
    }
}

// zero GEMM pad slots for nh heads (head-strided)
__global__ void pads_k(unsigned short* __restrict__ Gh, unsigned short* __restrict__ Gl,
                       unsigned short* __restrict__ TgFh, unsigned short* __restrict__ TgFl,
                       int nh) {
    int i = blockIdx.x * 256 + threadIdx.x;
    if (i < nh * 16640) {
        int h = i / 16640, r = i % 16640;
        size_t o = (size_t)h * TGF_STRIDE_US + (size_t)r * 112 + 111;
        TgFh[o] = 0; TgFl[o] = 0;
    }
    if (i < nh * 241536) {
        int h = i / 241536, j = i % 241536;
        int r = j / 17, c = 111 + j % 17;
        size_t o = (size_t)h * GH_STRIDE_US + (size_t)r * 128 + c;
        Gh[o] = 0; Gl[o] = 0;
    }
}

// =====================================================================
// v transpose (ext5): vcm16[(bb*128+ch)*POS+pos] = uv16[(bb*POS+pos)*256+128+ch]
// =====================================================================
__global__ void vtr_k(const unsigned short* __restrict__ uv, unsigned short* __restrict__ vcm) {
    __shared__ unsigned short tile[32][34];
    const int pos0 = blockIdx.x * 32, ch0 = blockIdx.y * 32, bb = blockIdx.z;
    const int tx = threadIdx.x, ty = threadIdx.y;
    #pragma unroll
    for (int i = 0; i < 32; i += 8) {
        tile[ty + i][tx] = uv[((size_t)(bb * POS + pos0 + ty + i)) * 256 + 128 + ch0 + tx];
    }
    __syncthreads();
    #pragma unroll
    for (int i = 0; i < 32; i += 8) {
        vcm[((size_t)(bb * 128 + ch0 + ty + i)) * POS + pos0 + tx] = tile[tx][ty + i];
    }
}

// =====================================================================
// fuse u *= y  (in place on u16) — fallback path.
// =====================================================================
__global__ void fusey_k(unsigned short* __restrict__ u, const unsigned short* __restrict__ y) {
    __shared__ unsigned short yt[32][34];
    const int pos0 = blockIdx.x * 32, k0 = blockIdx.y * 32, bb = blockIdx.z;
    const int tx = threadIdx.x, ty = threadIdx.y;
    #pragma unroll
    for (int i = 0; i < 32; i += 8) {
        int k = k0 + ty + i;
        yt[ty + i][tx] = y[((size_t)(bb * 128 + k)) * POS + pos0 + tx];
    }
    __syncthreads();
    #pragma unroll
    for (int i = 0; i < 32; i += 8) {
        size_t r = (size_t)bb * POS + pos0 + ty + i;
        size_t idx = r * 128 + k0 + tx;
        u[idx] = f2bf(bf2f(u[idx]) * bf2f(yt[tx][ty + i]));
    }
}

// =====================================================================
// fuse u*y -> uyf[r][h*128+k]. u has row stride lda (128 for u16, 256 for uv16).
// =====================================================================
__global__ void fusey2_k(const unsigned short* __restrict__ u, int lda,
                         const unsigned short* __restrict__ y,
                         unsigned short* __restrict__ uyf, int h) {
    __shared__ unsigned short yt[32][34];
    const int pos0 = blockIdx.x * 32, k0 = blockIdx.y * 32, bb = blockIdx.z;
    const int tx = threadIdx.x, ty = threadIdx.y;
    #pragma unroll
    for (int i = 0; i < 32; i += 8) {
        int k = k0 + ty + i;
        yt[ty + i][tx] = y[((size_t)(bb * 128 + k)) * POS + pos0 + tx];
    }
    __syncthreads();
    #pragma unroll
    for (int i = 0; i < 32; i += 8) {
        size_t r = (size_t)bb * POS + pos0 + ty + i;
        unsigned short uv = u[r * lda + k0 + tx];
        uyf[r * 1024 + h * 128 + k0 + tx] = f2bf(bf2f(uv) * bf2f(yt[tx][ty + i]));
    }
}

// =====================================================================
// hi/lo bf16 GEMM (3-product). Head-batched via blockIdx.z (zD/zC strides).
// =====================================================================
__device__ inline float cval(const float* __restrict__ Csrc, int cmode, int row, int kk) {
    if (cmode == 0)
        return (kk < 111 && row < 130) ? Csrc[kk * 130 + row] : 0.f;
    int s = (kk < 112) ? kk : (111 + (kk - 112));
    bool ok = (kk < 112) ? (kk < 111) : (kk < 223);
    return ok ? Csrc[(size_t)row * 222 + s] : 0.f;
}

__global__ __launch_bounds__(256) void hilo_gemm_k(
    const unsigned short* __restrict__ Dh, const unsigned short* __restrict__ Dl,
    const float* __restrict__ Csrc, int cmode, int constIsA,
    unsigned short* __restrict__ C0, unsigned short* __restrict__ C1,
    int omode, int K, unsigned zD, unsigned zC)
{
    __shared__ __align__(16) unsigned short Ash[4096];
    __shared__ __align__(16) unsigned short Asl[4096];
    __shared__ __align__(16) unsigned short Bsh[4096];
    __shared__ __align__(16) unsigned short Bsl[4096];
    const int t = threadIdx.x;
    const int lane = t & 63;
    const int quad = lane >> 4, ln = lane & 15;
    const int wave = t >> 6;
    const int wm = (wave >> 1) << 6, wn = (wave & 1) << 6;
    const int row0 = blockIdx.y << 7, col0 = blockIdx.x << 7;
    const int sc = t & 3, sm = t >> 2;
    const size_t zoffD = (size_t)blockIdx.z * zD, zoffC = (size_t)blockIdx.z * zC;
    Dh += zoffD; Dl += zoffD;
    C0 += zoffC; if (C1) C1 += zoffC;
    f4_t acc[4][4];
    #pragma unroll
    for (int i = 0; i < 4; ++i)
        #pragma unroll
        for (int j = 0; j < 4; ++j)
            acc[i][j] = (f4_t){0.f, 0.f, 0.f, 0.f};

    for (int k0 = 0; k0 < K; k0 += 32) {
        #pragma unroll
        for (int rep = 0; rep < 2; ++rep) {
            const int m = sm + (rep << 6);
            // ---- A tile ----
            {
                const int gr = row0 + m;
                us8_t hv, lv;
                if (constIsA) {
                    #pragma unroll
                    for (int j = 0; j < 8; ++j) {
                        int kk = k0 + (sc << 3) + j;
                        float v = cval(Csrc, cmode, gr, kk);
                        unsigned short h = f2bf(v);
                        hv[j] = h; lv[j] = f2bf(v - bf2f(h));
                    }
                } else {
                    hv = *(const us8_t*)(Dh + (size_t)gr * K + k0 + (sc << 3));
                    lv = *(const us8_t*)(Dl + (size_t)gr * K + k0 + (sc << 3));
                }
                *(us8_t*)&Ash[(sc << 10) + (m << 3)] = hv;
                *(us8_t*)&Asl[(sc << 10) + (m << 3)] = lv;
            }
            // ---- B tile ----
            {
                const int gc = col0 + m;
                us8_t hv, lv;
                if (constIsA) {
                    hv = *(const us8_t*)(Dh + (size_t)gc * K + k0 + (sc << 3));
                    lv = *(const us8_t*)(Dl + (size_t)gc * K + k0 + (sc << 3));
                } else {
                    #pragma unroll
                    for (int j = 0; j < 8; ++j) {
                        int kk = k0 + (sc << 3) + j;
                        float v = cval(Csrc, cmode, gc, kk);
                        unsigned short h = f2bf(v);
                        hv[j] = h; lv[j] = f2bf(v - bf2f(h));
                    }
                }
                *(us8_t*)&Bsh[(sc << 10) + (m << 3)] = hv;
                *(us8_t*)&Bsl[(sc << 10) + (m << 3)] = lv;
            }
        }
        __syncthreads();
        bf8_t ah[4], al[4], bh[4], bl[4];
        #pragma unroll
        for (int i = 0; i < 4; ++i) {
            ah[i] = *(const bf8_t*)&Ash[(quad << 10) + ((wm + (i << 4) + ln) << 3)];
            al[i] = *(const bf8_t*)&Asl[(quad << 10) + ((wm + (i << 4) + ln) << 3)];
            bh[i] = *(const bf8_t*)&Bsh[(quad << 10) + ((wn + (i << 4) + ln) << 3)];
            bl[i] = *(const bf8_t*)&Bsl[(quad << 10) + ((wn + (i << 4) + ln) << 3)];
        }
        #pragma unroll
        for (int i = 0; i < 4; ++i)
            #pragma unroll
            for (int j = 0; j < 4; ++j) {
                acc[i][j] = __builtin_amdgcn_mfma_f32_16x16x32_bf16(ah[i], bh[j], acc[i][j], 0, 0, 0);
                acc[i][j] = __builtin_amdgcn_mfma_f32_16x16x32_bf16(ah[i], bl[j], acc[i][j], 0, 0, 0);
                acc[i][j] = __builtin_amdgcn_mfma_f32_16x16x32_bf16(al[i], bh[j], acc[i][j], 0, 0, 0);
            }
        __syncthreads();
    }
    #pragma unroll
    for (int i = 0; i < 4; ++i) {
        #pragma unroll
        for (int j = 0; j < 4; ++j) {
            #pragma unroll
            for (int rr = 0; rr < 4; ++rr) {
                const int r = row0 + wm + (i << 4) + (quad << 2) + rr;
                const int c = col0 + wn + (j << 4) + ln;
                float v = acc[i][j][rr];
                if (omode == 1) {
                    C0[(size_t)r * 256 + c] = f2bf(v);
                } else {
                    if (r < 130) {
                        int kq = (r < 65) ? r : r - 65;
                        int im = (r < 65) ? 0 : 1;
                        int d = c / 111, p = c - d * 111;
                        size_t o = ((size_t)((d * 65 + kq) * 2 + im)) * 112 + p;
                        unsigned short h = f2bf(v);
                        C0[o] = h;
                        C1[o] = f2bf(v - bf2f(h));
                    }
                }
            }
        }
    }
}

// =====================================================================
// v conv (one head, in-place bf16): MFMA DFT stages per channel workgroup.
// Round-0 body, plain __launch_bounds__(512): VGPR 88, 2 blocks/CU,
// no spill, ~142-149 us. All restructurings regressed (r2/r3/r8/r10).
// =====================================================================
__global__ __launch_bounds__(512) void vfft_k(
    unsigned short* __restrict__ vcm, const unsigned short* __restrict__ Ghat,
    const unsigned short* __restrict__ RTcAh, const unsigned short* __restrict__ RTcAl,
    const unsigned short* __restrict__ MvAh,  const unsigned short* __restrict__ MvAl,
    const unsigned short* __restrict__ M2Ah,  const unsigned short* __restrict__ M2Al,
    const unsigned short* __restrict__ RT2Bh, const unsigned short* __restrict__ RT2Bl,
    const float* __restrict__ MvT, const float* __restrict__ M2cT,
    const float* __restrict__ RT2cT)
{
    __shared__ __align__(16) unsigned short Vs[64 * 72];    // [p][q] bf16, zero-pad
    __shared__ __align__(16) unsigned short TqT[32 * 136];  // [kqL][s(112)+pad]
    __shared__ __align__(16) unsigned short VhT[32 * 264];  // [kqL][r(256)+pad]
    __shared__ __align__(16) unsigned short QA[64 * 72];    // [p][k(64)+pad]
    __shared__ float tmp[424];                              // Nyquist temps
    const int tid = threadIdx.x;
    const int lane = tid & 63, wave = tid >> 6;
    const int quad = lane >> 4, ln = lane & 15;
    const int d = blockIdx.x >> 3, b = blockIdx.x & 7;
    unsigned short* chan = vcm + (size_t)(b * 128 + d) * POS;
    const unsigned short* ghd = Ghat + (size_t)d * FREQ;

    for (int i = tid; i < 64 * 72; i += 512) { Vs[i] = 0; QA[i] = 0; }
    {   // TqT K-pad cols 112..127 zero (rows 0..31)
        int rr = tid >> 4, cc = 112 + (tid & 15);
        if (tid < 512) TqT[rr * 136 + cc] = 0;
    }
    __syncthreads();
    for (int i = tid; i < POS; i += 512) {
        int p = i / 56, q = i - p * 56;
        Vs[p * 72 + q] = chan[i];
    }
    f4_t acc5[2] = { (f4_t){0,0,0,0}, (f4_t){0,0,0,0} };
    __syncthreads();

    // ===== Nyquist kq=64 tail (fp32 VALU, tiny) =====
    if (tid < 56) {
        const unsigned short* vp = Vs + tid * 72;
        float a = 0.f;
        for (int q = 0; q < 56; q += 2) a += bf2f(vp[q]) - bf2f(vp[q + 1]);
        tmp[tid] = a;
    }
    __syncthreads();
    if (tid < 256) {
        float a = 0.f;
        for (int s = 0; s < 56; ++s) a = fmaf(MvT[s * 256 + tid], tmp[s], a);
        tmp[56 + tid] = a;
    }
    __syncthreads();
    if (tid < 128) {
        float vr = tmp[56 + tid], vi = tmp[184 + tid];
        float gr = bf2f(ghd[64 * 256 + tid]), gm = bf2f(ghd[64 * 256 + 128 + tid]);
        tmp[56 + tid] = vr * gr - vi * gm;
        tmp[184 + tid] = vr * gm + vi * gr;
    }
    __syncthreads();
    if (tid < 112) {
        float a = 0.f;
        for (int r = 0; r < 256; ++r) a = fmaf(M2cT[r * 112 + tid], tmp[56 + r], a);
        tmp[312 + tid] = a;
    }
    __syncthreads();
    #pragma unroll
    for (int ti = 0; ti < 2; ++ti) {
        int t = wave * 2 + ti, mt = t >> 2, nt = t & 3;
        int bq = nt * 16 + ln;
        if (bq < 56) {
            float r1 = RT2cT[bq * 136 + 64], r2 = RT2cT[bq * 136 + 132];
            #pragma unroll
            for (int rr = 0; rr < 4; ++rr) {
                int p = mt * 16 + quad * 4 + rr;
                if (p < 56) acc5[ti][rr] += tmp[312 + p] * r1 + tmp[368 + p] * r2;
            }
        }
    }

    // ===== main chunks kq0 = 0, 32 =====
    for (int ck = 0; ck < 2; ++ck) {
        const int kq0 = ck * 32;
        __syncthreads();
        // ---- S1: D[c'][p] = RTcA[c'][q] . Vs[p][q], K=64 ----
        #pragma unroll
        for (int ti = 0; ti < 2; ++ti) {
            int t = wave * 2 + ti, mt = t >> 2, nt = t & 3;
            int m = mt * 16 + ln;
            int arow = (m >> 5) * 65 + kq0 + (m & 31);
            int pcol = nt * 16 + ln;
            f4_t a = (f4_t){0, 0, 0, 0};
            #pragma unroll
            for (int ks = 0; ks < 2; ++ks) {
                int k0 = ks * 32 + quad * 8;
                bf8_t Ah = *(const bf8_t*)(RTcAh + arow * 64 + k0);
                bf8_t Al = *(const bf8_t*)(RTcAl + arow * 64 + k0);
                bf8_t Bv = *(const bf8_t*)&Vs[pcol * 72 + k0];
                a = __builtin_amdgcn_mfma_f32_16x16x32_bf16(Ah, Bv, a, 0, 0, 0);
                a = __builtin_amdgcn_mfma_f32_16x16x32_bf16(Al, Bv, a, 0, 0, 0);
            }
            if (pcol < 56) {
                #pragma unroll
                for (int rr = 0; rr < 4; ++rr) {
                    int cp = mt * 16 + quad * 4 + rr;
                    TqT[(cp & 31) * 136 + (cp >> 5) * 56 + pcol] = f2bf(a[rr]);
                }
            }
        }
        __syncthreads();
        // ---- S2: D[r][c] = MvA[r][s] . TqT[c][s], K=128 ----
        #pragma unroll
        for (int ti = 0; ti < 4; ++ti) {
            int t = wave * 4 + ti, mt = t >> 1, nt = t & 1;
            int r = mt * 16 + ln, c = nt * 16 + ln;
            f4_t a = (f4_t){0, 0, 0, 0};
            #pragma unroll
            for (int ks = 0; ks < 4; ++ks) {
                int k0 = ks * 32 + quad * 8;
                bf8_t Ah = *(const bf8_t*)(MvAh + r * 128 + k0);
                bf8_t Al = *(const bf8_t*)(MvAl + r * 128 + k0);
                bf8_t Bv = *(const bf8_t*)&TqT[c * 136 + k0];
                a = __builtin_amdgcn_mfma_f32_16x16x32_bf16(Ah, Bv, a, 0, 0, 0);
                a = __builtin_amdgcn_mfma_f32_16x16x32_bf16(Al, Bv, a, 0, 0, 0);
            }
            int r0 = mt * 16 + quad * 4;
            ushort4 st;
            st.x = f2bf(a[0]); st.y = f2bf(a[1]); st.z = f2bf(a[2]); st.w = f2bf(a[3]);
            *(ushort4*)&VhT[c * 264 + r0] = st;
        }
        __syncthreads();
        // ---- S3: complex multiply with Ghat ----
        #pragma unroll
        for (int i = 0; i < 8; ++i) {
            int o = tid + 512 * i;
            int c = o >> 7, kp = o & 127;
            float vr = bf2f(VhT[c * 264 + kp]), vi = bf2f(VhT[c * 264 + 128 + kp]);
            int gi = (kq0 + c) * 256 + kp;
            float gr = bf2f(ghd[gi]), gm = bf2f(ghd[gi + 128]);
            VhT[c * 264 + kp] = f2bf(vr * gr - vi * gm);
            VhT[c * 264 + 128 + kp] = f2bf(vr * gm + vi * gr);
        }
        __syncthreads();
        // ---- S4: D[a][c] = M2A[a][r] . VhT[c][r], K=256 ----
        #pragma unroll
        for (int ti = 0; ti < 2; ++ti) {
            int t = wave * 2 + ti;
            if (t < 14) {
                int mt = t >> 1, nt = t & 1;
                int aa = mt * 16 + ln, c = nt * 16 + ln;
                f4_t a = (f4_t){0, 0, 0, 0};
                #pragma unroll
                for (int ks = 0; ks < 8; ++ks) {
                    int k0 = ks * 32 + quad * 8;
                    bf8_t Ah = *(const bf8_t*)(M2Ah + aa * 256 + k0);
                    bf8_t Al = *(const bf8_t*)(M2Al + aa * 256 + k0);
                    bf8_t Bv = *(const bf8_t*)&VhT[c * 264 + k0];
                    a = __builtin_amdgcn_mfma_f32_16x16x32_bf16(Ah, Bv, a, 0, 0, 0);
                    a = __builtin_amdgcn_mfma_f32_16x16x32_bf16(Al, Bv, a, 0, 0, 0);
                }
                #pragma unroll
                for (int rr = 0; rr < 4; ++rr) {
                    int av_ = mt * 16 + quad * 4 + rr;
                    int p = (av_ < 56) ? av_ : av_ - 56;
                    int reg = (av_ < 56) ? 0 : 32;
                    QA[p * 72 + reg + c] = f2bf(a[rr]);
                }
            }
        }
        __syncthreads();
        // ---- S5: acc[p][bq] += QA[p][k] . RT2B[bq][k], K=64 ----
        #pragma unroll
        for (int ti = 0; ti < 2; ++ti) {
            int t = wave * 2 + ti, mt = t >> 2, nt = t & 3;
            int p = mt * 16 + ln, bq = nt * 16 + ln;
            #pragma unroll
            for (int ks = 0; ks < 2; ++ks) {
                int k0 = ks * 32 + quad * 8;
                bf8_t Aq = *(const bf8_t*)&QA[p * 72 + k0];
                int col = (ks ? 72 : 0) + kq0 + quad * 8;
                bf8_t Bh = *(const bf8_t*)(RT2Bh + bq * 144 + col);
                bf8_t Bl = *(const bf8_t*)(RT2Bl + bq * 144 + col);
                acc5[ti] = __builtin_amdgcn_mfma_f32_16x16x32_bf16(Aq, Bh, acc5[ti], 0, 0, 0);
                acc5[ti] = __builtin_amdgcn_mfma_f32_16x16x32_bf16(Aq, Bl, acc5[ti], 0, 0, 0);
            }
        }
    }
    // ===== store y (bf16, in place) =====
    #pragma unroll
    for (int ti = 0; ti < 2; ++ti) {
        int t = wave * 2 + ti, mt = t >> 2, nt = t & 3;
        int bq = nt * 16 + ln;
        if (bq < 56) {
            #pragma unroll
            for (int rr = 0; rr < 4; ++rr) {
                int p = mt * 16 + quad * 4 + rr;
                if (p < 56) chan[p * 56 + bq] = f2bf(acc5[ti][rr]);
            }
        }
    }
}

// =====================================================================
extern "C" void kernel_launch(void* const* d_in, const int* in_sizes, int n_in,
                              void* d_out, int out_size, void* d_ws, size_t ws_size,
                              hipStream_t stream) {
    (void)in_sizes; (void)n_in; (void)out_size;
    const float* x         = (const float*)d_in[0];
    const float* W_u       = (const float*)d_in[1];
    const float* b_u       = (const float*)d_in[2];
    const float* W_v       = (const float*)d_in[3];
    const float* b_v       = (const float*)d_in[4];
    const float* W_o       = (const float*)d_in[5];
    const float* b_o       = (const float*)d_in[6];
    const float* rpe_in_w  = (const float*)d_in[7];
    const float* rpe_in_b  = (const float*)d_in[8];
    const float* rpe_h_w   = (const float*)d_in[9];
    const float* rpe_h_b   = (const float*)d_in[10];
    const float* rpe_out_w = (const float*)d_in[11];
    const float* rpe_out_b = (const float*)d_in[12];
    float* out = (float*)d_out;

    if (ws_size < (size_t)WS_FLOATS * 4) {
        probe_k<<<1, 1, 0, stream>>>(out, 1000.0f + (float)((double)ws_size * 1e-6));
        return;
    }
    const bool ext  = ws_size >= (size_t)WS_EXT * 4;
    const bool ext2 = ws_size >= (size_t)WS_EXT2 * 4;
    const bool ext3 = ws_size >= (size_t)WS_EXT3 * 4;
    const bool ext5 = ws_size >= (size_t)WS_EXT5 * 4;
    float* ws    = (float*)d_ws;
    float* MvT   = ws + OFF_MVT;
    float* M2cT  = ws + OFF_M2T;
    float* RT2cT = ws + OFF_RT2T;
    float* RTc   = ws + OFF_RTC;
    float* Mg    = ws + OFF_MG;
    unsigned short* RTcAh = (unsigned short*)(ws + OFF_RTCAH);
    unsigned short* RTcAl = (unsigned short*)(ws + OFF_RTCAL);
    unsigned short* MvAh  = (unsigned short*)(ws + OFF_MVAH);
    unsigned short* MvAl  = (unsigned short*)(ws + OFF_MVAL);
    unsigned short* M2Ah  = (unsigned short*)(ws + OFF_M2AH);
    unsigned short* M2Al  = (unsigned short*)(ws + OFF_M2AL);
    unsigned short* RT2Bh = (unsigned short*)(ws + OFF_RT2BH);
    unsigned short* RT2Bl = (unsigned short*)(ws + OFF_RT2BL);
    float* ninv  = ws + OFF_NINV;
    float* sinv  = ws + OFF_SINV;
    unsigned short* WB  = (unsigned short*)(ws + OFF_WB);
    unsigned short* wub = WB + WB_WU;
    unsigned short* wvb = WB + WB_WV;
    unsigned short* wob = WB + WB_WO;
    unsigned short* whb = WB + WB_WH;
    unsigned short* wrob= WB + WB_WRO;
    unsigned short* tb16= (unsigned short*)(ws + OFF_TB16);
    float* pool  = ws + OFF_POOL;
    unsigned short* Ghat16 = (unsigned short*)pool;
    unsigned short* u16    = (unsigned short*)(pool + POOL_U16);
    unsigned short* vcm16  = (unsigned short*)(pool + POOL_VCM);
    unsigned short* Gh   = (unsigned short*)(pool + POOL_GH);
    unsigned short* Gl   = (unsigned short*)(pool + POOL_GL);
    unsigned short* TgFh = (unsigned short*)(pool + POOL_TGFH);
    unsigned short* TgFl = (unsigned short*)(pool + POOL_TGFL);
    unsigned short* tbA  = (unsigned short*)pool;   // ladder bf16 ping (pool dead until per-head loop)
    unsigned short* xn16 = (unsigned short*)(ws + OFF_XN16);
    unsigned short* wuv  = (unsigned short*)(ws + OFF_WUV);
    float* buv   = ws + OFF_BUV;
    unsigned short* uyf  = (unsigned short*)(ws + OFF_UYF);
    unsigned short* GhA   = (unsigned short*)(ws + OFF_GHA);
    unsigned short* GlA   = (unsigned short*)(ws + OFF_GLA);
    unsigned short* TgFhA = (unsigned short*)(ws + OFF_TGFHA);
    unsigned short* TgFlA = (unsigned short*)(ws + OFF_TGFLA);
    unsigned short* GhatA = (unsigned short*)(ws + OFF_GHATA); // aliases GhA/GlA
    unsigned short* uv16  = (unsigned short*)(ws + OFF_UV16);
    float* tF    = out;                // single fp32 ladder scratch in d_out
    float* g_row_all = out;            // [12321][1024] fp32 in d_out scratch (after ladder)

    consts_k<<<533, 256, 0, stream>>>(RTc, MvT, Mg, M2cT, RT2cT);
    consts2_k<<<309, 256, 0, stream>>>(MvT, M2cT, RT2cT, RTcAh, RTcAl,
                                       MvAh, MvAl, M2Ah, M2Al, RT2Bh, RT2Bl);

    // weights -> bf16
    if (ext) {
        convuv_k<<<4096, 256, 0, stream>>>(W_u, W_v, b_u, b_v, wuv, buv);
    } else {
        convw_k<<<2048, 256, 0, stream>>>(W_u, wub, 524288);
        convw_k<<<2048, 256, 0, stream>>>(W_v, wvb, 524288);
    }
    convw_k<<<2048, 256, 0, stream>>>(W_o, wob, 524288);
    convw_k<<<3072, 256, 0, stream>>>(rpe_h_w, whb, 786432);
    convw_k<<<2048, 256, 0, stream>>>(rpe_out_w, wrob, 524288);

    // ---- RPE MLP hidden ladder (bf16 A, fused norm+relu+convert) ----
    // t0n: t0 row computed in registers -> bf16(relu*sinv) directly (no fp32 t0).
    // Each GEMM: amode 1 (A bf16, half the fetch of amode 0's fp32 4x re-read).
    // normt: one pass fp32 -> bf16(relu*sinv), bit-identical to old staging.
    t0n_k<<<3081, 256, 0, stream>>>(rpe_in_w, rpe_in_b, tbA);
    mgemm_k<<<dim3(4, 97), 256, 0, stream>>>(tbA, whb, 512, nullptr, nullptr, 0, 1,
        tF, rpe_h_b, nullptr, nullptr, 0, 0, GROWS, 512, 512);
    normt_k<<<3081, 256, 0, stream>>>(tF, tbA);
    mgemm_k<<<dim3(4, 97), 256, 0, stream>>>(tbA, whb + 262144, 512, nullptr, nullptr, 0, 1,
        tF, rpe_h_b + 512, nullptr, nullptr, 0, 0, GROWS, 512, 512);
    normt_k<<<3081, 256, 0, stream>>>(tF, tbA);
    mgemm_k<<<dim3(4, 97), 256, 0, stream>>>(tbA, whb + 524288, 512, nullptr, nullptr, 0, 1,
        tF, rpe_h_b + 1024, nullptr, nullptr, 0, 0, GROWS, 512, 512);
    normt_k<<<3081, 256, 0, stream>>>(tF, tb16);

    if (ext) {
        normx_k<<<6272, 256, 0, stream>>>(x, xn16);
    } else {
        norms_k<<<6272, 256, 0, stream>>>(x, ninv, ROWS);
    }

    // batched RPE-out GEMM for all heads: tb16 @ wrob^T -> g_row_all[12321][1024]
    mgemm_k<<<dim3(8, 97), 256, 0, stream>>>(tb16, wrob, 512, nullptr, nullptr, 0, 1,
        g_row_all, rpe_out_b, nullptr, nullptr, 0, 0, GROWS, 1024, 512);

    if (ext3) {
        // ---- batched all-heads g-spectrum: 4 launches ----
        gtr_k<<<dim3(386, 4, 8), dim3(32, 8), 0, stream>>>(g_row_all, 1024, GhA, GlA);
        pads_k<<<7548, 256, 0, stream>>>(GhA, GlA, TgFhA, TgFlA, 8);
        hilo_gemm_k<<<dim3(111, 2, 8), 256, 0, stream>>>(GhA, GlA, RTc, 0, 1,
            TgFhA, TgFlA, 0, 128, GH_STRIDE_US, TGF_STRIDE_US);
        hilo_gemm_k<<<dim3(2, 65, 8), 256, 0, stream>>>(TgFhA, TgFlA, Mg, 1, 0,
            GhatA, nullptr, 1, 224, TGF_STRIDE_US, GHAT_STRIDE_US);
    }

    // ---- per-head main path ----
    for (int h = 0; h < 8; ++h) {
        const size_t wo = (size_t)h * 65536;
        const unsigned short* ghat_h = ext3 ? (GhatA + (size_t)h * GHAT_STRIDE_US) : Ghat16;
        if (!ext3) {
            gtr_k<<<dim3(386, 4, 1), dim3(32, 8), 0, stream>>>(g_row_all + h * 128, 1024, Gh, Gl);
            pads_k<<<944, 256, 0, stream>>>(Gh, Gl, TgFh, TgFl, 1);
            hilo_gemm_k<<<dim3(111, 2), 256, 0, stream>>>(Gh, Gl, RTc, 0, 1,
                TgFh, TgFl, 0, 128, 0, 0);
            hilo_gemm_k<<<dim3(2, 65), 256, 0, stream>>>(TgFh, TgFl, Mg, 1, 0,
                Ghat16, nullptr, 1, 224, 0, 0);
        }
        if (ext5) {
            mgemm_k<<<dim3(2, 196), 256, 0, stream>>>(xn16, wuv + (size_t)h * 131072, 512,
                nullptr, nullptr, 0, 1,
                uv16, buv + h * 256, nullptr, nullptr, 0, 2, ROWS, 256, 512);
            vtr_k<<<dim3(98, 4, 8), dim3(32, 8), 0, stream>>>(uv16, vcm16);
        } else if (ext) {
            mgemm_k<<<dim3(2, 196), 256, 0, stream>>>(xn16, wuv + (size_t)h * 131072, 512,
                vcm16, nullptr, 0, 1,
                u16, buv + h * 256, nullptr, nullptr, 0, 5, ROWS, 256, 512);
        } else {
            mgemm_k<<<dim3(1, 196), 256, 0, stream>>>(x, wvb + wo, 512, nullptr, ninv, 0, 0,
                vcm16, b_v + h * 128, nullptr, nullptr, 0, 4, ROWS, 128, 512);
        }
        vfft_k<<<1024, 512, 0, stream>>>(vcm16, ghat_h, RTcAh, RTcAl, MvAh, MvAl,
            M2Ah, M2Al, RT2Bh, RT2Bl, MvT, M2cT, RT2cT);
        if (!ext) {
            mgemm_k<<<dim3(1, 196), 256, 0, stream>>>(x, wub + wo, 512, nullptr, ninv, 0, 0,
                u16, b_u + h * 128, nullptr, nullptr, 0, 2, ROWS, 128, 512);
        }
        if (ext2) {
            if (ext5) {
                fusey2_k<<<dim3(98, 4, 8), dim3(32, 8), 0, stream>>>(uv16, 256, vcm16, uyf, h);
            } else {
                fusey2_k<<<dim3(98, 4, 8), dim3(32, 8), 0, stream>>>(u16, 128, vcm16, uyf, h);
            }
        } else {
            fusey_k<<<dim3(98, 4, 8), dim3(32, 8), 0, stream>>>(u16, vcm16);
            mgemm_k<<<dim3(4, 196), 256, 0, stream>>>(u16, wob + h * 128, 1024, nullptr, nullptr, 0, 1,
                nullptr, b_o, x, out, (h == 0) ? 1 : 0, 3, ROWS, 512, 128);
        }
    }
    if (ext2) {
        // single output GEMM: out = uyf[25088x1024] @ W_o^T + b_o + x
        mgemm_k<<<dim3(4, 196), 256, 0, stream>>>(uyf, wob, 1024, nullptr, nullptr, 0, 1,
            nullptr, b_o, x, out, 1, 3, ROWS, 512, 1024);
    }
}

// Round 15
// 2168.457 us; speedup vs baseline: 1.6796x; 1.0484x over previous
//
#include <hip/hip_runtime.h>
#include <math.h>

// ---------------- problem sizes ----------------
#define NB 8
#define NN 56
#define POS 3136             // 56*56
#define ROWS 25088           // 8*3136
#define GR 111               // 2N-1
#define GROWS 12321          // 111*111
#define FREQ 16640           // per-channel spectrum: [kq 65][256] (re 128 | im 128)

// ---------------- workspace layout (float offsets), base 36.5 MB ----------------
#define OFF_MVT    0u
#define OFF_M2T    28672u
#define OFF_RT2T   57344u
#define OFF_RTC    64960u
#define OFF_MG     79392u
#define OFF_RTCAH  136224u
#define OFF_RTCAL  140384u
#define OFF_MVAH   144544u
#define OFF_MVAL   160928u
#define OFF_M2AH   177312u
#define OFF_M2AL   191648u
#define OFF_RT2BH  205984u
#define OFF_RT2BL  210592u
#define OFF_NINV   215200u
#define OFF_SINV   240288u
#define OFF_WB     252624u
#define OFF_TB16   1694416u
#define OFF_POOL   4848592u
#define WS_FLOATS  9124816u   // 36.5 MB
// ---- ext1: fused u|v projection ----
#define OFF_XN16   9124816u   // 25088x512 bf16 = 6,422,528 fl
#define OFF_WUV    15547344u  // [8][256][512] bf16 = 524,288 fl
#define OFF_BUV    16071632u  // [2048] fp32
#define WS_EXT     16073680u  // 64.3 MB
// ---- ext2: single K=1024 output GEMM ----
#define OFF_UYF    16073680u  // 25088x1024 bf16 = 12,845,056 fl
#define WS_EXT2    28918736u  // 115.7 MB
// ---- ext3: batched all-heads g-spectrum pipeline ----
#define GH_STRIDE_US   1818624u   // 14208*128
#define TGF_STRIDE_US  1863680u   // 16640*112 (= 8320*224)
#define GHAT_STRIDE_US 2129920u   // 128*65*256
#define OFF_GHA    28918736u  // [8]*GH_STRIDE bf16 = 7,274,496 fl
#define OFF_GLA    36193232u  // 7,274,496 fl
#define OFF_TGFHA  43467728u  // [8]*TGF_STRIDE bf16 = 7,454,720 fl
#define OFF_TGFLA  50922448u  // 7,454,720 fl
#define OFF_GHATA  28918736u  // [8]*GHAT_STRIDE bf16 — ALIASES GhA/GlA (dead after stage1)
#define WS_EXT3    58377168u  // 233.5 MB
// ---- ext5: batched all-heads uv GEMM, row-major uvA staging ----
// r14 post-mortem: the persistent 151us/134.7MB dispatch is the RPE-out
// GEMM (repeated bench iterations of ONE launch; identical LDS-conflict
// count across rounds proves it). The 8 per-head uv GEMMs (392 blocks,
// ~40% fill) are the batchable analog: one N=2048 GEMM, row-major into
// uvA (NO scatter — r10's failure was the 2B channel-major scatter).
// uvA [25088][2048] bf16 = 25,690,112 fl overlays GlA-tail + TgFhA/TgFlA
// (all dead after g-spectrum stage2) + old uv16: 37,438,416..63,128,528
// < WS_EXT5 — fits the PROVEN r12/r14 budget, no new gate.
#define OFF_UVA    37438416u  // = OFF_GHATA + GHAT size (GhatA stays live)
#define WS_EXT5    64799696u  // 259.2 MB (proven working since r12)
// WB sub-offsets (ushort units)
#define WB_WU  0u
#define WB_WV  524288u
#define WB_WO  1048576u
#define WB_WH  1572864u
#define WB_WRO 2359296u
// pool sub-offsets (fl units) — fallback (non-ext3) per-head g-path:
#define POOL_U16   1064960u
#define POOL_VCM   2670592u
#define POOL_GH    0u
#define POOL_GL    909312u
#define POOL_TGFH  1818624u
#define POOL_TGFL  2750464u
// ladder-time overlay: tbA bf16 [12321][512] = 3,154,176 fl at pool+0
// (pool is dead until the per-head loop starts)

typedef __attribute__((ext_vector_type(8))) short bf8_t;
typedef __attribute__((ext_vector_type(8))) unsigned short us8_t;
typedef __attribute__((ext_vector_type(4))) float f4_t;

__device__ inline float bf2f(unsigned short b) {
    union { unsigned u; float f; } v; v.u = ((unsigned)b) << 16; return v.f;
}
__device__ inline unsigned short f2bf(float f) {
    union { float f; unsigned u; } v; v.f = f;
    unsigned r = v.u + 0x7FFF + ((v.u >> 16) & 1);
    return (unsigned short)(r >> 16);
}

__global__ void probe_k(float* out, float code) { out[0] = code; }

// =====================================================================
// fp32 constants (gfft + vfft Nyquist tail). angle reduced: (a*b) mod 128
// =====================================================================
__global__ void consts_k(float* RTc, float* MvT, float* Mg, float* M2cT, float* RT2cT) {
    int idx = blockIdx.x * 256 + threadIdx.x;
    const float STEP = 0.049087385212340526f; // 2*pi/128
    if (idx < 14430) { // RTc[q*130+col]: gfft row DFT
        int q = idx / 130, col = idx % 130;
        int a = (col < 65) ? col : col - 65;
        float th = (float)((a * q) & 127) * STEP;
        RTc[idx] = (col < 65) ? cosf(th) : -sinf(th);
        return;
    }
    idx -= 14430;
    if (idx < 28672) { // MvT[s*256+r]
        int s = idx / 256, r = idx % 256;
        int kp = (r < 128) ? r : r - 128;
        int sp = (s < 56) ? s : s - 56;
        float th = (float)((kp * sp) & 127) * STEP;
        float cv = cosf(th), sv = sinf(th);
        MvT[idx] = (r < 128) ? ((s < 56) ? cv : sv) : ((s < 56) ? -sv : cv);
        return;
    }
    idx -= 28672;
    if (idx < 56832) { // Mg[r*222+s]: gfft col DFT
        int r = idx / 222, s = idx % 222;
        int kp = (r < 128) ? r : r - 128;
        int sp = (s < 111) ? s : s - 111;
        float th = (float)((kp * sp) & 127) * STEP;
        float cv = cosf(th), sv = sinf(th);
        Mg[idx] = (r < 128) ? ((s < 111) ? cv : sv) : ((s < 111) ? -sv : cv);
        return;
    }
    idx -= 56832;
    if (idx < 28672) { // M2cT[s*112+r]
        int s = idx / 112, r = idx % 112;
        int a = (r < 56) ? (r + 55) : (r - 1);
        int kp = (s < 128) ? s : s - 128;
        float th = (float)((kp * a) & 127) * STEP;
        float cv = cosf(th), sv = sinf(th);
        M2cT[idx] = (r < 56) ? ((s < 128) ? cv : -sv) : ((s < 128) ? sv : cv);
        return;
    }
    idx -= 28672;
    if (idx < 7616) { // RT2cT[b*136+col], w/L^2 folded
        int b = idx / 136, col = idx % 136;
        float val = 0.f;
        if (col < 65 || (col >= 68 && col < 133)) {
            int kq = (col < 65) ? col : col - 68;
            float w = (kq == 0 || kq == 64) ? 1.f : 2.f;
            float th = (float)((kq * (b + 55)) & 127) * STEP;
            val = ((col < 65) ? cosf(th) : -sinf(th)) * w * (1.f / 16384.f);
        }
        RT2cT[idx] = val;
    }
}

// =====================================================================
// bf16 hi/lo MFMA constants (derived from fp32 consts; run after consts_k)
// =====================================================================
__global__ void consts2_k(const float* __restrict__ MvT, const float* __restrict__ M2cT,
                          const float* __restrict__ RT2cT,
                          unsigned short* RTcAh, unsigned short* RTcAl,
                          unsigned short* MvAh, unsigned short* MvAl,
                          unsigned short* M2Ah, unsigned short* M2Al,
                          unsigned short* RT2Bh, unsigned short* RT2Bl) {
    int idx = blockIdx.x * 256 + threadIdx.x;
    const float STEP = 0.049087385212340526f;
    float v = 0.f; unsigned short *ph, *pl; int off;
    if (idx < 8320) {               // RTcA [130 rows (65 re | 65 im)][64]
        int row = idx >> 6, q = idx & 63;
        if (q < 56) {
            int kq = (row < 65) ? row : row - 65;
            float th = (float)((kq * q) & 127) * STEP;
            v = (row < 65) ? cosf(th) : -sinf(th);
        }
        ph = RTcAh; pl = RTcAl; off = idx;
    } else if (idx < 41088) {       // MvA [256][128] (cols 112..127 zero)
        int i = idx - 8320; int r = i >> 7, s = i & 127;
        if (s < 112) v = MvT[s * 256 + r];
        ph = MvAh; pl = MvAl; off = i;
    } else if (idx < 69760) {       // M2A [112][256]
        int i = idx - 41088; int a = i >> 8, r = i & 255;
        v = M2cT[r * 112 + a];
        ph = M2Ah; pl = M2Al; off = i;
    } else if (idx < 78976) {       // RT2B [64][144]: 0..64 re | 72..136 im
        int i = idx - 69760; int bq = i / 144, col = i % 144;
        if (bq < 56) {
            if (col < 65) v = RT2cT[bq * 136 + col];
            else if (col >= 72 && col < 137) v = RT2cT[bq * 136 + 68 + (col - 72)];
        }
        ph = RT2Bh; pl = RT2Bl; off = i;
    } else return;
    unsigned short h = f2bf(v);
    ph[off] = h;
    pl[off] = f2bf(v - bf2f(h));
}

// =====================================================================
// row L2 norms -> inverse simple-rms scale, D=512 (fallback path)
// =====================================================================
__global__ void norms_k(const float* __restrict__ X, float* __restrict__ out, int rows) {
    int row = blockIdx.x * 4 + (threadIdx.x >> 6);
    int lane = threadIdx.x & 63;
    if (row >= rows) return;
    const float* p = X + (size_t)row * 512;
    float s = 0.f;
    #pragma unroll
    for (int i = 0; i < 8; ++i) { float v = p[lane + 64 * i]; s += v * v; }
    #pragma unroll
    for (int o = 32; o > 0; o >>= 1) s += __shfl_down(s, o, 64);
    if (lane == 0) out[row] = 1.f / (sqrtf(s) * 0.04419417382415922f + 1e-8f);
}

// =====================================================================
// fused row-norm + bf16(x*ninv): one pass over x.
// =====================================================================
__global__ void normx_k(const float* __restrict__ X, unsigned short* __restrict__ xn) {
    int row = blockIdx.x * 4 + (threadIdx.x >> 6);
    int lane = threadIdx.x & 63;
    if (row >= ROWS) return;
    const float* p = X + (size_t)row * 512 + lane * 8;
    float4 f1 = *(const float4*)p, f2 = *(const float4*)(p + 4);
    float s = f1.x * f1.x + f1.y * f1.y + f1.z * f1.z + f1.w * f1.w
            + f2.x * f2.x + f2.y * f2.y + f2.z * f2.z + f2.w * f2.w;
    #pragma unroll
    for (int o = 32; o > 0; o >>= 1) s += __shfl_down(s, o, 64);
    s = __shfl(s, 0, 64);
    float inv = 1.f / (sqrtf(s) * 0.04419417382415922f + 1e-8f);
    us8_t o;
    o[0] = f2bf(f1.x * inv); o[1] = f2bf(f1.y * inv);
    o[2] = f2bf(f1.z * inv); o[3] = f2bf(f1.w * inv);
    o[4] = f2bf(f2.x * inv); o[5] = f2bf(f2.y * inv);
    o[6] = f2bf(f2.z * inv); o[7] = f2bf(f2.w * inv);
    *(us8_t*)(xn + (size_t)row * 512 + lane * 8) = o;
}

// =====================================================================
// fused row-norm + bf16(relu(t)*sinv): one pass over fp32 ladder output.
// Identical bits to the old norms_k + amode-0 staging (fmax then *s).
// =====================================================================
__global__ void normt_k(const float* __restrict__ T, unsigned short* __restrict__ tn) {
    int row = blockIdx.x * 4 + (threadIdx.x >> 6);
    int lane = threadIdx.x & 63;
    if (row >= GROWS) return;
    const float* p = T + (size_t)row * 512 + lane * 8;
    float4 f1 = *(const float4*)p, f2 = *(const float4*)(p + 4);
    float s = f1.x * f1.x + f1.y * f1.y + f1.z * f1.z + f1.w * f1.w
            + f2.x * f2.x + f2.y * f2.y + f2.z * f2.z + f2.w * f2.w;
    #pragma unroll
    for (int o = 32; o > 0; o >>= 1) s += __shfl_down(s, o, 64);
    s = __shfl(s, 0, 64);
    float inv = 1.f / (sqrtf(s) * 0.04419417382415922f + 1e-8f);
    us8_t o;
    o[0] = f2bf(fmaxf(f1.x, 0.f) * inv); o[1] = f2bf(fmaxf(f1.y, 0.f) * inv);
    o[2] = f2bf(fmaxf(f1.z, 0.f) * inv); o[3] = f2bf(fmaxf(f1.w, 0.f) * inv);
    o[4] = f2bf(fmaxf(f2.x, 0.f) * inv); o[5] = f2bf(fmaxf(f2.y, 0.f) * inv);
    o[6] = f2bf(fmaxf(f2.z, 0.f) * inv); o[7] = f2bf(fmaxf(f2.w, 0.f) * inv);
    *(us8_t*)(tn + (size_t)row * 512 + lane * 8) = o;
}

// =====================================================================
// fused t0 + row-norm + bf16(relu*sinv): computes t0 row in registers.
// =====================================================================
__global__ void t0n_k(const float* __restrict__ w, const float* __restrict__ b,
                      unsigned short* __restrict__ tn) {
    int row = blockIdx.x * 4 + (threadIdx.x >> 6);
    int lane = threadIdx.x & 63;
    if (row >= GROWS) return;
    int i = row / 111, j = row % 111;
    float dp = (float)(i - 55), dq = (float)(j - 55);
    int c8 = lane * 8;
    float4 w0 = *(const float4*)(w + c8 * 2);
    float4 w1 = *(const float4*)(w + c8 * 2 + 4);
    float4 w2 = *(const float4*)(w + c8 * 2 + 8);
    float4 w3 = *(const float4*)(w + c8 * 2 + 12);
    float4 b0 = *(const float4*)(b + c8);
    float4 b1 = *(const float4*)(b + c8 + 4);
    float v[8];
    v[0] = dp * w0.x + dq * w0.y + b0.x;
    v[1] = dp * w0.z + dq * w0.w + b0.y;
    v[2] = dp * w1.x + dq * w1.y + b0.z;
    v[3] = dp * w1.z + dq * w1.w + b0.w;
    v[4] = dp * w2.x + dq * w2.y + b1.x;
    v[5] = dp * w2.z + dq * w2.w + b1.y;
    v[6] = dp * w3.x + dq * w3.y + b1.z;
    v[7] = dp * w3.z + dq * w3.w + b1.w;
    float s = 0.f;
    #pragma unroll
    for (int k = 0; k < 8; ++k) s += v[k] * v[k];
    #pragma unroll
    for (int o = 32; o > 0; o >>= 1) s += __shfl_down(s, o, 64);
    s = __shfl(s, 0, 64);
    float inv = 1.f / (sqrtf(s) * 0.04419417382415922f + 1e-8f);
    us8_t o;
    #pragma unroll
    for (int k = 0; k < 8; ++k) o[k] = f2bf(fmaxf(v[k], 0.f) * inv);
    *(us8_t*)(tn + (size_t)row * 512 + c8) = o;
}

__global__ void convw_k(const float* __restrict__ src, unsigned short* __restrict__ dst, int n) {
    int i = blockIdx.x * 256 + threadIdx.x;
    if (i < n) dst[i] = f2bf(src[i]);
}

// wuv[h*256 + j][k]: j<128 -> W_u row h*128+j; else W_v row h*128+j-128.
__global__ void convuv_k(const float* __restrict__ Wu, const float* __restrict__ Wv,
                         const float* __restrict__ bu, const float* __restrict__ bv,
                         unsigned short* __restrict__ wuv, float* __restrict__ buv) {
    int i = blockIdx.x * 256 + threadIdx.x;      // 1,048,576 exact -> 4096 blocks
    if (i < 1048576) {
        int row = i >> 9, k = i & 511;
        int h = row >> 8, j = row & 255;
        float v = (j < 128) ? Wu[(size_t)(h * 128 + j) * 512 + k]
                            : Wv[(size_t)(h * 128 + j - 128) * 512 + k];
        wuv[i] = f2bf(v);
    }
    if (i < 2048) {
        int h = i >> 8, j = i & 255;
        buv[i] = (j < 128) ? bu[h * 128 + j] : bv[h * 128 + j - 128];
    }
}

// =====================================================================
// bf16 MFMA GEMM (verified fragment pattern), epilogue/amode variants
//  amode 0: A fp32 rm -> relu?*scale -> bf16 ; amode 1: A bf16 rm
//  amode 2: A = bf16(u*y gather) — legacy
//  emode 0: fp32 rm +bias ; emode 2: bf16 rm +bias+silu
//  emode 3: out accum (+bias+xres if first) ; emode 4: bf16 cm +bias+silu
//  emode 5: split u|v one head (scatter — superseded)
// =====================================================================
__global__ __launch_bounds__(256) void mgemm_k(
    const void* __restrict__ Aptr, const unsigned short* __restrict__ B, int ldb,
    const unsigned short* __restrict__ yv, const float* __restrict__ scale,
    int relu_in, int amode,
    void* __restrict__ Cptr, const float* __restrict__ bias,
    const float* __restrict__ xres, float* __restrict__ outAcc, int first,
    int emode, int M, int N, int K)
{
    __shared__ __align__(16) unsigned short As[4096];
    __shared__ __align__(16) unsigned short Bs[4096];
    const int t = threadIdx.x;
    const int lane = t & 63;
    const int quad = lane >> 4, ln = lane & 15;
    const int wave = t >> 6;
    const int wm = (wave >> 1) << 6, wn = (wave & 1) << 6;
    const int row0 = blockIdx.y << 7, col0 = blockIdx.x << 7;
    const int sc = t & 3;
    const int sm = t >> 2;
    const float* Af = (const float*)Aptr;
    const unsigned short* Au = (const unsigned short*)Aptr;
    f4_t acc[4][4];
    #pragma unroll
    for (int i = 0; i < 4; ++i)
        #pragma unroll
        for (int j = 0; j < 4; ++j)
            acc[i][j] = (f4_t){0.f, 0.f, 0.f, 0.f};

    for (int k0 = 0; k0 < K; k0 += 32) {
        #pragma unroll
        for (int rep = 0; rep < 2; ++rep) {
            const int m = sm + (rep << 6);
            const int am = row0 + m;
            us8_t av = {0, 0, 0, 0, 0, 0, 0, 0};
            if (am < M) {
                if (amode == 0) {
                    const float s = scale ? scale[am] : 1.f;
                    const float* ap = Af + (size_t)am * K + k0 + (sc << 3);
                    float4 f1 = *(const float4*)ap;
                    float4 f2 = *(const float4*)(ap + 4);
                    if (relu_in) {
                        f1.x = fmaxf(f1.x, 0.f); f1.y = fmaxf(f1.y, 0.f);
                        f1.z = fmaxf(f1.z, 0.f); f1.w = fmaxf(f1.w, 0.f);
                        f2.x = fmaxf(f2.x, 0.f); f2.y = fmaxf(f2.y, 0.f);
                        f2.z = fmaxf(f2.z, 0.f); f2.w = fmaxf(f2.w, 0.f);
                    }
                    av[0] = f2bf(f1.x * s); av[1] = f2bf(f1.y * s);
                    av[2] = f2bf(f1.z * s); av[3] = f2bf(f1.w * s);
                    av[4] = f2bf(f2.x * s); av[5] = f2bf(f2.y * s);
                    av[6] = f2bf(f2.z * s); av[7] = f2bf(f2.w * s);
                } else if (amode == 1) {
                    av = *(const us8_t*)(Au + (size_t)am * K + k0 + (sc << 3));
                } else {
                    const unsigned short* up = Au + (size_t)am * K + k0 + (sc << 3);
                    const int bb = am / POS, pos = am - bb * POS;
                    const unsigned short* yb = yv + ((size_t)(bb * 128 + k0 + (sc << 3))) * POS + pos;
                    #pragma unroll
                    for (int j = 0; j < 8; ++j)
                        av[j] = f2bf(bf2f(up[j]) * bf2f(yb[(size_t)j * POS]));
                }
            }
            *(us8_t*)&As[(sc << 10) + (m << 3)] = av;
        }
        #pragma unroll
        for (int rep = 0; rep < 2; ++rep) {
            const int n = sm + (rep << 6);
            us8_t bv = *(const us8_t*)(B + (size_t)(col0 + n) * ldb + k0 + (sc << 3));
            *(us8_t*)&Bs[(sc << 10) + (n << 3)] = bv;
        }
        __syncthreads();
        bf8_t af[4], bfr[4];
        #pragma unroll
        for (int i = 0; i < 4; ++i)
            af[i] = *(const bf8_t*)&As[(quad << 10) + ((wm + (i << 4) + ln) << 3)];
        #pragma unroll
        for (int i = 0; i < 4; ++i)
            bfr[i] = *(const bf8_t*)&Bs[(quad << 10) + ((wn + (i << 4) + ln) << 3)];
        #pragma unroll
        for (int i = 0; i < 4; ++i)
            #pragma unroll
            for (int j = 0; j < 4; ++j)
                acc[i][j] = __builtin_amdgcn_mfma_f32_16x16x32_bf16(af[i], bfr[j], acc[i][j], 0, 0, 0);
        __syncthreads();
    }
    #pragma unroll
    for (int i = 0; i < 4; ++i) {
        #pragma unroll
        for (int j = 0; j < 4; ++j) {
            #pragma unroll
            for (int rr = 0; rr < 4; ++rr) {
                const int r = row0 + wm + (i << 4) + (quad << 2) + rr;
                const int c = col0 + wn + (j << 4) + ln;
                if (r >= M) continue;
                float v = acc[i][j][rr];
                if (emode == 0) {
                    v += bias[c];
                    ((float*)Cptr)[(size_t)r * N + c] = v;
                } else if (emode == 2) {
                    v += bias[c]; v = v / (1.f + expf(-v));
                    ((unsigned short*)Cptr)[(size_t)r * N + c] = f2bf(v);
                } else if (emode == 4) {
                    v += bias[c]; v = v / (1.f + expf(-v));
                    const int bb = r / POS, pos = r - bb * POS;
                    ((unsigned short*)Cptr)[((size_t)(bb * 128 + c)) * POS + pos] = f2bf(v);
                } else if (emode == 5) {
                    v += bias[c]; v = v / (1.f + expf(-v));
                    unsigned short bv16 = f2bf(v);
                    if (c < 128) {
                        ((unsigned short*)Cptr)[(size_t)r * 128 + c] = bv16;
                    } else {
                        const int bb = r / POS, pos = r - bb * POS;
                        ((unsigned short*)yv)[((size_t)(bb * 128 + (c - 128))) * POS + pos] = bv16;
                    }
                } else {
                    const size_t oi = (size_t)r * 512 + c;
                    v += first ? (bias[c] + xres[oi]) : outAcc[oi];
                    outAcc[oi] = v;
                }
            }
        }
    }
}

// =====================================================================
// fused transpose + bf16 hi/lo split (head-batched via blockIdx.z)
// =====================================================================
__global__ void gtr_k(const float* __restrict__ src, int ld,
                      unsigned short* __restrict__ Gh, unsigned short* __restrict__ Gl) {
    __shared__ float tile[32][33];
    const int z = blockIdx.z;
    src += (size_t)z * 128;
    Gh += (size_t)z * GH_STRIDE_US;
    Gl += (size_t)z * GH_STRIDE_US;
    int s0 = blockIdx.x * 32, d0 = blockIdx.y * 32;
    int tx = threadIdx.x, ty = threadIdx.y;
    #pragma unroll
    for (int i = 0; i < 32; i += 8) {
        int s = s0 + ty + i;
        if (s < GROWS) tile[ty + i][tx] = src[(size_t)s * ld + d0 + tx];
    }
    __syncthreads();
    int s = s0 + tx;
    if (s < GROWS) {
        int p = s / 111, q = s - p * 111;
        #pragma unroll
        for (int i = 0; i < 32; i += 8) {
            int d = d0 + ty + i;
            float v = tile[tx][ty + i];
            unsigned short h = f2bf(v);
            size_t o = (size_t)(d * 111 + p) * 128 + q;
            Gh[o] = h;
            Gl[o] = f2bf(v - bf2f(h));
        }
    }
}

// zero GEMM pad slots for nh heads (head-strided)
__global__ void pads_k(unsigned short* __restrict__ Gh, unsigned short* __restrict__ Gl,
                       unsigned short* __restrict__ TgFh, unsigned short* __restrict__ TgFl,
                       int nh) {
    int i = blockIdx.x * 256 + threadIdx.x;
    if (i < nh * 16640) {
        int h = i / 16640, r = i % 16640;
        size_t o = (size_t)h * TGF_STRIDE_US + (size_t)r * 112 + 111;
        TgFh[o] = 0; TgFl[o] = 0;
    }
    if (i < nh * 241536) {
        int h = i / 241536, j = i % 241536;
        int r = j / 17, c = 111 + j % 17;
        size_t o = (size_t)h * GH_STRIDE_US + (size_t)r * 128 + c;
        Gh[o] = 0; Gl[o] = 0;
    }
}

// =====================================================================
// v transpose: vcm16[(bb*128+ch)*POS+pos] = uv[(bb*POS+pos)*lda + ch]
// (uv pointer pre-offset to the v-column base; lda = row stride).
// LDS 32x32 tile; both global sides are 64B-run coalesced.
// =====================================================================
__global__ void vtr_k(const unsigned short* __restrict__ uv, int lda,
                      unsigned short* __restrict__ vcm) {
    __shared__ unsigned short tile[32][34];
    const int pos0 = blockIdx.x * 32, ch0 = blockIdx.y * 32, bb = blockIdx.z;
    const int tx = threadIdx.x, ty = threadIdx.y;
    #pragma unroll
    for (int i = 0; i < 32; i += 8) {
        tile[ty + i][tx] = uv[((size_t)(bb * POS + pos0 + ty + i)) * lda + ch0 + tx];
    }
    __syncthreads();
    #pragma unroll
    for (int i = 0; i < 32; i += 8) {
        vcm[((size_t)(bb * 128 + ch0 + ty + i)) * POS + pos0 + tx] = tile[tx][ty + i];
    }
}

// =====================================================================
// fuse u *= y  (in place on u16) — fallback path.
// =====================================================================
__global__ void fusey_k(unsigned short* __restrict__ u, const unsigned short* __restrict__ y) {
    __shared__ unsigned short yt[32][34];
    const int pos0 = blockIdx.x * 32, k0 = blockIdx.y * 32, bb = blockIdx.z;
    const int tx = threadIdx.x, ty = threadIdx.y;
    #pragma unroll
    for (int i = 0; i < 32; i += 8) {
        int k = k0 + ty + i;
        yt[ty + i][tx] = y[((size_t)(bb * 128 + k)) * POS + pos0 + tx];
    }
    __syncthreads();
    #pragma unroll
    for (int i = 0; i < 32; i += 8) {
        size_t r = (size_t)bb * POS + pos0 + ty + i;
        size_t idx = r * 128 + k0 + tx;
        u[idx] = f2bf(bf2f(u[idx]) * bf2f(yt[tx][ty + i]));
    }
}

// =====================================================================
// fuse u*y -> uyf[r][h*128+k]. u has row stride lda (pointer pre-offset
// to the head's u-column base).
// =====================================================================
__global__ void fusey2_k(const unsigned short* __restrict__ u, int lda,
                         const unsigned short* __restrict__ y,
                         unsigned short* __restrict__ uyf, int h) {
    __shared__ unsigned short yt[32][34];
    const int pos0 = blockIdx.x * 32, k0 = blockIdx.y * 32, bb = blockIdx.z;
    const int tx = threadIdx.x, ty = threadIdx.y;
    #pragma unroll
    for (int i = 0; i < 32; i += 8) {
        int k = k0 + ty + i;
        yt[ty + i][tx] = y[((size_t)(bb * 128 + k)) * POS + pos0 + tx];
    }
    __syncthreads();
    #pragma unroll
    for (int i = 0; i < 32; i += 8) {
        size_t r = (size_t)bb * POS + pos0 + ty + i;
        unsigned short uv = u[r * lda + k0 + tx];
        uyf[r * 1024 + h * 128 + k0 + tx] = f2bf(bf2f(uv) * bf2f(yt[tx][ty + i]));
    }
}

// =====================================================================
// hi/lo bf16 GEMM (3-product). Head-batched via blockIdx.z (zD/zC strides).
// =====================================================================
__device__ inline float cval(const float* __restrict__ Csrc, int cmode, int row, int kk) {
    if (cmode == 0)
        return (kk < 111 && row < 130) ? Csrc[kk * 130 + row] : 0.f;
    int s = (kk < 112) ? kk : (111 + (kk - 112));
    bool ok = (kk < 112) ? (kk < 111) : (kk < 223);
    return ok ? Csrc[(size_t)row * 222 + s] : 0.f;
}

__global__ __launch_bounds__(256) void hilo_gemm_k(
    const unsigned short* __restrict__ Dh, const unsigned short* __restrict__ Dl,
    const float* __restrict__ Csrc, int cmode, int constIsA,
    unsigned short* __restrict__ C0, unsigned short* __restrict__ C1,
    int omode, int K, unsigned zD, unsigned zC)
{
    __shared__ __align__(16) unsigned short Ash[4096];
    __shared__ __align__(16) unsigned short Asl[4096];
    __shared__ __align__(16) unsigned short Bsh[4096];
    __shared__ __align__(16) unsigned short Bsl[4096];
    const int t = threadIdx.x;
    const int lane = t & 63;
    const int quad = lane >> 4, ln = lane & 15;
    const int wave = t >> 6;
    const int wm = (wave >> 1) << 6, wn = (wave & 1) << 6;
    const int row0 = blockIdx.y << 7, col0 = blockIdx.x << 7;
    const int sc = t & 3, sm = t >> 2;
    const size_t zoffD = (size_t)blockIdx.z * zD, zoffC = (size_t)blockIdx.z * zC;
    Dh += zoffD; Dl += zoffD;
    C0 += zoffC; if (C1) C1 += zoffC;
    f4_t acc[4][4];
    #pragma unroll
    for (int i = 0; i < 4; ++i)
        #pragma unroll
        for (int j = 0; j < 4; ++j)
            acc[i][j] = (f4_t){0.f, 0.f, 0.f, 0.f};

    for (int k0 = 0; k0 < K; k0 += 32) {
        #pragma unroll
        for (int rep = 0; rep < 2; ++rep) {
            const int m = sm + (rep << 6);
            // ---- A tile ----
            {
                const int gr = row0 + m;
                us8_t hv, lv;
                if (constIsA) {
                    #pragma unroll
                    for (int j = 0; j < 8; ++j) {
                        int kk = k0 + (sc << 3) + j;
                        float v = cval(Csrc, cmode, gr, kk);
                        unsigned short h = f2bf(v);
                        hv[j] = h; lv[j] = f2bf(v - bf2f(h));
                    }
                } else {
                    hv = *(const us8_t*)(Dh + (size_t)gr * K + k0 + (sc << 3));
                    lv = *(const us8_t*)(Dl + (size_t)gr * K + k0 + (sc << 3));
                }
                *(us8_t*)&Ash[(sc << 10) + (m << 3)] = hv;
                *(us8_t*)&Asl[(sc << 10) + (m << 3)] = lv;
            }
            // ---- B tile ----
            {
                const int gc = col0 + m;
                us8_t hv, lv;
                if (constIsA) {
                    hv = *(const us8_t*)(Dh + (size_t)gc * K + k0 + (sc << 3));
                    lv = *(const us8_t*)(Dl + (size_t)gc * K + k0 + (sc << 3));
                } else {
                    #pragma unroll
                    for (int j = 0; j < 8; ++j) {
                        int kk = k0 + (sc << 3) + j;
                        float v = cval(Csrc, cmode, gc, kk);
                        unsigned short h = f2bf(v);
                        hv[j] = h; lv[j] = f2bf(v - bf2f(h));
                    }
                }
                *(us8_t*)&Bsh[(sc << 10) + (m << 3)] = hv;
                *(us8_t*)&Bsl[(sc << 10) + (m << 3)] = lv;
            }
        }
        __syncthreads();
        bf8_t ah[4], al[4], bh[4], bl[4];
        #pragma unroll
        for (int i = 0; i < 4; ++i) {
            ah[i] = *(const bf8_t*)&Ash[(quad << 10) + ((wm + (i << 4) + ln) << 3)];
            al[i] = *(const bf8_t*)&Asl[(quad << 10) + ((wm + (i << 4) + ln) << 3)];
            bh[i] = *(const bf8_t*)&Bsh[(quad << 10) + ((wn + (i << 4) + ln) << 3)];
            bl[i] = *(const bf8_t*)&Bsl[(quad << 10) + ((wn + (i << 4) + ln) << 3)];
        }
        #pragma unroll
        for (int i = 0; i < 4; ++i)
            #pragma unroll
            for (int j = 0; j < 4; ++j) {
                acc[i][j] = __builtin_amdgcn_mfma_f32_16x16x32_bf16(ah[i], bh[j], acc[i][j], 0, 0, 0);
                acc[i][j] = __builtin_amdgcn_mfma_f32_16x16x32_bf16(ah[i], bl[j], acc[i][j], 0, 0, 0);
                acc[i][j] = __builtin_amdgcn_mfma_f32_16x16x32_bf16(al[i], bh[j], acc[i][j], 0, 0, 0);
            }
        __syncthreads();
    }
    #pragma unroll
    for (int i = 0; i < 4; ++i) {
        #pragma unroll
        for (int j = 0; j < 4; ++j) {
            #pragma unroll
            for (int rr = 0; rr < 4; ++rr) {
                const int r = row0 + wm + (i << 4) + (quad << 2) + rr;
                const int c = col0 + wn + (j << 4) + ln;
                float v = acc[i][j][rr];
                if (omode == 1) {
                    C0[(size_t)r * 256 + c] = f2bf(v);
                } else {
                    if (r < 130) {
                        int kq = (r < 65) ? r : r - 65;
                        int im = (r < 65) ? 0 : 1;
                        int d = c / 111, p = c - d * 111;
                        size_t o = ((size_t)((d * 65 + kq) * 2 + im)) * 112 + p;
                        unsigned short h = f2bf(v);
                        C0[o] = h;
                        C1[o] = f2bf(v - bf2f(h));
                    }
                }
            }
        }
    }
}

// =====================================================================
// v conv (one head, in-place bf16): MFMA DFT stages per channel workgroup.
// Round-0 body, plain __launch_bounds__(512): VGPR 88, 2 blocks/CU,
// no spill, ~142-149 us. All restructurings regressed (r2/r3/r8/r10).
// =====================================================================
__global__ __launch_bounds__(512) void vfft_k(
    unsigned short* __restrict__ vcm, const unsigned short* __restrict__ Ghat,
    const unsigned short* __restrict__ RTcAh, const unsigned short* __restrict__ RTcAl,
    const unsigned short* __restrict__ MvAh,  const unsigned short* __restrict__ MvAl,
    const unsigned short* __restrict__ M2Ah,  const unsigned short* __restrict__ M2Al,
    const unsigned short* __restrict__ RT2Bh, const unsigned short* __restrict__ RT2Bl,
    const float* __restrict__ MvT, const float* __restrict__ M2cT,
    const float* __restrict__ RT2cT)
{
    __shared__ __align__(16) unsigned short Vs[64 * 72];    // [p][q] bf16, zero-pad
    __shared__ __align__(16) unsigned short TqT[32 * 136];  // [kqL][s(112)+pad]
    __shared__ __align__(16) unsigned short VhT[32 * 264];  // [kqL][r(256)+pad]
    __shared__ __align__(16) unsigned short QA[64 * 72];    // [p][k(64)+pad]
    __shared__ float tmp[424];                              // Nyquist temps
    const int tid = threadIdx.x;
    const int lane = tid & 63, wave = tid >> 6;
    const int quad = lane >> 4, ln = lane & 15;
    const int d = blockIdx.x >> 3, b = blockIdx.x & 7;
    unsigned short* chan = vcm + (size_t)(b * 128 + d) * POS;
    const unsigned short* ghd = Ghat + (size_t)d * FREQ;

    for (int i = tid; i < 64 * 72; i += 512) { Vs[i] = 0; QA[i] = 0; }
    {   // TqT K-pad cols 112..127 zero (rows 0..31)
        int rr = tid >> 4, cc = 112 + (tid & 15);
        if (tid < 512) TqT[rr * 136 + cc] = 0;
    }
    __syncthreads();
    for (int i = tid; i < POS; i += 512) {
        int p = i / 56, q = i - p * 56;
        Vs[p * 72 + q] = chan[i];
    }
    f4_t acc5[2] = { (f4_t){0,0,0,0}, (f4_t){0,0,0,0} };
    __syncthreads();

    // ===== Nyquist kq=64 tail (fp32 VALU, tiny) =====
    if (tid < 56) {
        const unsigned short* vp = Vs + tid * 72;
        float a = 0.f;
        for (int q = 0; q < 56; q += 2) a += bf2f(vp[q]) - bf2f(vp[q + 1]);
        tmp[tid] = a;
    }
    __syncthreads();
    if (tid < 256) {
        float a = 0.f;
        for (int s = 0; s < 56; ++s) a = fmaf(MvT[s * 256 + tid], tmp[s], a);
        tmp[56 + tid] = a;
    }
    __syncthreads();
    if (tid < 128) {
        float vr = tmp[56 + tid], vi = tmp[184 + tid];
        float gr = bf2f(ghd[64 * 256 + tid]), gm = bf2f(ghd[64 * 256 + 128 + tid]);
        tmp[56 + tid] = vr * gr - vi * gm;
        tmp[184 + tid] = vr * gm + vi * gr;
    }
    __syncthreads();
    if (tid < 112) {
        float a = 0.f;
        for (int r = 0; r < 256; ++r) a = fmaf(M2cT[r * 112 + tid], tmp[56 + r], a);
        tmp[312 + tid] = a;
    }
    __syncthreads();
    #pragma unroll
    for (int ti = 0; ti < 2; ++ti) {
        int t = wave * 2 + ti, mt = t >> 2, nt = t & 3;
        int bq = nt * 16 + ln;
        if (bq < 56) {
            float r1 = RT2cT[bq * 136 + 64], r2 = RT2cT[bq * 136 + 132];
            #pragma unroll
            for (int rr = 0; rr < 4; ++rr) {
                int p = mt * 16 + quad * 4 + rr;
                if (p < 56) acc5[ti][rr] += tmp[312 + p] * r1 + tmp[368 + p] * r2;
            }
        }
    }

    // ===== main chunks kq0 = 0, 32 =====
    for (int ck = 0; ck < 2; ++ck) {
        const int kq0 = ck * 32;
        __syncthreads();
        // ---- S1: D[c'][p] = RTcA[c'][q] . Vs[p][q], K=64 ----
        #pragma unroll
        for (int ti = 0; ti < 2; ++ti) {
            int t = wave * 2 + ti, mt = t >> 2, nt = t & 3;
            int m = mt * 16 + ln;
            int arow = (m >> 5) * 65 + kq0 + (m & 31);
            int pcol = nt * 16 + ln;
            f4_t a = (f4_t){0, 0, 0, 0};
            #pragma unroll
            for (int ks = 0; ks < 2; ++ks) {
                int k0 = ks * 32 + quad * 8;
                bf8_t Ah = *(const bf8_t*)(RTcAh + arow * 64 + k0);
                bf8_t Al = *(const bf8_t*)(RTcAl + arow * 64 + k0);
                bf8_t Bv = *(const bf8_t*)&Vs[pcol * 72 + k0];
                a = __builtin_amdgcn_mfma_f32_16x16x32_bf16(Ah, Bv, a, 0, 0, 0);
                a = __builtin_amdgcn_mfma_f32_16x16x32_bf16(Al, Bv, a, 0, 0, 0);
            }
            if (pcol < 56) {
                #pragma unroll
                for (int rr = 0; rr < 4; ++rr) {
                    int cp = mt * 16 + quad * 4 + rr;
                    TqT[(cp & 31) * 136 + (cp >> 5) * 56 + pcol] = f2bf(a[rr]);
                }
            }
        }
        __syncthreads();
        // ---- S2: D[r][c] = MvA[r][s] . TqT[c][s], K=128 ----
        #pragma unroll
        for (int ti = 0; ti < 4; ++ti) {
            int t = wave * 4 + ti, mt = t >> 1, nt = t & 1;
            int r = mt * 16 + ln, c = nt * 16 + ln;
            f4_t a = (f4_t){0, 0, 0, 0};
            #pragma unroll
            for (int ks = 0; ks < 4; ++ks) {
                int k0 = ks * 32 + quad * 8;
                bf8_t Ah = *(const bf8_t*)(MvAh + r * 128 + k0);
                bf8_t Al = *(const bf8_t*)(MvAl + r * 128 + k0);
                bf8_t Bv = *(const bf8_t*)&TqT[c * 136 + k0];
                a = __builtin_amdgcn_mfma_f32_16x16x32_bf16(Ah, Bv, a, 0, 0, 0);
                a = __builtin_amdgcn_mfma_f32_16x16x32_bf16(Al, Bv, a, 0, 0, 0);
            }
            int r0 = mt * 16 + quad * 4;
            ushort4 st;
            st.x = f2bf(a[0]); st.y = f2bf(a[1]); st.z = f2bf(a[2]); st.w = f2bf(a[3]);
            *(ushort4*)&VhT[c * 264 + r0] = st;
        }
        __syncthreads();
        // ---- S3: complex multiply with Ghat ----
        #pragma unroll
        for (int i = 0; i < 8; ++i) {
            int o = tid + 512 * i;
            int c = o >> 7, kp = o & 127;
            float vr = bf2f(VhT[c * 264 + kp]), vi = bf2f(VhT[c * 264 + 128 + kp]);
            int gi = (kq0 + c) * 256 + kp;
            float gr = bf2f(ghd[gi]), gm = bf2f(ghd[gi + 128]);
            VhT[c * 264 + kp] = f2bf(vr * gr - vi * gm);
            VhT[c * 264 + 128 + kp] = f2bf(vr * gm + vi * gr);
        }
        __syncthreads();
        // ---- S4: D[a][c] = M2A[a][r] . VhT[c][r], K=256 ----
        #pragma unroll
        for (int ti = 0; ti < 2; ++ti) {
            int t = wave * 2 + ti;
            if (t < 14) {
                int mt = t >> 1, nt = t & 1;
                int aa = mt * 16 + ln, c = nt * 16 + ln;
                f4_t a = (f4_t){0, 0, 0, 0};
                #pragma unroll
                for (int ks = 0; ks < 8; ++ks) {
                    int k0 = ks * 32 + quad * 8;
                    bf8_t Ah = *(const bf8_t*)(M2Ah + aa * 256 + k0);
                    bf8_t Al = *(const bf8_t*)(M2Al + aa * 256 + k0);
                    bf8_t Bv = *(const bf8_t*)&VhT[c * 264 + k0];
                    a = __builtin_amdgcn_mfma_f32_16x16x32_bf16(Ah, Bv, a, 0, 0, 0);
                    a = __builtin_amdgcn_mfma_f32_16x16x32_bf16(Al, Bv, a, 0, 0, 0);
                }
                #pragma unroll
                for (int rr = 0; rr < 4; ++rr) {
                    int av_ = mt * 16 + quad * 4 + rr;
                    int p = (av_ < 56) ? av_ : av_ - 56;
                    int reg = (av_ < 56) ? 0 : 32;
                    QA[p * 72 + reg + c] = f2bf(a[rr]);
                }
            }
        }
        __syncthreads();
        // ---- S5: acc[p][bq] += QA[p][k] . RT2B[bq][k], K=64 ----
        #pragma unroll
        for (int ti = 0; ti < 2; ++ti) {
            int t = wave * 2 + ti, mt = t >> 2, nt = t & 3;
            int p = mt * 16 + ln, bq = nt * 16 + ln;
            #pragma unroll
            for (int ks = 0; ks < 2; ++ks) {
                int k0 = ks * 32 + quad * 8;
                bf8_t Aq = *(const bf8_t*)&QA[p * 72 + k0];
                int col = (ks ? 72 : 0) + kq0 + quad * 8;
                bf8_t Bh = *(const bf8_t*)(RT2Bh + bq * 144 + col);
                bf8_t Bl = *(const bf8_t*)(RT2Bl + bq * 144 + col);
                acc5[ti] = __builtin_amdgcn_mfma_f32_16x16x32_bf16(Aq, Bh, acc5[ti], 0, 0, 0);
                acc5[ti] = __builtin_amdgcn_mfma_f32_16x16x32_bf16(Aq, Bl, acc5[ti], 0, 0, 0);
            }
        }
    }
    // ===== store y (bf16, in place) =====
    #pragma unroll
    for (int ti = 0; ti < 2; ++ti) {
        int t = wave * 2 + ti, mt = t >> 2, nt = t & 3;
        int bq = nt * 16 + ln;
        if (bq < 56) {
            #pragma unroll
            for (int rr = 0; rr < 4; ++rr) {
                int p = mt * 16 + quad * 4 + rr;
                if (p < 56) chan[p * 56 + bq] = f2bf(acc5[ti][rr]);
            }
        }
    }
}

// =====================================================================
extern "C" void kernel_launch(void* const* d_in, const int* in_sizes, int n_in,
                              void* d_out, int out_size, void* d_ws, size_t ws_size,
                              hipStream_t stream) {
    (void)in_sizes; (void)n_in; (void)out_size;
    const float* x         = (const float*)d_in[0];
    const float* W_u       = (const float*)d_in[1];
    const float* b_u       = (const float*)d_in[2];
    const float* W_v       = (const float*)d_in[3];
    const float* b_v       = (const float*)d_in[4];
    const float* W_o       = (const float*)d_in[5];
    const float* b_o       = (const float*)d_in[6];
    const float* rpe_in_w  = (const float*)d_in[7];
    const float* rpe_in_b  = (const float*)d_in[8];
    const float* rpe_h_w   = (const float*)d_in[9];
    const float* rpe_h_b   = (const float*)d_in[10];
    const float* rpe_out_w = (const float*)d_in[11];
    const float* rpe_out_b = (const float*)d_in[12];
    float* out = (float*)d_out;

    if (ws_size < (size_t)WS_FLOATS * 4) {
        probe_k<<<1, 1, 0, stream>>>(out, 1000.0f + (float)((double)ws_size * 1e-6));
        return;
    }
    const bool ext  = ws_size >= (size_t)WS_EXT * 4;
    const bool ext2 = ws_size >= (size_t)WS_EXT2 * 4;
    const bool ext3 = ws_size >= (size_t)WS_EXT3 * 4;
    const bool ext5 = ws_size >= (size_t)WS_EXT5 * 4;   // implies ext3/ext2/ext
    float* ws    = (float*)d_ws;
    float* MvT   = ws + OFF_MVT;
    float* M2cT  = ws + OFF_M2T;
    float* RT2cT = ws + OFF_RT2T;
    float* RTc   = ws + OFF_RTC;
    float* Mg    = ws + OFF_MG;
    unsigned short* RTcAh = (unsigned short*)(ws + OFF_RTCAH);
    unsigned short* RTcAl = (unsigned short*)(ws + OFF_RTCAL);
    unsigned short* MvAh  = (unsigned short*)(ws + OFF_MVAH);
    unsigned short* MvAl  = (unsigned short*)(ws + OFF_MVAL);
    unsigned short* M2Ah  = (unsigned short*)(ws + OFF_M2AH);
    unsigned short* M2Al  = (unsigned short*)(ws + OFF_M2AL);
    unsigned short* RT2Bh = (unsigned short*)(ws + OFF_RT2BH);
    unsigned short* RT2Bl = (unsigned short*)(ws + OFF_RT2BL);
    float* ninv  = ws + OFF_NINV;
    float* sinv  = ws + OFF_SINV;
    unsigned short* WB  = (unsigned short*)(ws + OFF_WB);
    unsigned short* wub = WB + WB_WU;
    unsigned short* wvb = WB + WB_WV;
    unsigned short* wob = WB + WB_WO;
    unsigned short* whb = WB + WB_WH;
    unsigned short* wrob= WB + WB_WRO;
    unsigned short* tb16= (unsigned short*)(ws + OFF_TB16);
    float* pool  = ws + OFF_POOL;
    unsigned short* Ghat16 = (unsigned short*)pool;
    unsigned short* u16    = (unsigned short*)(pool + POOL_U16);
    unsigned short* vcm16  = (unsigned short*)(pool + POOL_VCM);
    unsigned short* Gh   = (unsigned short*)(pool + POOL_GH);
    unsigned short* Gl   = (unsigned short*)(pool + POOL_GL);
    unsigned short* TgFh = (unsigned short*)(pool + POOL_TGFH);
    unsigned short* TgFl = (unsigned short*)(pool + POOL_TGFL);
    unsigned short* tbA  = (unsigned short*)pool;   // ladder bf16 ping (pool dead until per-head loop)
    unsigned short* xn16 = (unsigned short*)(ws + OFF_XN16);
    unsigned short* wuv  = (unsigned short*)(ws + OFF_WUV);
    float* buv   = ws + OFF_BUV;
    unsigned short* uyf  = (unsigned short*)(ws + OFF_UYF);
    unsigned short* GhA   = (unsigned short*)(ws + OFF_GHA);
    unsigned short* GlA   = (unsigned short*)(ws + OFF_GLA);
    unsigned short* TgFhA = (unsigned short*)(ws + OFF_TGFHA);
    unsigned short* TgFlA = (unsigned short*)(ws + OFF_TGFLA);
    unsigned short* GhatA = (unsigned short*)(ws + OFF_GHATA); // aliases GhA/GlA
    unsigned short* uvA   = (unsigned short*)(ws + OFF_UVA);   // [25088][2048] bf16,
                                                               // overlays TgF (dead post-stage2)
    float* tF    = out;                // single fp32 ladder scratch in d_out
    float* g_row_all = out;            // [12321][1024] fp32 in d_out scratch (after ladder)

    consts_k<<<533, 256, 0, stream>>>(RTc, MvT, Mg, M2cT, RT2cT);
    consts2_k<<<309, 256, 0, stream>>>(MvT, M2cT, RT2cT, RTcAh, RTcAl,
                                       MvAh, MvAl, M2Ah, M2Al, RT2Bh, RT2Bl);

    // weights -> bf16
    if (ext) {
        convuv_k<<<4096, 256, 0, stream>>>(W_u, W_v, b_u, b_v, wuv, buv);
    } else {
        convw_k<<<2048, 256, 0, stream>>>(W_u, wub, 524288);
        convw_k<<<2048, 256, 0, stream>>>(W_v, wvb, 524288);
    }
    convw_k<<<2048, 256, 0, stream>>>(W_o, wob, 524288);
    convw_k<<<3072, 256, 0, stream>>>(rpe_h_w, whb, 786432);
    convw_k<<<2048, 256, 0, stream>>>(rpe_out_w, wrob, 524288);

    // ---- RPE MLP hidden ladder (bf16 A, fused norm+relu+convert) ----
    t0n_k<<<3081, 256, 0, stream>>>(rpe_in_w, rpe_in_b, tbA);
    mgemm_k<<<dim3(4, 97), 256, 0, stream>>>(tbA, whb, 512, nullptr, nullptr, 0, 1,
        tF, rpe_h_b, nullptr, nullptr, 0, 0, GROWS, 512, 512);
    normt_k<<<3081, 256, 0, stream>>>(tF, tbA);
    mgemm_k<<<dim3(4, 97), 256, 0, stream>>>(tbA, whb + 262144, 512, nullptr, nullptr, 0, 1,
        tF, rpe_h_b + 512, nullptr, nullptr, 0, 0, GROWS, 512, 512);
    normt_k<<<3081, 256, 0, stream>>>(tF, tbA);
    mgemm_k<<<dim3(4, 97), 256, 0, stream>>>(tbA, whb + 524288, 512, nullptr, nullptr, 0, 1,
        tF, rpe_h_b + 1024, nullptr, nullptr, 0, 0, GROWS, 512, 512);
    normt_k<<<3081, 256, 0, stream>>>(tF, tb16);

    if (ext) {
        normx_k<<<6272, 256, 0, stream>>>(x, xn16);
    } else {
        norms_k<<<6272, 256, 0, stream>>>(x, ninv, ROWS);
    }

    // batched RPE-out GEMM for all heads: tb16 @ wrob^T -> g_row_all[12321][1024]
    mgemm_k<<<dim3(8, 97), 256, 0, stream>>>(tb16, wrob, 512, nullptr, nullptr, 0, 1,
        g_row_all, rpe_out_b, nullptr, nullptr, 0, 0, GROWS, 1024, 512);

    if (ext3) {
        // ---- batched all-heads g-spectrum: 4 launches ----
        gtr_k<<<dim3(386, 4, 8), dim3(32, 8), 0, stream>>>(g_row_all, 1024, GhA, GlA);
        pads_k<<<7548, 256, 0, stream>>>(GhA, GlA, TgFhA, TgFlA, 8);
        hilo_gemm_k<<<dim3(111, 2, 8), 256, 0, stream>>>(GhA, GlA, RTc, 0, 1,
            TgFhA, TgFlA, 0, 128, GH_STRIDE_US, TGF_STRIDE_US);
        hilo_gemm_k<<<dim3(2, 65, 8), 256, 0, stream>>>(TgFhA, TgFlA, Mg, 1, 0,
            GhatA, nullptr, 1, 224, TGF_STRIDE_US, GHAT_STRIDE_US);
    }

    if (ext5) {
        // batched all-heads u|v projection: ONE full-width GEMM (3136 blocks
        // vs 8x 392-block launches). Row-major emode-2 writes into uvA —
        // no scatter. TgFhA/TgFlA (which uvA overlays) are dead post-stage2.
        mgemm_k<<<dim3(16, 196), 256, 0, stream>>>(xn16, wuv, 512, nullptr, nullptr, 0, 1,
            uvA, buv, nullptr, nullptr, 0, 2, ROWS, 2048, 512);
    }

    // ---- per-head main path ----
    for (int h = 0; h < 8; ++h) {
        const size_t wo = (size_t)h * 65536;
        const unsigned short* ghat_h = ext3 ? (GhatA + (size_t)h * GHAT_STRIDE_US) : Ghat16;
        if (!ext3) {
            gtr_k<<<dim3(386, 4, 1), dim3(32, 8), 0, stream>>>(g_row_all + h * 128, 1024, Gh, Gl);
            pads_k<<<944, 256, 0, stream>>>(Gh, Gl, TgFh, TgFl, 1);
            hilo_gemm_k<<<dim3(111, 2), 256, 0, stream>>>(Gh, Gl, RTc, 0, 1,
                TgFh, TgFl, 0, 128, 0, 0);
            hilo_gemm_k<<<dim3(2, 65), 256, 0, stream>>>(TgFh, TgFl, Mg, 1, 0,
                Ghat16, nullptr, 1, 224, 0, 0);
        }
        if (ext5) {
            // slice v columns of this head out of uvA into vcm16
            vtr_k<<<dim3(98, 4, 8), dim3(32, 8), 0, stream>>>(uvA + h * 256 + 128, 2048, vcm16);
        } else if (ext) {
            mgemm_k<<<dim3(2, 196), 256, 0, stream>>>(xn16, wuv + (size_t)h * 131072, 512,
                vcm16, nullptr, 0, 1,
                u16, buv + h * 256, nullptr, nullptr, 0, 5, ROWS, 256, 512);
        } else {
            mgemm_k<<<dim3(1, 196), 256, 0, stream>>>(x, wvb + wo, 512, nullptr, ninv, 0, 0,
                vcm16, b_v + h * 128, nullptr, nullptr, 0, 4, ROWS, 128, 512);
        }
        vfft_k<<<1024, 512, 0, stream>>>(vcm16, ghat_h, RTcAh, RTcAl, MvAh, MvAl,
            M2Ah, M2Al, RT2Bh, RT2Bl, MvT, M2cT, RT2cT);
        if (!ext) {
            mgemm_k<<<dim3(1, 196), 256, 0, stream>>>(x, wub + wo, 512, nullptr, ninv, 0, 0,
                u16, b_u + h * 128, nullptr, nullptr, 0, 2, ROWS, 128, 512);
        }
        if (ext2) {
            if (ext5) {
                fusey2_k<<<dim3(98, 4, 8), dim3(32, 8), 0, stream>>>(uvA + h * 256, 2048, vcm16, uyf, h);
            } else {
                fusey2_k<<<dim3(98, 4, 8), dim3(32, 8), 0, stream>>>(u16, 128, vcm16, uyf, h);
            }
        } else {
            fusey_k<<<dim3(98, 4, 8), dim3(32, 8), 0, stream>>>(u16, vcm16);
            mgemm_k<<<dim3(4, 196), 256, 0, stream>>>(u16, wob + h * 128, 1024, nullptr, nullptr, 0, 1,
                nullptr, b_o, x, out, (h == 0) ? 1 : 0, 3, ROWS, 512, 128);
        }
    }
    if (ext2) {
        // single output GEMM: out = uyf[25088x1024] @ W_o^T + b_o + x
        mgemm_k<<<dim3(4, 196), 256, 0, stream>>>(uyf, wob, 1024, nullptr, nullptr, 0, 1,
            nullptr, b_o, x, out, 1, 3, ROWS, 512, 1024);
    }
}